// Round 9
// baseline (26107.562 us; speedup 1.0000x reference)
//
#include <hip/hip_runtime.h>
#include <stdint.h>

typedef long long i64;
typedef __attribute__((ext_vector_type(8))) short bf16x8;
typedef __attribute__((ext_vector_type(4))) float f32x4;

#define SV 11
#define SE 17
#define ARITY 10
#define NHEDGE 32768
#define NNODE 65536
#define NTOTAL 100000

__device__ __forceinline__ float b2f(ushort u) {
  union { uint32_t i; float f; } v; v.i = (uint32_t)u << 16; return v.f;
}
__device__ __forceinline__ ushort f2b(float f) {
  union { float f; uint32_t i; } v; v.f = f;
  uint32_t u = v.i + 0x7fffu + ((v.i >> 16) & 1u);
  return (ushort)(u >> 16);
}
__device__ __forceinline__ uint pack2(float a, float b) {
  return (uint)f2b(a) | ((uint)f2b(b) << 16);
}
__device__ __forceinline__ void cvt8(uint4 v, float* f) {
  f[0] = b2f((ushort)(v.x & 0xffff)); f[1] = b2f((ushort)(v.x >> 16));
  f[2] = b2f((ushort)(v.y & 0xffff)); f[3] = b2f((ushort)(v.y >> 16));
  f[4] = b2f((ushort)(v.z & 0xffff)); f[5] = b2f((ushort)(v.z >> 16));
  f[6] = b2f((ushort)(v.w & 0xffff)); f[7] = b2f((ushort)(v.w >> 16));
}

__device__ __forceinline__ void gload_lds16(const void* g, void* l) {
  __builtin_amdgcn_global_load_lds((const __attribute__((address_space(1))) void*)g,
                                   (__attribute__((address_space(3))) void*)l, 16, 0, 0);
}

__device__ __forceinline__ int xcd_swizzle(int orig, int nwg) {
  const int xcd = orig & 7, rest = orig >> 3;
  const int q = nwg >> 3, r = nwg & 7;
  return (xcd < r ? xcd * (q + 1) : r * (q + 1) + (xcd - r) * q) + rest;
}

// ================= compaction: count / scan / fill =============================
__global__ __launch_bounds__(256) void cnt_k(const int* __restrict__ mask, int width,
                                             int extra, int* __restrict__ cnt, int n) {
  const int i = blockIdx.x * 256 + threadIdx.x;
  if (i >= n) return;
  int c = extra;
  for (int j = 0; j < width; j++) c += (mask[(i64)i * width + j] != 0);
  cnt[i] = c;
}

__global__ __launch_bounds__(256) void scan1_k(const int* __restrict__ cnt,
                                               int* __restrict__ ss,
                                               int* __restrict__ part, int n) {
  __shared__ int sm[256];
  const int i = blockIdx.x * 256 + threadIdx.x;
  const int v = (i < n) ? cnt[i] : 0;
  sm[threadIdx.x] = v;
  __syncthreads();
  for (int o = 1; o < 256; o <<= 1) {
    const int t = (threadIdx.x >= o) ? sm[threadIdx.x - o] : 0;
    __syncthreads();
    sm[threadIdx.x] += t;
    __syncthreads();
  }
  if (i < n) ss[i] = sm[threadIdx.x] - v;  // exclusive
  if (threadIdx.x == 255) part[blockIdx.x] = sm[255];
}

__global__ __launch_bounds__(256) void scan2_k(int* __restrict__ part, int nb,
                                               int* __restrict__ ss, int n) {
  __shared__ int sm[256];
  const int v = (threadIdx.x < nb) ? part[threadIdx.x] : 0;
  sm[threadIdx.x] = v;
  __syncthreads();
  for (int o = 1; o < 256; o <<= 1) {
    const int t = (threadIdx.x >= o) ? sm[threadIdx.x - o] : 0;
    __syncthreads();
    sm[threadIdx.x] += t;
    __syncthreads();
  }
  if (threadIdx.x < nb) part[threadIdx.x] = sm[threadIdx.x] - v;
  if (threadIdx.x == 255) ss[n] = sm[255];
}

__global__ __launch_bounds__(256) void scan3_k(int* __restrict__ ss,
                                               const int* __restrict__ part,
                                               const int* __restrict__ mask, int width,
                                               int extra, int* __restrict__ tok, int n) {
  const int i = blockIdx.x * 256 + threadIdx.x;
  if (i >= n) return;
  int off = ss[i] + part[blockIdx.x];
  ss[i] = off;
  if (extra) {
    tok[off++] = (i << 5);
    for (int j = 0; j < width; j++)
      if (mask[(i64)i * width + j] != 0) tok[off++] = (i << 5) | (j + 1);
  } else {
    for (int j = 0; j < width; j++)
      if (mask[(i64)i * width + j] != 0) tok[off++] = (i << 5) | j;
  }
}

// ================= 128x128 bf16 MFMA GEMM =====================================
template <int K, int MODE>
__global__ __launch_bounds__(256) void gemm_bf16_k(const ushort* __restrict__ A,
                                                   const ushort* __restrict__ W,
                                                   const float* __restrict__ bias,
                                                   ushort* __restrict__ C, int M, int N,
                                                   const int* ssn, int nseq,
                                                   const int* arp) {
  const int tid = threadIdx.x;
  const int wave = tid >> 6, lane = tid & 63;
  const int nwg = gridDim.x * gridDim.y;
  const int wg = xcd_swizzle(blockIdx.y * gridDim.x + blockIdx.x, nwg);
  const int bx = wg % gridDim.x, by = wg / gridDim.x;
  const int m0 = by << 7, n0 = bx << 7;
  if (ssn && m0 >= ssn[nseq] - ssn[0]) return;
  __shared__ ushort As[128 * 64];
  __shared__ ushort Ws[128 * 64];
  const int wr = wave >> 1, wc = wave & 1;

  f32x4 acc[4][4];
#pragma unroll
  for (int m = 0; m < 4; m++)
#pragma unroll
    for (int n = 0; n < 4; n++) acc[m][n] = (f32x4){0.f, 0.f, 0.f, 0.f};

  const int srow = (wave << 5) + (lane >> 3);
  const int kblk_g = (lane & 7) ^ (lane >> 3);
  const i64 arow = arp ? (i64)(arp[m0 + srow] - arp[0]) : (i64)(m0 + srow);
  const ushort* Ag = A + arow * K + (kblk_g << 3);
  const ushort* Wg = W + (i64)(n0 + srow) * K + (kblk_g << 3);
  char* lA = (char*)As + (wave << 12);
  char* lB = (char*)Ws + (wave << 12);

#pragma unroll
  for (int i = 0; i < 4; i++) {
    gload_lds16(Ag + (i64)(i * 8) * K, lA + i * 1024);
    gload_lds16(Wg + (i64)(i * 8) * K, lB + i * 1024);
  }

  for (int k0 = 0; k0 < K; k0 += 64) {
    __syncthreads();
    bf16x8 af[2][4], bf[2][4];
#pragma unroll
    for (int kh = 0; kh < 2; kh++) {
      const int kb = (kh << 2) + (lane >> 4);
#pragma unroll
      for (int m = 0; m < 4; m++) {
        const int row = (wr << 6) + (m << 4) + (lane & 15);
        af[kh][m] = *(const bf16x8*)&As[row * 64 + ((kb ^ (row & 7)) << 3)];
      }
#pragma unroll
      for (int n = 0; n < 4; n++) {
        const int row = (wc << 6) + (n << 4) + (lane & 15);
        bf[kh][n] = *(const bf16x8*)&Ws[row * 64 + ((kb ^ (row & 7)) << 3)];
      }
    }
    __syncthreads();
    if (k0 + 64 < K) {
#pragma unroll
      for (int i = 0; i < 4; i++) {
        gload_lds16(Ag + (k0 + 64) + (i64)(i * 8) * K, lA + i * 1024);
        gload_lds16(Wg + (k0 + 64) + (i64)(i * 8) * K, lB + i * 1024);
      }
    }
#pragma unroll
    for (int kh = 0; kh < 2; kh++)
#pragma unroll
      for (int m = 0; m < 4; m++)
#pragma unroll
        for (int n = 0; n < 4; n++)
          acc[m][n] = __builtin_amdgcn_mfma_f32_16x16x32_bf16(bf[kh][n], af[kh][m], acc[m][n], 0, 0, 0);
  }

#pragma unroll
  for (int m = 0; m < 4; m++) {
    const int row = m0 + (wr << 6) + (m << 4) + (lane & 15);
#pragma unroll
    for (int n = 0; n < 4; n++) {
      const int col = n0 + (wc << 6) + (n << 4) + ((lane >> 4) << 2);
      float v0 = acc[m][n][0], v1 = acc[m][n][1], v2 = acc[m][n][2], v3 = acc[m][n][3];
      if (MODE > 0) {
        const f32x4 bv = *(const f32x4*)&bias[col];
        v0 += bv[0]; v1 += bv[1]; v2 += bv[2]; v3 += bv[3];
      }
      if (MODE == 2) {
        v0 = fmaxf(v0, 0.f); v1 = fmaxf(v1, 0.f);
        v2 = fmaxf(v2, 0.f); v3 = fmaxf(v3, 0.f);
      }
      uint2 o; o.x = pack2(v0, v1); o.y = pack2(v2, v3);
      *(uint2*)&C[(i64)row * N + col] = o;
    }
  }
}

// ============ Fused GEMM + residual + LayerNorm (N = 256) ======================
template <int K>
__global__ __launch_bounds__(512) void gemm_ln_k(const ushort* __restrict__ A,
                                                 const ushort* __restrict__ W,
                                                 const float* __restrict__ bias,
                                                 const ushort* R, int rstride,
                                                 const float* __restrict__ g,
                                                 const float* __restrict__ b,
                                                 ushort* C, int cstride, int M,
                                                 const int* ssn, int nseq,
                                                 const int* rrp) {
  const int m0 = blockIdx.x << 7;
  if (ssn && m0 >= ssn[nseq] - ssn[0]) return;
  __shared__ ushort As[128 * 64];
  __shared__ ushort Ws[256 * 64];
  __shared__ float partS[128][4];
  __shared__ float partQ[128][4];
  const int tid = threadIdx.x;
  const int wave = tid >> 6, lane = tid & 63;
  const int wr = wave >> 2, wc = wave & 3;

  f32x4 acc[4][4];
#pragma unroll
  for (int m = 0; m < 4; m++)
#pragma unroll
    for (int n = 0; n < 4; n++) acc[m][n] = (f32x4){0.f, 0.f, 0.f, 0.f};

  int rowA[2], kgA[2];
#pragma unroll
  for (int i = 0; i < 2; i++) {
    const int u = wave * 128 + i * 64 + lane;
    rowA[i] = u >> 3; kgA[i] = (u & 7) ^ ((u >> 3) & 7);
  }
  int rowW[4], kgW[4];
#pragma unroll
  for (int i = 0; i < 4; i++) {
    const int u = wave * 256 + i * 64 + lane;
    rowW[i] = u >> 3; kgW[i] = (u & 7) ^ ((u >> 3) & 7);
  }

#pragma unroll
  for (int i = 0; i < 2; i++)
    gload_lds16(A + (i64)(m0 + rowA[i]) * K + (kgA[i] << 3),
                (char*)As + (wave * 128 + i * 64) * 16);
#pragma unroll
  for (int i = 0; i < 4; i++)
    gload_lds16(W + (i64)rowW[i] * K + (kgW[i] << 3),
                (char*)Ws + (wave * 256 + i * 64) * 16);

  for (int k0 = 0; k0 < K; k0 += 64) {
    __syncthreads();
    bf16x8 af[2][4], bf[2][4];
#pragma unroll
    for (int kh = 0; kh < 2; kh++) {
      const int kb = (kh << 2) + (lane >> 4);
#pragma unroll
      for (int m = 0; m < 4; m++) {
        const int row = (wr << 6) + (m << 4) + (lane & 15);
        af[kh][m] = *(const bf16x8*)&As[row * 64 + ((kb ^ (row & 7)) << 3)];
      }
#pragma unroll
      for (int n = 0; n < 4; n++) {
        const int row = (wc << 6) + (n << 4) + (lane & 15);
        bf[kh][n] = *(const bf16x8*)&Ws[row * 64 + ((kb ^ (row & 7)) << 3)];
      }
    }
    __syncthreads();
    if (k0 + 64 < K) {
#pragma unroll
      for (int i = 0; i < 2; i++)
        gload_lds16(A + (i64)(m0 + rowA[i]) * K + (k0 + 64) + (kgA[i] << 3),
                    (char*)As + (wave * 128 + i * 64) * 16);
#pragma unroll
      for (int i = 0; i < 4; i++)
        gload_lds16(W + (i64)rowW[i] * K + (k0 + 64) + (kgW[i] << 3),
                    (char*)Ws + (wave * 256 + i * 64) * 16);
    }
#pragma unroll
    for (int kh = 0; kh < 2; kh++)
#pragma unroll
      for (int m = 0; m < 4; m++)
#pragma unroll
        for (int n = 0; n < 4; n++)
          acc[m][n] = __builtin_amdgcn_mfma_f32_16x16x32_bf16(bf[kh][n], af[kh][m], acc[m][n], 0, 0, 0);
  }

#pragma unroll
  for (int m = 0; m < 4; m++) {
    const int tokl = (wr << 6) + (m << 4) + (lane & 15);
    const int row = m0 + tokl;
    const i64 rr = rrp ? (i64)(rrp[row] - rrp[0]) : (i64)row;
    float s = 0.f, q = 0.f;
#pragma unroll
    for (int n = 0; n < 4; n++) {
      const int col = (wc << 6) + (n << 4) + ((lane >> 4) << 2);
      const f32x4 bv = *(const f32x4*)&bias[col];
      const uint2 ru = *(const uint2*)&R[rr * rstride + col];
      float v0 = acc[m][n][0] + bv[0] + b2f((ushort)(ru.x & 0xffff));
      float v1 = acc[m][n][1] + bv[1] + b2f((ushort)(ru.x >> 16));
      float v2 = acc[m][n][2] + bv[2] + b2f((ushort)(ru.y & 0xffff));
      float v3 = acc[m][n][3] + bv[3] + b2f((ushort)(ru.y >> 16));
      acc[m][n][0] = v0; acc[m][n][1] = v1; acc[m][n][2] = v2; acc[m][n][3] = v3;
      s += v0 + v1 + v2 + v3;
      q += v0 * v0 + v1 * v1 + v2 * v2 + v3 * v3;
    }
    s += __shfl_xor(s, 16, 64); s += __shfl_xor(s, 32, 64);
    q += __shfl_xor(q, 16, 64); q += __shfl_xor(q, 32, 64);
    if (lane < 16) { partS[tokl][wc] = s; partQ[tokl][wc] = q; }
  }
  __syncthreads();
#pragma unroll
  for (int m = 0; m < 4; m++) {
    const int tokl = (wr << 6) + (m << 4) + (lane & 15);
    const i64 row = (i64)(m0 + tokl);
    const f32x4 s4 = *(const f32x4*)&partS[tokl][0];
    const f32x4 q4 = *(const f32x4*)&partQ[tokl][0];
    const float mean = (s4[0] + s4[1] + s4[2] + s4[3]) * (1.f / 256.f);
    const float var = (q4[0] + q4[1] + q4[2] + q4[3]) * (1.f / 256.f) - mean * mean;
    const float rs = rsqrtf(var + 1e-5f);
#pragma unroll
    for (int n = 0; n < 4; n++) {
      const int col = (wc << 6) + (n << 4) + ((lane >> 4) << 2);
      const f32x4 g4 = *(const f32x4*)&g[col];
      const f32x4 b4 = *(const f32x4*)&b[col];
      uint2 o;
      o.x = pack2((acc[m][n][0] - mean) * rs * g4[0] + b4[0],
                  (acc[m][n][1] - mean) * rs * g4[1] + b4[1]);
      o.y = pack2((acc[m][n][2] - mean) * rs * g4[2] + b4[2],
                  (acc[m][n][3] - mean) * rs * g4[3] + b4[3]);
      *(uint2*)&C[row * cstride + col] = o;
    }
  }
}

// ========= Layer-1 attention (compact, mask-free, variable length) ============
template <int S>
__global__ __launch_bounds__(16 * S) void attn1_k(const ushort* __restrict__ QKV,
                                                  const int* __restrict__ ss,
                                                  ushort* __restrict__ O) {
  __shared__ float KL[4][S][68];
  __shared__ float VL[4][S][68];
  const int tid = threadIdx.x;
  const int s0 = ss[0];
  const int base = ss[blockIdx.x] - s0;
  const int L = ss[blockIdx.x + 1] - ss[blockIdx.x];

  for (int u = tid; u < 128 * L; u += 16 * S) {
    const int d4 = u & 15, h = (u >> 4) & 3, mt = u >> 6;
    const int mat = (mt >= L), t = mat ? mt - L : mt;
    const ushort* gp = QKV + (i64)(base + t) * 768 + 256 + mat * 256 + h * 64 + d4 * 4;
    ushort4 raw = *(const ushort4*)gp;
    float* dst = (mat ? &VL[h][t][0] : &KL[h][t][0]) + d4 * 4;
    dst[0] = b2f(raw.x); dst[1] = b2f(raw.y); dst[2] = b2f(raw.z); dst[3] = b2f(raw.w);
  }
  __syncthreads();

  const int h = tid / (4 * S);
  const int r = tid - h * 4 * S;
  const int q = r >> 2, j = r & 3;
  if (q >= L) return;

  float qv[16];
  {
    const ushort* qp = QKV + (i64)(base + q) * 768 + h * 64 + j * 16;
    cvt8(*(const uint4*)qp, qv);
    cvt8(*(const uint4*)(qp + 8), qv + 8);
  }

  float w[S];
  float mx = -1e30f;
#pragma unroll
  for (int s = 0; s < S; s++) {
    float p = -1e30f;
    if (s < L) {
      const float* kr = &KL[h][s][j * 16];
      p = 0.f;
#pragma unroll
      for (int e = 0; e < 4; e++) {
        const float4 kv = *(const float4*)(kr + e * 4);
        p = fmaf(qv[e * 4 + 0], kv.x, p);
        p = fmaf(qv[e * 4 + 1], kv.y, p);
        p = fmaf(qv[e * 4 + 2], kv.z, p);
        p = fmaf(qv[e * 4 + 3], kv.w, p);
      }
      p += __shfl_xor(p, 1, 64);
      p += __shfl_xor(p, 2, 64);
      p *= 0.125f;
    }
    w[s] = p;
    mx = fmaxf(mx, p);
  }
  float sum = 0.f;
#pragma unroll
  for (int s = 0; s < S; s++) { w[s] = __expf(w[s] - mx); sum += w[s]; }
  const float inv = 1.f / sum;

  float o[16];
#pragma unroll
  for (int e = 0; e < 16; e++) o[e] = 0.f;
#pragma unroll
  for (int s = 0; s < S; s++) {
    if (s < L) {
      const float ws = w[s];
      const float* vr = &VL[h][s][j * 16];
#pragma unroll
      for (int e = 0; e < 4; e++) {
        const float4 vv = *(const float4*)(vr + e * 4);
        o[e * 4 + 0] = fmaf(ws, vv.x, o[e * 4 + 0]);
        o[e * 4 + 1] = fmaf(ws, vv.y, o[e * 4 + 1]);
        o[e * 4 + 2] = fmaf(ws, vv.z, o[e * 4 + 2]);
        o[e * 4 + 3] = fmaf(ws, vv.w, o[e * 4 + 3]);
      }
    }
  }
  uint4 st0, st1;
  st0.x = pack2(o[0] * inv, o[1] * inv);   st0.y = pack2(o[2] * inv, o[3] * inv);
  st0.z = pack2(o[4] * inv, o[5] * inv);   st0.w = pack2(o[6] * inv, o[7] * inv);
  st1.x = pack2(o[8] * inv, o[9] * inv);   st1.y = pack2(o[10] * inv, o[11] * inv);
  st1.z = pack2(o[12] * inv, o[13] * inv); st1.w = pack2(o[14] * inv, o[15] * inv);
  ushort* op = O + (i64)(base + q) * 256 + h * 64 + j * 16;
  *(uint4*)op = st0;
  *(uint4*)(op + 8) = st1;
}

// ===== Layer-2 attention, CLS query ===========================================
template <int S>
__global__ __launch_bounds__(256) void attn_cls_k(const ushort* __restrict__ Qc,
                                                  const ushort* __restrict__ KV,
                                                  const int* __restrict__ ss,
                                                  ushort* __restrict__ Ocls) {
  const int tid = threadIdx.x;
  const int sl = tid >> 4, h = (tid >> 2) & 3, j = tid & 3;
  const int seq = blockIdx.x * 16 + sl;
  const int base = ss[seq] - ss[0];
  const int L = ss[seq + 1] - ss[seq];

  float qv[16];
  {
    const ushort* qp = Qc + (i64)seq * 256 + h * 64 + j * 16;
    cvt8(*(const uint4*)qp, qv);
    cvt8(*(const uint4*)(qp + 8), qv + 8);
  }
  float w[S];
  float mx = -1e30f;
#pragma unroll
  for (int s = 0; s < S; s++) {
    float p = -1e30f;
    if (s < L) {
      float kf[16];
      const ushort* kp = KV + (i64)(base + s) * 512 + h * 64 + j * 16;
      cvt8(*(const uint4*)kp, kf);
      cvt8(*(const uint4*)(kp + 8), kf + 8);
      p = 0.f;
#pragma unroll
      for (int e = 0; e < 16; e++) p = fmaf(qv[e], kf[e], p);
      p += __shfl_xor(p, 1, 64);
      p += __shfl_xor(p, 2, 64);
      p *= 0.125f;
    }
    w[s] = p;
    mx = fmaxf(mx, p);
  }
  float sum = 0.f;
#pragma unroll
  for (int s = 0; s < S; s++) { w[s] = __expf(w[s] - mx); sum += w[s]; }
  const float inv = 1.f / sum;

  float o[16];
#pragma unroll
  for (int e = 0; e < 16; e++) o[e] = 0.f;
#pragma unroll
  for (int s = 0; s < S; s++) {
    if (s < L) {
      float vf[16];
      const ushort* vp = KV + (i64)(base + s) * 512 + 256 + h * 64 + j * 16;
      cvt8(*(const uint4*)vp, vf);
      cvt8(*(const uint4*)(vp + 8), vf + 8);
      const float ws = w[s];
#pragma unroll
      for (int e = 0; e < 16; e++) o[e] = fmaf(ws, vf[e], o[e]);
    }
  }
  uint4 st0, st1;
  st0.x = pack2(o[0] * inv, o[1] * inv);   st0.y = pack2(o[2] * inv, o[3] * inv);
  st0.z = pack2(o[4] * inv, o[5] * inv);   st0.w = pack2(o[6] * inv, o[7] * inv);
  st1.x = pack2(o[8] * inv, o[9] * inv);   st1.y = pack2(o[10] * inv, o[11] * inv);
  st1.z = pack2(o[12] * inv, o[13] * inv); st1.w = pack2(o[14] * inv, o[15] * inv);
  ushort* op = Ocls + (i64)seq * 256 + h * 64 + j * 16;
  *(uint4*)op = st0;
  *(uint4*)(op + 8) = st1;
}

// ================= gathers / scatters / conversion =============================
__global__ __launch_bounds__(256) void f2b_cvt_k(const float* __restrict__ in,
                                                 ushort* __restrict__ out, int n) {
  for (int i = blockIdx.x * 256 + threadIdx.x; i < n; i += gridDim.x * 256)
    out[i] = f2b(in[i]);
}

__global__ __launch_bounds__(256) void gather_v2e_k(const float* __restrict__ unity,
                                                    const float* __restrict__ pos,
                                                    const int* __restrict__ xid,
                                                    const int* __restrict__ xpos,
                                                    const int* __restrict__ tok,
                                                    const int* __restrict__ ss, int nseq,
                                                    ushort* __restrict__ X) {
  const int t = blockIdx.x * 4 + (threadIdx.x >> 6);
  const int lane = threadIdx.x & 63;
  const int s0 = ss[0];
  if (t >= ss[nseq] - s0) return;
  const int code = tok[s0 + t];
  const int e = code >> 5, slot = code & 31;
  float4 v = make_float4(0.f, 0.f, 0.f, 0.f);
  if (slot > 0) {
    const int id = xid[(i64)e * ARITY + (slot - 1)];
    v = *(const float4*)&unity[(i64)id * 256 + lane * 4];
  }
  const int pp = xpos[(i64)e * SV + slot];
  const float4 pv = *(const float4*)&pos[(i64)pp * 256 + lane * 4];
  uint2 o;
  o.x = pack2(v.x + pv.x, v.y + pv.y);
  o.y = pack2(v.z + pv.z, v.w + pv.w);
  *(uint2*)&X[(i64)t * 256 + lane * 4] = o;
}

__global__ __launch_bounds__(256) void gather_e2v_k(const ushort* __restrict__ ext,
                                                    const int* __restrict__ hid,
                                                    const int* __restrict__ tok,
                                                    const int* __restrict__ ss, int nseq,
                                                    ushort* __restrict__ X) {
  const int t = blockIdx.x * 4 + (threadIdx.x >> 6);
  const int lane = threadIdx.x & 63;
  const int s0 = ss[0];
  if (t >= ss[nseq] - s0) return;
  const int code = tok[s0 + t];
  const int n = code >> 5, slot = code & 31;
  const int id = hid[(i64)n * SE + slot];
  *(uint2*)&X[(i64)t * 256 + lane * 4] =
      *(const uint2*)&ext[(i64)id * 256 + lane * 4];
}

__global__ __launch_bounds__(256) void scatter_k(const ushort* __restrict__ Xc,
                                                 const int* __restrict__ subg,
                                                 float* __restrict__ unity, int n0) {
  const int nl = blockIdx.x * 4 + (threadIdx.x >> 6);
  const int lane = threadIdx.x & 63;
  const int dst = subg[n0 + nl];
  ushort4 v = *(const ushort4*)&Xc[(i64)nl * 256 + lane * 4];
  float4 o; o.x = b2f(v.x); o.y = b2f(v.y); o.z = b2f(v.z); o.w = b2f(v.w);
  *(float4*)&unity[(i64)dst * 256 + lane * 4] = o;
}

__global__ __launch_bounds__(256) void ext_init_k(ushort* __restrict__ ext,
                                                  const float* __restrict__ pad,
                                                  const float* __restrict__ cls) {
  const int d = threadIdx.x;
  ext[(i64)NHEDGE * 256 + d] = f2b(pad[d]);
  ext[(i64)(NHEDGE + 1) * 256 + d] = f2b(cls[d]);
}

__global__ __launch_bounds__(256) void out_gather_k(const ushort* __restrict__ ext,
                                                    const int* __restrict__ pred,
                                                    float* __restrict__ out) {
  const int i = blockIdx.x * 4 + (threadIdx.x >> 6);
  const int lane = threadIdx.x & 63;
  const int e = pred[i];
  ushort4 v = *(const ushort4*)&ext[(i64)e * 256 + lane * 4];
  float4 o; o.x = b2f(v.x); o.y = b2f(v.y); o.z = b2f(v.z); o.w = b2f(v.w);
  *(float4*)&out[(i64)i * 256 + lane * 4] = o;
}

// ================= host orchestration ==========================================
extern "C" void kernel_launch(void* const* d_in, const int* in_sizes, int n_in,
                              void* d_out, int out_size, void* d_ws, size_t ws_size,
                              hipStream_t stream) {
  (void)in_sizes; (void)n_in; (void)out_size;
  const float* unity_in = (const float*)d_in[0];
  const float* cls_emb  = (const float*)d_in[1];
  const float* pad_emb  = (const float*)d_in[2];
  const float* pos_tab  = (const float*)d_in[3];
  const float* qkv_w    = (const float*)d_in[4];
  const float* qkv_b    = (const float*)d_in[5];
  const float* out_w    = (const float*)d_in[6];
  const float* out_b    = (const float*)d_in[7];
  const float* ln1_g    = (const float*)d_in[8];
  const float* ln1_b    = (const float*)d_in[9];
  const float* ln2_g    = (const float*)d_in[10];
  const float* ln2_b    = (const float*)d_in[11];
  const float* ff1_w    = (const float*)d_in[12];
  const float* ff1_b    = (const float*)d_in[13];
  const float* ff2_w    = (const float*)d_in[14];
  const float* ff2_b    = (const float*)d_in[15];
  const int* xid   = (const int*)d_in[16];
  const int* vmask = (const int*)d_in[17];
  const int* xpos  = (const int*)d_in[18];
  const int* hid   = (const int*)d_in[19];
  const int* hmask = (const int*)d_in[20];
  const int* subg  = (const int*)d_in[21];
  const int* pred  = (const int*)d_in[22];

  const i64 unity_b = (i64)NTOTAL * 256 * 4;
  const i64 ext_b   = (i64)(NHEDGE + 2) * 256 * 2;
  const int nq = 2 * 768 * 256, no = 2 * 256 * 256,
            n1 = 2 * 1024 * 256, n2 = 2 * 256 * 1024;
  const i64 wts_b = (i64)(nq + no + n1 + n2) * 2;
  const i64 idx_b = ((i64)NNODE + NHEDGE + 512 +
                     (NNODE + 1) + (NHEDGE + 1) +
                     (i64)NNODE * SE + (i64)NHEDGE * SV) * 4;
  const i64 per_elem = (i64)SE * (512 + 2048 + 512);
  // CHUNK=2048: per-chunk working set (X+Y+O ~ 107 MB) fits the 256 MB L3, so
  // inter-kernel intermediates stay Infinity-Cache-resident instead of HBM.
  int CHUNK = 2048;
  while (CHUNK > 256 &&
         unity_b + ext_b + wts_b + idx_b + (i64)CHUNK * per_elem > (i64)ws_size)
    CHUNK >>= 1;

  char* w = (char*)d_ws;
  float*  unity = (float*)w;  w += unity_b;
  ushort* ext   = (ushort*)w; w += ext_b;
  ushort* wq    = (ushort*)w; w += (i64)nq * 2;
  ushort* wo    = (ushort*)w; w += (i64)no * 2;
  ushort* w1    = (ushort*)w; w += (i64)n1 * 2;
  ushort* w2    = (ushort*)w; w += (i64)n2 * 2;
  ushort* X     = (ushort*)w; w += (i64)CHUNK * SE * 256 * 2;
  ushort* Y     = (ushort*)w; w += (i64)CHUNK * SE * 1024 * 2;
  ushort* O     = (ushort*)w; w += (i64)CHUNK * SE * 256 * 2;
  int* cntE  = (int*)w; w += (i64)NNODE * 4;
  int* cntV  = (int*)w; w += (i64)NHEDGE * 4;
  int* partE = (int*)w; w += 256 * 4;
  int* partV = (int*)w; w += 256 * 4;
  int* ssE   = (int*)w; w += (i64)(NNODE + 1) * 4;
  int* ssV   = (int*)w; w += (i64)(NHEDGE + 1) * 4;
  int* tokE  = (int*)w; w += (i64)NNODE * SE * 4;
  int* tokV  = (int*)w; w += (i64)NHEDGE * SV * 4;
  ushort* Ocls = O;
  ushort* Qcls = O + (i64)CHUNK * 256;
  ushort* X2   = O + (i64)2 * CHUNK * 256;
  ushort* X3   = O + (i64)3 * CHUNK * 256;

  f2b_cvt_k<<<512, 256, 0, stream>>>(qkv_w, wq, nq);
  f2b_cvt_k<<<512, 256, 0, stream>>>(out_w, wo, no);
  f2b_cvt_k<<<512, 256, 0, stream>>>(ff1_w, w1, n1);
  f2b_cvt_k<<<512, 256, 0, stream>>>(ff2_w, w2, n2);
  hipMemcpyAsync(unity, unity_in, unity_b, hipMemcpyDeviceToDevice, stream);
  ext_init_k<<<1, 256, 0, stream>>>(ext, pad_emb, cls_emb);

  cnt_k<<<NHEDGE / 256, 256, 0, stream>>>(vmask, ARITY, 1, cntV, NHEDGE);
  scan1_k<<<NHEDGE / 256, 256, 0, stream>>>(cntV, ssV, partV, NHEDGE);
  scan2_k<<<1, 256, 0, stream>>>(partV, NHEDGE / 256, ssV, NHEDGE);
  scan3_k<<<NHEDGE / 256, 256, 0, stream>>>(ssV, partV, vmask, ARITY, 1, tokV, NHEDGE);
  cnt_k<<<NNODE / 256, 256, 0, stream>>>(hmask, SE, 0, cntE, NNODE);
  scan1_k<<<NNODE / 256, 256, 0, stream>>>(cntE, ssE, partE, NNODE);
  scan2_k<<<1, 256, 0, stream>>>(partE, NNODE / 256, ssE, NNODE);
  scan3_k<<<NNODE / 256, 256, 0, stream>>>(ssE, partE, hmask, SE, 0, tokE, NNODE);

  for (int k = 0; k <= 2; k++) {
    // ---- V2E ----
    for (int c = 0; c < NHEDGE / CHUNK; c++) {
      const int e0 = c * CHUNK;
      const int* ssc = ssV + e0;
      const int Mmax = CHUNK * SV;
      gather_v2e_k<<<Mmax / 4, 256, 0, stream>>>(unity, pos_tab, xid, xpos,
                                                 tokV, ssc, CHUNK, X);
      gemm_bf16_k<256, 1><<<dim3(6, Mmax / 128), 256, 0, stream>>>(
          X, wq, qkv_b, Y, Mmax, 768, ssc, CHUNK, nullptr);
      attn1_k<SV><<<CHUNK, 16 * SV, 0, stream>>>(Y, ssc, O);
      gemm_ln_k<256><<<Mmax / 128, 512, 0, stream>>>(
          O, wo, out_b, X, 256, ln1_g, ln1_b, X, 256, Mmax, ssc, CHUNK, nullptr);
      gemm_bf16_k<256, 2><<<dim3(8, Mmax / 128), 256, 0, stream>>>(
          X, w1, ff1_b, Y, Mmax, 1024, ssc, CHUNK, nullptr);
      gemm_ln_k<1024><<<Mmax / 128, 512, 0, stream>>>(
          Y, w2, ff2_b, X, 256, ln2_g, ln2_b, X, 256, Mmax, ssc, CHUNK, nullptr);
      gemm_bf16_k<256, 1><<<dim3(4, Mmax / 128), 256, 0, stream>>>(
          X, wq + (i64)768 * 256 + (i64)256 * 256, qkv_b + 768 + 256,
          Y, Mmax, 512, ssc, CHUNK, nullptr);
      gemm_bf16_k<256, 1><<<dim3(2, CHUNK / 128), 256, 0, stream>>>(
          X, wq + (i64)768 * 256, qkv_b + 768, Qcls, CHUNK, 256,
          nullptr, 0, ssc);
      attn_cls_k<SV><<<CHUNK / 16, 256, 0, stream>>>(Qcls, Y, ssc, Ocls);
      gemm_ln_k<256><<<CHUNK / 128, 512, 0, stream>>>(
          Ocls, wo + (i64)256 * 256, out_b + 256, X, 256,
          ln1_g + 256, ln1_b + 256, X2, 256, CHUNK, nullptr, 0, ssc);
      gemm_bf16_k<256, 2><<<dim3(8, CHUNK / 128), 256, 0, stream>>>(
          X2, w1 + (i64)1024 * 256, ff1_b + 1024, Y, CHUNK, 1024,
          nullptr, 0, nullptr);
      gemm_ln_k<1024><<<CHUNK / 128, 512, 0, stream>>>(
          Y, w2 + (i64)256 * 1024, ff2_b + 256, X2, 256,
          ln2_g + 256, ln2_b + 256, ext + (i64)e0 * 256, 256, CHUNK,
          nullptr, 0, nullptr);
    }
    // ---- E2V ----
    if (k < 2) {
      for (int c = 0; c < NNODE / CHUNK; c++) {
        const int n0 = c * CHUNK;
        const int* ssc = ssE + n0;
        const int Mmax = CHUNK * SE;
        gather_e2v_k<<<Mmax / 4, 256, 0, stream>>>(ext, hid, tokE, ssc, CHUNK, X);
        gemm_bf16_k<256, 1><<<dim3(6, Mmax / 128), 256, 0, stream>>>(
            X, wq, qkv_b, Y, Mmax, 768, ssc, CHUNK, nullptr);
        attn1_k<SE><<<CHUNK, 16 * SE, 0, stream>>>(Y, ssc, O);
        gemm_ln_k<256><<<Mmax / 128, 512, 0, stream>>>(
            O, wo, out_b, X, 256, ln1_g, ln1_b, X, 256, Mmax, ssc, CHUNK, nullptr);
        gemm_bf16_k<256, 2><<<dim3(8, Mmax / 128), 256, 0, stream>>>(
            X, w1, ff1_b, Y, Mmax, 1024, ssc, CHUNK, nullptr);
        gemm_ln_k<1024><<<Mmax / 128, 512, 0, stream>>>(
            Y, w2, ff2_b, X, 256, ln2_g, ln2_b, X, 256, Mmax, ssc, CHUNK, nullptr);
        gemm_bf16_k<256, 1><<<dim3(4, Mmax / 128), 256, 0, stream>>>(
            X, wq + (i64)768 * 256 + (i64)256 * 256, qkv_b + 768 + 256,
            Y, Mmax, 512, ssc, CHUNK, nullptr);
        gemm_bf16_k<256, 1><<<dim3(2, CHUNK / 128), 256, 0, stream>>>(
            X, wq + (i64)768 * 256, qkv_b + 768, Qcls, CHUNK, 256,
            nullptr, 0, ssc);
        attn_cls_k<SE><<<CHUNK / 16, 256, 0, stream>>>(Qcls, Y, ssc, Ocls);
        gemm_ln_k<256><<<CHUNK / 128, 512, 0, stream>>>(
            Ocls, wo + (i64)256 * 256, out_b + 256, X, 256,
            ln1_g + 256, ln1_b + 256, X2, 256, CHUNK, nullptr, 0, ssc);
        gemm_bf16_k<256, 2><<<dim3(8, CHUNK / 128), 256, 0, stream>>>(
            X2, w1 + (i64)1024 * 256, ff1_b + 1024, Y, CHUNK, 1024,
            nullptr, 0, nullptr);
        gemm_ln_k<1024><<<CHUNK / 128, 512, 0, stream>>>(
            Y, w2 + (i64)256 * 1024, ff2_b + 256, X2, 256,
            ln2_g + 256, ln2_b + 256, X3, 256, CHUNK, nullptr, 0, nullptr);
        scatter_k<<<CHUNK / 4, 256, 0, stream>>>(X3, subg, unity, n0);
      }
    }
  }
  out_gather_k<<<64, 256, 0, stream>>>(ext, pred, (float*)d_out);
}

// Round 10
// 18105.568 us; speedup vs baseline: 1.4420x; 1.4420x over previous
//
#include <hip/hip_runtime.h>
#include <stdint.h>

typedef long long i64;
typedef __attribute__((ext_vector_type(8))) short bf16x8;
typedef __attribute__((ext_vector_type(4))) float f32x4;

#define SV 11
#define SE 17
#define ARITY 10
#define NHEDGE 32768
#define NNODE 65536
#define NTOTAL 100000
#define EXTROWS 32896  // NHEDGE+2 padded to 128 multiple

__device__ __forceinline__ float b2f(ushort u) {
  union { uint32_t i; float f; } v; v.i = (uint32_t)u << 16; return v.f;
}
__device__ __forceinline__ ushort f2b(float f) {
  union { float f; uint32_t i; } v; v.f = f;
  uint32_t u = v.i + 0x7fffu + ((v.i >> 16) & 1u);
  return (ushort)(u >> 16);
}
__device__ __forceinline__ uint pack2(float a, float b) {
  return (uint)f2b(a) | ((uint)f2b(b) << 16);
}
__device__ __forceinline__ void cvt8(uint4 v, float* f) {
  f[0] = b2f((ushort)(v.x & 0xffff)); f[1] = b2f((ushort)(v.x >> 16));
  f[2] = b2f((ushort)(v.y & 0xffff)); f[3] = b2f((ushort)(v.y >> 16));
  f[4] = b2f((ushort)(v.z & 0xffff)); f[5] = b2f((ushort)(v.z >> 16));
  f[6] = b2f((ushort)(v.w & 0xffff)); f[7] = b2f((ushort)(v.w >> 16));
}

__device__ __forceinline__ void gload_lds16(const void* g, void* l) {
  __builtin_amdgcn_global_load_lds((const __attribute__((address_space(1))) void*)g,
                                   (__attribute__((address_space(3))) void*)l, 16, 0, 0);
}

__device__ __forceinline__ int xcd_swizzle(int orig, int nwg) {
  const int xcd = orig & 7, rest = orig >> 3;
  const int q = nwg >> 3, r = nwg & 7;
  return (xcd < r ? xcd * (q + 1) : r * (q + 1) + (xcd - r) * q) + rest;
}

// ================= compaction: count / scan / fill =============================
__global__ __launch_bounds__(256) void cnt_k(const int* __restrict__ mask, int width,
                                             int extra, int* __restrict__ cnt, int n) {
  const int i = blockIdx.x * 256 + threadIdx.x;
  if (i >= n) return;
  int c = extra;
  for (int j = 0; j < width; j++) c += (mask[(i64)i * width + j] != 0);
  cnt[i] = c;
}

__global__ __launch_bounds__(256) void scan1_k(const int* __restrict__ cnt,
                                               int* __restrict__ ss,
                                               int* __restrict__ part, int n) {
  __shared__ int sm[256];
  const int i = blockIdx.x * 256 + threadIdx.x;
  const int v = (i < n) ? cnt[i] : 0;
  sm[threadIdx.x] = v;
  __syncthreads();
  for (int o = 1; o < 256; o <<= 1) {
    const int t = (threadIdx.x >= o) ? sm[threadIdx.x - o] : 0;
    __syncthreads();
    sm[threadIdx.x] += t;
    __syncthreads();
  }
  if (i < n) ss[i] = sm[threadIdx.x] - v;  // exclusive
  if (threadIdx.x == 255) part[blockIdx.x] = sm[255];
}

__global__ __launch_bounds__(256) void scan2_k(int* __restrict__ part, int nb,
                                               int* __restrict__ ss, int n) {
  __shared__ int sm[256];
  const int v = (threadIdx.x < nb) ? part[threadIdx.x] : 0;
  sm[threadIdx.x] = v;
  __syncthreads();
  for (int o = 1; o < 256; o <<= 1) {
    const int t = (threadIdx.x >= o) ? sm[threadIdx.x - o] : 0;
    __syncthreads();
    sm[threadIdx.x] += t;
    __syncthreads();
  }
  if (threadIdx.x < nb) part[threadIdx.x] = sm[threadIdx.x] - v;
  if (threadIdx.x == 255) ss[n] = sm[255];
}

__global__ __launch_bounds__(256) void scan3_k(int* __restrict__ ss,
                                               const int* __restrict__ part,
                                               const int* __restrict__ mask, int width,
                                               int extra, int* __restrict__ tok, int n) {
  const int i = blockIdx.x * 256 + threadIdx.x;
  if (i >= n) return;
  int off = ss[i] + part[blockIdx.x];
  ss[i] = off;
  if (extra) {
    tok[off++] = (i << 5);
    for (int j = 0; j < width; j++)
      if (mask[(i64)i * width + j] != 0) tok[off++] = (i << 5) | (j + 1);
  } else {
    for (int j = 0; j < width; j++)
      if (mask[(i64)i * width + j] != 0) tok[off++] = (i << 5) | j;
  }
}

// ================= 128x128 bf16 MFMA GEMM =====================================
template <int K, int MODE>
__global__ __launch_bounds__(256) void gemm_bf16_k(const ushort* __restrict__ A,
                                                   const ushort* __restrict__ W,
                                                   const float* __restrict__ bias,
                                                   ushort* __restrict__ C, int M, int N,
                                                   const int* ssn, int nseq,
                                                   const int* arp) {
  const int tid = threadIdx.x;
  const int wave = tid >> 6, lane = tid & 63;
  const int nwg = gridDim.x * gridDim.y;
  const int wg = xcd_swizzle(blockIdx.y * gridDim.x + blockIdx.x, nwg);
  const int bx = wg % gridDim.x, by = wg / gridDim.x;
  const int m0 = by << 7, n0 = bx << 7;
  if (ssn && m0 >= ssn[nseq] - ssn[0]) return;
  __shared__ ushort As[128 * 64];
  __shared__ ushort Ws[128 * 64];
  const int wr = wave >> 1, wc = wave & 1;

  f32x4 acc[4][4];
#pragma unroll
  for (int m = 0; m < 4; m++)
#pragma unroll
    for (int n = 0; n < 4; n++) acc[m][n] = (f32x4){0.f, 0.f, 0.f, 0.f};

  const int srow = (wave << 5) + (lane >> 3);
  const int kblk_g = (lane & 7) ^ (lane >> 3);
  const i64 arow = arp ? (i64)(arp[m0 + srow] - arp[0]) : (i64)(m0 + srow);
  const ushort* Ag = A + arow * K + (kblk_g << 3);
  const ushort* Wg = W + (i64)(n0 + srow) * K + (kblk_g << 3);
  char* lA = (char*)As + (wave << 12);
  char* lB = (char*)Ws + (wave << 12);

#pragma unroll
  for (int i = 0; i < 4; i++) {
    gload_lds16(Ag + (i64)(i * 8) * K, lA + i * 1024);
    gload_lds16(Wg + (i64)(i * 8) * K, lB + i * 1024);
  }

  for (int k0 = 0; k0 < K; k0 += 64) {
    __syncthreads();
    bf16x8 af[2][4], bf[2][4];
#pragma unroll
    for (int kh = 0; kh < 2; kh++) {
      const int kb = (kh << 2) + (lane >> 4);
#pragma unroll
      for (int m = 0; m < 4; m++) {
        const int row = (wr << 6) + (m << 4) + (lane & 15);
        af[kh][m] = *(const bf16x8*)&As[row * 64 + ((kb ^ (row & 7)) << 3)];
      }
#pragma unroll
      for (int n = 0; n < 4; n++) {
        const int row = (wc << 6) + (n << 4) + (lane & 15);
        bf[kh][n] = *(const bf16x8*)&Ws[row * 64 + ((kb ^ (row & 7)) << 3)];
      }
    }
    __syncthreads();
    if (k0 + 64 < K) {
#pragma unroll
      for (int i = 0; i < 4; i++) {
        gload_lds16(Ag + (k0 + 64) + (i64)(i * 8) * K, lA + i * 1024);
        gload_lds16(Wg + (k0 + 64) + (i64)(i * 8) * K, lB + i * 1024);
      }
    }
#pragma unroll
    for (int kh = 0; kh < 2; kh++)
#pragma unroll
      for (int m = 0; m < 4; m++)
#pragma unroll
        for (int n = 0; n < 4; n++)
          acc[m][n] = __builtin_amdgcn_mfma_f32_16x16x32_bf16(bf[kh][n], af[kh][m], acc[m][n], 0, 0, 0);
  }

#pragma unroll
  for (int m = 0; m < 4; m++) {
    const int row = m0 + (wr << 6) + (m << 4) + (lane & 15);
#pragma unroll
    for (int n = 0; n < 4; n++) {
      const int col = n0 + (wc << 6) + (n << 4) + ((lane >> 4) << 2);
      float v0 = acc[m][n][0], v1 = acc[m][n][1], v2 = acc[m][n][2], v3 = acc[m][n][3];
      if (MODE > 0) {
        const f32x4 bv = *(const f32x4*)&bias[col];
        v0 += bv[0]; v1 += bv[1]; v2 += bv[2]; v3 += bv[3];
      }
      if (MODE == 2) {
        v0 = fmaxf(v0, 0.f); v1 = fmaxf(v1, 0.f);
        v2 = fmaxf(v2, 0.f); v3 = fmaxf(v3, 0.f);
      }
      uint2 o; o.x = pack2(v0, v1); o.y = pack2(v2, v3);
      *(uint2*)&C[(i64)row * N + col] = o;
    }
  }
}

// ============ Fused GEMM + residual + LayerNorm (N = 256) ======================
template <int K>
__global__ __launch_bounds__(512) void gemm_ln_k(const ushort* __restrict__ A,
                                                 const ushort* __restrict__ W,
                                                 const float* __restrict__ bias,
                                                 const ushort* R, int rstride,
                                                 const float* __restrict__ g,
                                                 const float* __restrict__ b,
                                                 ushort* C, int cstride, int M,
                                                 const int* ssn, int nseq,
                                                 const int* rrp) {
  const int m0 = blockIdx.x << 7;
  if (ssn && m0 >= ssn[nseq] - ssn[0]) return;
  __shared__ ushort As[128 * 64];
  __shared__ ushort Ws[256 * 64];
  __shared__ float partS[128][4];
  __shared__ float partQ[128][4];
  const int tid = threadIdx.x;
  const int wave = tid >> 6, lane = tid & 63;
  const int wr = wave >> 2, wc = wave & 3;

  f32x4 acc[4][4];
#pragma unroll
  for (int m = 0; m < 4; m++)
#pragma unroll
    for (int n = 0; n < 4; n++) acc[m][n] = (f32x4){0.f, 0.f, 0.f, 0.f};

  int rowA[2], kgA[2];
#pragma unroll
  for (int i = 0; i < 2; i++) {
    const int u = wave * 128 + i * 64 + lane;
    rowA[i] = u >> 3; kgA[i] = (u & 7) ^ ((u >> 3) & 7);
  }
  int rowW[4], kgW[4];
#pragma unroll
  for (int i = 0; i < 4; i++) {
    const int u = wave * 256 + i * 64 + lane;
    rowW[i] = u >> 3; kgW[i] = (u & 7) ^ ((u >> 3) & 7);
  }

#pragma unroll
  for (int i = 0; i < 2; i++)
    gload_lds16(A + (i64)(m0 + rowA[i]) * K + (kgA[i] << 3),
                (char*)As + (wave * 128 + i * 64) * 16);
#pragma unroll
  for (int i = 0; i < 4; i++)
    gload_lds16(W + (i64)rowW[i] * K + (kgW[i] << 3),
                (char*)Ws + (wave * 256 + i * 64) * 16);

  for (int k0 = 0; k0 < K; k0 += 64) {
    __syncthreads();
    bf16x8 af[2][4], bf[2][4];
#pragma unroll
    for (int kh = 0; kh < 2; kh++) {
      const int kb = (kh << 2) + (lane >> 4);
#pragma unroll
      for (int m = 0; m < 4; m++) {
        const int row = (wr << 6) + (m << 4) + (lane & 15);
        af[kh][m] = *(const bf16x8*)&As[row * 64 + ((kb ^ (row & 7)) << 3)];
      }
#pragma unroll
      for (int n = 0; n < 4; n++) {
        const int row = (wc << 6) + (n << 4) + (lane & 15);
        bf[kh][n] = *(const bf16x8*)&Ws[row * 64 + ((kb ^ (row & 7)) << 3)];
      }
    }
    __syncthreads();
    if (k0 + 64 < K) {
#pragma unroll
      for (int i = 0; i < 2; i++)
        gload_lds16(A + (i64)(m0 + rowA[i]) * K + (k0 + 64) + (kgA[i] << 3),
                    (char*)As + (wave * 128 + i * 64) * 16);
#pragma unroll
      for (int i = 0; i < 4; i++)
        gload_lds16(W + (i64)rowW[i] * K + (k0 + 64) + (kgW[i] << 3),
                    (char*)Ws + (wave * 256 + i * 64) * 16);
    }
#pragma unroll
    for (int kh = 0; kh < 2; kh++)
#pragma unroll
      for (int m = 0; m < 4; m++)
#pragma unroll
        for (int n = 0; n < 4; n++)
          acc[m][n] = __builtin_amdgcn_mfma_f32_16x16x32_bf16(bf[kh][n], af[kh][m], acc[m][n], 0, 0, 0);
  }

#pragma unroll
  for (int m = 0; m < 4; m++) {
    const int tokl = (wr << 6) + (m << 4) + (lane & 15);
    const int row = m0 + tokl;
    const i64 rr = rrp ? (i64)(rrp[row] - rrp[0]) : (i64)row;
    float s = 0.f, q = 0.f;
#pragma unroll
    for (int n = 0; n < 4; n++) {
      const int col = (wc << 6) + (n << 4) + ((lane >> 4) << 2);
      const f32x4 bv = *(const f32x4*)&bias[col];
      const uint2 ru = *(const uint2*)&R[rr * rstride + col];
      float v0 = acc[m][n][0] + bv[0] + b2f((ushort)(ru.x & 0xffff));
      float v1 = acc[m][n][1] + bv[1] + b2f((ushort)(ru.x >> 16));
      float v2 = acc[m][n][2] + bv[2] + b2f((ushort)(ru.y & 0xffff));
      float v3 = acc[m][n][3] + bv[3] + b2f((ushort)(ru.y >> 16));
      acc[m][n][0] = v0; acc[m][n][1] = v1; acc[m][n][2] = v2; acc[m][n][3] = v3;
      s += v0 + v1 + v2 + v3;
      q += v0 * v0 + v1 * v1 + v2 * v2 + v3 * v3;
    }
    s += __shfl_xor(s, 16, 64); s += __shfl_xor(s, 32, 64);
    q += __shfl_xor(q, 16, 64); q += __shfl_xor(q, 32, 64);
    if (lane < 16) { partS[tokl][wc] = s; partQ[tokl][wc] = q; }
  }
  __syncthreads();
#pragma unroll
  for (int m = 0; m < 4; m++) {
    const int tokl = (wr << 6) + (m << 4) + (lane & 15);
    const i64 row = (i64)(m0 + tokl);
    const f32x4 s4 = *(const f32x4*)&partS[tokl][0];
    const f32x4 q4 = *(const f32x4*)&partQ[tokl][0];
    const float mean = (s4[0] + s4[1] + s4[2] + s4[3]) * (1.f / 256.f);
    const float var = (q4[0] + q4[1] + q4[2] + q4[3]) * (1.f / 256.f) - mean * mean;
    const float rs = rsqrtf(var + 1e-5f);
#pragma unroll
    for (int n = 0; n < 4; n++) {
      const int col = (wc << 6) + (n << 4) + ((lane >> 4) << 2);
      const f32x4 g4 = *(const f32x4*)&g[col];
      const f32x4 b4 = *(const f32x4*)&b[col];
      uint2 o;
      o.x = pack2((acc[m][n][0] - mean) * rs * g4[0] + b4[0],
                  (acc[m][n][1] - mean) * rs * g4[1] + b4[1]);
      o.y = pack2((acc[m][n][2] - mean) * rs * g4[2] + b4[2],
                  (acc[m][n][3] - mean) * rs * g4[3] + b4[3]);
      *(uint2*)&C[row * cstride + col] = o;
    }
  }
}

// ========= Layer-1 attention (compact, from per-token QKV rows) ===============
template <int S>
__global__ __launch_bounds__(16 * S) void attn1_k(const ushort* __restrict__ QKV,
                                                  const int* __restrict__ ss,
                                                  ushort* __restrict__ O) {
  __shared__ float KL[4][S][68];
  __shared__ float VL[4][S][68];
  const int tid = threadIdx.x;
  const int s0 = ss[0];
  const int base = ss[blockIdx.x] - s0;
  const int L = ss[blockIdx.x + 1] - ss[blockIdx.x];

  for (int u = tid; u < 128 * L; u += 16 * S) {
    const int d4 = u & 15, h = (u >> 4) & 3, mt = u >> 6;
    const int mat = (mt >= L), t = mat ? mt - L : mt;
    const ushort* gp = QKV + (i64)(base + t) * 768 + 256 + mat * 256 + h * 64 + d4 * 4;
    ushort4 raw = *(const ushort4*)gp;
    float* dst = (mat ? &VL[h][t][0] : &KL[h][t][0]) + d4 * 4;
    dst[0] = b2f(raw.x); dst[1] = b2f(raw.y); dst[2] = b2f(raw.z); dst[3] = b2f(raw.w);
  }
  __syncthreads();

  const int h = tid / (4 * S);
  const int r = tid - h * 4 * S;
  const int q = r >> 2, j = r & 3;
  if (q >= L) return;

  float qv[16];
  {
    const ushort* qp = QKV + (i64)(base + q) * 768 + h * 64 + j * 16;
    cvt8(*(const uint4*)qp, qv);
    cvt8(*(const uint4*)(qp + 8), qv + 8);
  }

  float w[S];
  float mx = -1e30f;
#pragma unroll
  for (int s = 0; s < S; s++) {
    float p = -1e30f;
    if (s < L) {
      const float* kr = &KL[h][s][j * 16];
      p = 0.f;
#pragma unroll
      for (int e = 0; e < 4; e++) {
        const float4 kv = *(const float4*)(kr + e * 4);
        p = fmaf(qv[e * 4 + 0], kv.x, p);
        p = fmaf(qv[e * 4 + 1], kv.y, p);
        p = fmaf(qv[e * 4 + 2], kv.z, p);
        p = fmaf(qv[e * 4 + 3], kv.w, p);
      }
      p += __shfl_xor(p, 1, 64);
      p += __shfl_xor(p, 2, 64);
      p *= 0.125f;
    }
    w[s] = p;
    mx = fmaxf(mx, p);
  }
  float sum = 0.f;
#pragma unroll
  for (int s = 0; s < S; s++) { w[s] = __expf(w[s] - mx); sum += w[s]; }
  const float inv = 1.f / sum;

  float o[16];
#pragma unroll
  for (int e = 0; e < 16; e++) o[e] = 0.f;
#pragma unroll
  for (int s = 0; s < S; s++) {
    if (s < L) {
      const float ws = w[s];
      const float* vr = &VL[h][s][j * 16];
#pragma unroll
      for (int e = 0; e < 4; e++) {
        const float4 vv = *(const float4*)(vr + e * 4);
        o[e * 4 + 0] = fmaf(ws, vv.x, o[e * 4 + 0]);
        o[e * 4 + 1] = fmaf(ws, vv.y, o[e * 4 + 1]);
        o[e * 4 + 2] = fmaf(ws, vv.z, o[e * 4 + 2]);
        o[e * 4 + 3] = fmaf(ws, vv.w, o[e * 4 + 3]);
      }
    }
  }
  uint4 st0, st1;
  st0.x = pack2(o[0] * inv, o[1] * inv);   st0.y = pack2(o[2] * inv, o[3] * inv);
  st0.z = pack2(o[4] * inv, o[5] * inv);   st0.w = pack2(o[6] * inv, o[7] * inv);
  st1.x = pack2(o[8] * inv, o[9] * inv);   st1.y = pack2(o[10] * inv, o[11] * inv);
  st1.z = pack2(o[12] * inv, o[13] * inv); st1.w = pack2(o[14] * inv, o[15] * inv);
  ushort* op = O + (i64)(base + q) * 256 + h * 64 + j * 16;
  *(uint4*)op = st0;
  *(uint4*)(op + 8) = st1;
}

// ========= Layer-1 attention, E2V: QKV gathered from hedge table ==============
// QKVE[row 768] is the per-hedge QKV (dedup: QKV(ext[hid]) == (ext@W)[hid]).
// gid[token] = hedge row id for that compact token.
template <int S>
__global__ __launch_bounds__(16 * S) void attn1g_k(const ushort* __restrict__ QKVE,
                                                   const int* __restrict__ gid,
                                                   const int* __restrict__ ss,
                                                   ushort* __restrict__ O) {
  __shared__ float KL[4][S][68];
  __shared__ float VL[4][S][68];
  __shared__ int ids[S];
  const int tid = threadIdx.x;
  const int s0 = ss[0];
  const int base = ss[blockIdx.x] - s0;
  const int L = ss[blockIdx.x + 1] - ss[blockIdx.x];

  if (tid < L) ids[tid] = gid[base + tid];
  __syncthreads();

  for (int u = tid; u < 128 * L; u += 16 * S) {
    const int d4 = u & 15, h = (u >> 4) & 3, mt = u >> 6;
    const int mat = (mt >= L), t = mat ? mt - L : mt;
    const ushort* gp = QKVE + (i64)ids[t] * 768 + 256 + mat * 256 + h * 64 + d4 * 4;
    ushort4 raw = *(const ushort4*)gp;
    float* dst = (mat ? &VL[h][t][0] : &KL[h][t][0]) + d4 * 4;
    dst[0] = b2f(raw.x); dst[1] = b2f(raw.y); dst[2] = b2f(raw.z); dst[3] = b2f(raw.w);
  }
  __syncthreads();

  const int h = tid / (4 * S);
  const int r = tid - h * 4 * S;
  const int q = r >> 2, j = r & 3;
  if (q >= L) return;

  float qv[16];
  {
    const ushort* qp = QKVE + (i64)ids[q] * 768 + h * 64 + j * 16;
    cvt8(*(const uint4*)qp, qv);
    cvt8(*(const uint4*)(qp + 8), qv + 8);
  }

  float w[S];
  float mx = -1e30f;
#pragma unroll
  for (int s = 0; s < S; s++) {
    float p = -1e30f;
    if (s < L) {
      const float* kr = &KL[h][s][j * 16];
      p = 0.f;
#pragma unroll
      for (int e = 0; e < 4; e++) {
        const float4 kv = *(const float4*)(kr + e * 4);
        p = fmaf(qv[e * 4 + 0], kv.x, p);
        p = fmaf(qv[e * 4 + 1], kv.y, p);
        p = fmaf(qv[e * 4 + 2], kv.z, p);
        p = fmaf(qv[e * 4 + 3], kv.w, p);
      }
      p += __shfl_xor(p, 1, 64);
      p += __shfl_xor(p, 2, 64);
      p *= 0.125f;
    }
    w[s] = p;
    mx = fmaxf(mx, p);
  }
  float sum = 0.f;
#pragma unroll
  for (int s = 0; s < S; s++) { w[s] = __expf(w[s] - mx); sum += w[s]; }
  const float inv = 1.f / sum;

  float o[16];
#pragma unroll
  for (int e = 0; e < 16; e++) o[e] = 0.f;
#pragma unroll
  for (int s = 0; s < S; s++) {
    if (s < L) {
      const float ws = w[s];
      const float* vr = &VL[h][s][j * 16];
#pragma unroll
      for (int e = 0; e < 4; e++) {
        const float4 vv = *(const float4*)(vr + e * 4);
        o[e * 4 + 0] = fmaf(ws, vv.x, o[e * 4 + 0]);
        o[e * 4 + 1] = fmaf(ws, vv.y, o[e * 4 + 1]);
        o[e * 4 + 2] = fmaf(ws, vv.z, o[e * 4 + 2]);
        o[e * 4 + 3] = fmaf(ws, vv.w, o[e * 4 + 3]);
      }
    }
  }
  uint4 st0, st1;
  st0.x = pack2(o[0] * inv, o[1] * inv);   st0.y = pack2(o[2] * inv, o[3] * inv);
  st0.z = pack2(o[4] * inv, o[5] * inv);   st0.w = pack2(o[6] * inv, o[7] * inv);
  st1.x = pack2(o[8] * inv, o[9] * inv);   st1.y = pack2(o[10] * inv, o[11] * inv);
  st1.z = pack2(o[12] * inv, o[13] * inv); st1.w = pack2(o[14] * inv, o[15] * inv);
  ushort* op = O + (i64)(base + q) * 256 + h * 64 + j * 16;
  *(uint4*)op = st0;
  *(uint4*)(op + 8) = st1;
}

// ===== Layer-2 attention, CLS query ===========================================
template <int S>
__global__ __launch_bounds__(256) void attn_cls_k(const ushort* __restrict__ Qc,
                                                  const ushort* __restrict__ KV,
                                                  const int* __restrict__ ss,
                                                  ushort* __restrict__ Ocls) {
  const int tid = threadIdx.x;
  const int sl = tid >> 4, h = (tid >> 2) & 3, j = tid & 3;
  const int seq = blockIdx.x * 16 + sl;
  const int base = ss[seq] - ss[0];
  const int L = ss[seq + 1] - ss[seq];

  float qv[16];
  {
    const ushort* qp = Qc + (i64)seq * 256 + h * 64 + j * 16;
    cvt8(*(const uint4*)qp, qv);
    cvt8(*(const uint4*)(qp + 8), qv + 8);
  }
  float w[S];
  float mx = -1e30f;
#pragma unroll
  for (int s = 0; s < S; s++) {
    float p = -1e30f;
    if (s < L) {
      float kf[16];
      const ushort* kp = KV + (i64)(base + s) * 512 + h * 64 + j * 16;
      cvt8(*(const uint4*)kp, kf);
      cvt8(*(const uint4*)(kp + 8), kf + 8);
      p = 0.f;
#pragma unroll
      for (int e = 0; e < 16; e++) p = fmaf(qv[e], kf[e], p);
      p += __shfl_xor(p, 1, 64);
      p += __shfl_xor(p, 2, 64);
      p *= 0.125f;
    }
    w[s] = p;
    mx = fmaxf(mx, p);
  }
  float sum = 0.f;
#pragma unroll
  for (int s = 0; s < S; s++) { w[s] = __expf(w[s] - mx); sum += w[s]; }
  const float inv = 1.f / sum;

  float o[16];
#pragma unroll
  for (int e = 0; e < 16; e++) o[e] = 0.f;
#pragma unroll
  for (int s = 0; s < S; s++) {
    if (s < L) {
      float vf[16];
      const ushort* vp = KV + (i64)(base + s) * 512 + 256 + h * 64 + j * 16;
      cvt8(*(const uint4*)vp, vf);
      cvt8(*(const uint4*)(vp + 8), vf + 8);
      const float ws = w[s];
#pragma unroll
      for (int e = 0; e < 16; e++) o[e] = fmaf(ws, vf[e], o[e]);
    }
  }
  uint4 st0, st1;
  st0.x = pack2(o[0] * inv, o[1] * inv);   st0.y = pack2(o[2] * inv, o[3] * inv);
  st0.z = pack2(o[4] * inv, o[5] * inv);   st0.w = pack2(o[6] * inv, o[7] * inv);
  st1.x = pack2(o[8] * inv, o[9] * inv);   st1.y = pack2(o[10] * inv, o[11] * inv);
  st1.z = pack2(o[12] * inv, o[13] * inv); st1.w = pack2(o[14] * inv, o[15] * inv);
  ushort* op = Ocls + (i64)seq * 256 + h * 64 + j * 16;
  *(uint4*)op = st0;
  *(uint4*)(op + 8) = st1;
}

// ================= gathers / scatters / conversion =============================
__global__ __launch_bounds__(256) void f2b_cvt_k(const float* __restrict__ in,
                                                 ushort* __restrict__ out, int n) {
  for (int i = blockIdx.x * 256 + threadIdx.x; i < n; i += gridDim.x * 256)
    out[i] = f2b(in[i]);
}

__global__ __launch_bounds__(256) void gather_v2e_k(const float* __restrict__ unity,
                                                    const float* __restrict__ pos,
                                                    const int* __restrict__ xid,
                                                    const int* __restrict__ xpos,
                                                    const int* __restrict__ tok,
                                                    const int* __restrict__ ss, int nseq,
                                                    ushort* __restrict__ X) {
  const int t = blockIdx.x * 4 + (threadIdx.x >> 6);
  const int lane = threadIdx.x & 63;
  const int s0 = ss[0];
  if (t >= ss[nseq] - s0) return;
  const int code = tok[s0 + t];
  const int e = code >> 5, slot = code & 31;
  float4 v = make_float4(0.f, 0.f, 0.f, 0.f);
  if (slot > 0) {
    const int id = xid[(i64)e * ARITY + (slot - 1)];
    v = *(const float4*)&unity[(i64)id * 256 + lane * 4];
  }
  const int pp = xpos[(i64)e * SV + slot];
  const float4 pv = *(const float4*)&pos[(i64)pp * 256 + lane * 4];
  uint2 o;
  o.x = pack2(v.x + pv.x, v.y + pv.y);
  o.y = pack2(v.z + pv.z, v.w + pv.w);
  *(uint2*)&X[(i64)t * 256 + lane * 4] = o;
}

__global__ __launch_bounds__(256) void gather_e2v_k(const ushort* __restrict__ ext,
                                                    const int* __restrict__ hid,
                                                    const int* __restrict__ tok,
                                                    const int* __restrict__ ss, int nseq,
                                                    ushort* __restrict__ X,
                                                    int* __restrict__ gid) {
  const int t = blockIdx.x * 4 + (threadIdx.x >> 6);
  const int lane = threadIdx.x & 63;
  const int s0 = ss[0];
  if (t >= ss[nseq] - s0) return;
  const int code = tok[s0 + t];
  const int n = code >> 5, slot = code & 31;
  const int id = hid[(i64)n * SE + slot];
  if (lane == 0) gid[t] = id;
  *(uint2*)&X[(i64)t * 256 + lane * 4] =
      *(const uint2*)&ext[(i64)id * 256 + lane * 4];
}

__global__ __launch_bounds__(256) void scatter_k(const ushort* __restrict__ Xc,
                                                 const int* __restrict__ subg,
                                                 float* __restrict__ unity, int n0) {
  const int nl = blockIdx.x * 4 + (threadIdx.x >> 6);
  const int lane = threadIdx.x & 63;
  const int dst = subg[n0 + nl];
  ushort4 v = *(const ushort4*)&Xc[(i64)nl * 256 + lane * 4];
  float4 o; o.x = b2f(v.x); o.y = b2f(v.y); o.z = b2f(v.z); o.w = b2f(v.w);
  *(float4*)&unity[(i64)dst * 256 + lane * 4] = o;
}

__global__ __launch_bounds__(256) void ext_init_k(ushort* __restrict__ ext,
                                                  const float* __restrict__ pad,
                                                  const float* __restrict__ cls) {
  const int d = threadIdx.x;
  ext[(i64)NHEDGE * 256 + d] = f2b(pad[d]);
  ext[(i64)(NHEDGE + 1) * 256 + d] = f2b(cls[d]);
  // zero the padding rows so their QKV stays finite (never gathered anyway)
  for (int r = NHEDGE + 2; r < EXTROWS; r += 1)
    ext[(i64)r * 256 + d] = 0;
}

__global__ __launch_bounds__(256) void out_gather_k(const ushort* __restrict__ ext,
                                                    const int* __restrict__ pred,
                                                    float* __restrict__ out) {
  const int i = blockIdx.x * 4 + (threadIdx.x >> 6);
  const int lane = threadIdx.x & 63;
  const int e = pred[i];
  ushort4 v = *(const ushort4*)&ext[(i64)e * 256 + lane * 4];
  float4 o; o.x = b2f(v.x); o.y = b2f(v.y); o.z = b2f(v.z); o.w = b2f(v.w);
  *(float4*)&out[(i64)i * 256 + lane * 4] = o;
}

// ================= host orchestration ==========================================
extern "C" void kernel_launch(void* const* d_in, const int* in_sizes, int n_in,
                              void* d_out, int out_size, void* d_ws, size_t ws_size,
                              hipStream_t stream) {
  (void)in_sizes; (void)n_in; (void)out_size;
  const float* unity_in = (const float*)d_in[0];
  const float* cls_emb  = (const float*)d_in[1];
  const float* pad_emb  = (const float*)d_in[2];
  const float* pos_tab  = (const float*)d_in[3];
  const float* qkv_w    = (const float*)d_in[4];
  const float* qkv_b    = (const float*)d_in[5];
  const float* out_w    = (const float*)d_in[6];
  const float* out_b    = (const float*)d_in[7];
  const float* ln1_g    = (const float*)d_in[8];
  const float* ln1_b    = (const float*)d_in[9];
  const float* ln2_g    = (const float*)d_in[10];
  const float* ln2_b    = (const float*)d_in[11];
  const float* ff1_w    = (const float*)d_in[12];
  const float* ff1_b    = (const float*)d_in[13];
  const float* ff2_w    = (const float*)d_in[14];
  const float* ff2_b    = (const float*)d_in[15];
  const int* xid   = (const int*)d_in[16];
  const int* vmask = (const int*)d_in[17];
  const int* xpos  = (const int*)d_in[18];
  const int* hid   = (const int*)d_in[19];
  const int* hmask = (const int*)d_in[20];
  const int* subg  = (const int*)d_in[21];
  const int* pred  = (const int*)d_in[22];

  const i64 unity_b = (i64)NTOTAL * 256 * 4;
  const i64 ext_b   = (i64)EXTROWS * 256 * 2;
  const i64 qkvE_b  = (i64)EXTROWS * 768 * 2;  // 50.5 MB hedge-QKV table
  const int nq = 2 * 768 * 256, no = 2 * 256 * 256,
            n1 = 2 * 1024 * 256, n2 = 2 * 256 * 1024;
  const i64 wts_b = (i64)(nq + no + n1 + n2) * 2;
  const i64 idx_b = ((i64)NNODE + NHEDGE + 512 +
                     (NNODE + 1) + (NHEDGE + 1) +
                     (i64)NNODE * SE + (i64)NHEDGE * SV) * 4;
  const i64 per_elem = (i64)SE * (512 + 2048 + 512 + 4);  // X+Y+O+gid
  int CHUNK = 8192;
  while (CHUNK > 256 &&
         unity_b + ext_b + qkvE_b + wts_b + idx_b + (i64)CHUNK * per_elem > (i64)ws_size)
    CHUNK >>= 1;

  char* w = (char*)d_ws;
  float*  unity = (float*)w;  w += unity_b;
  ushort* ext   = (ushort*)w; w += ext_b;
  ushort* qkvE  = (ushort*)w; w += qkvE_b;
  ushort* wq    = (ushort*)w; w += (i64)nq * 2;
  ushort* wo    = (ushort*)w; w += (i64)no * 2;
  ushort* w1    = (ushort*)w; w += (i64)n1 * 2;
  ushort* w2    = (ushort*)w; w += (i64)n2 * 2;
  ushort* X     = (ushort*)w; w += (i64)CHUNK * SE * 256 * 2;
  ushort* Y     = (ushort*)w; w += (i64)CHUNK * SE * 1024 * 2;
  ushort* O     = (ushort*)w; w += (i64)CHUNK * SE * 256 * 2;
  int* gid   = (int*)w; w += (i64)CHUNK * SE * 4;
  int* cntE  = (int*)w; w += (i64)NNODE * 4;
  int* cntV  = (int*)w; w += (i64)NHEDGE * 4;
  int* partE = (int*)w; w += 256 * 4;
  int* partV = (int*)w; w += 256 * 4;
  int* ssE   = (int*)w; w += (i64)(NNODE + 1) * 4;
  int* ssV   = (int*)w; w += (i64)(NHEDGE + 1) * 4;
  int* tokE  = (int*)w; w += (i64)NNODE * SE * 4;
  int* tokV  = (int*)w; w += (i64)NHEDGE * SV * 4;
  ushort* Ocls = O;
  ushort* Qcls = O + (i64)CHUNK * 256;
  ushort* X2   = O + (i64)2 * CHUNK * 256;
  ushort* X3   = O + (i64)3 * CHUNK * 256;

  f2b_cvt_k<<<512, 256, 0, stream>>>(qkv_w, wq, nq);
  f2b_cvt_k<<<512, 256, 0, stream>>>(out_w, wo, no);
  f2b_cvt_k<<<512, 256, 0, stream>>>(ff1_w, w1, n1);
  f2b_cvt_k<<<512, 256, 0, stream>>>(ff2_w, w2, n2);
  hipMemcpyAsync(unity, unity_in, unity_b, hipMemcpyDeviceToDevice, stream);
  ext_init_k<<<1, 256, 0, stream>>>(ext, pad_emb, cls_emb);

  cnt_k<<<NHEDGE / 256, 256, 0, stream>>>(vmask, ARITY, 1, cntV, NHEDGE);
  scan1_k<<<NHEDGE / 256, 256, 0, stream>>>(cntV, ssV, partV, NHEDGE);
  scan2_k<<<1, 256, 0, stream>>>(partV, NHEDGE / 256, ssV, NHEDGE);
  scan3_k<<<NHEDGE / 256, 256, 0, stream>>>(ssV, partV, vmask, ARITY, 1, tokV, NHEDGE);
  cnt_k<<<NNODE / 256, 256, 0, stream>>>(hmask, SE, 0, cntE, NNODE);
  scan1_k<<<NNODE / 256, 256, 0, stream>>>(cntE, ssE, partE, NNODE);
  scan2_k<<<1, 256, 0, stream>>>(partE, NNODE / 256, ssE, NNODE);
  scan3_k<<<NNODE / 256, 256, 0, stream>>>(ssE, partE, hmask, SE, 0, tokE, NNODE);

  for (int k = 0; k <= 2; k++) {
    // ---- V2E ----
    for (int c = 0; c < NHEDGE / CHUNK; c++) {
      const int e0 = c * CHUNK;
      const int* ssc = ssV + e0;
      const int Mmax = CHUNK * SV;
      gather_v2e_k<<<Mmax / 4, 256, 0, stream>>>(unity, pos_tab, xid, xpos,
                                                 tokV, ssc, CHUNK, X);
      gemm_bf16_k<256, 1><<<dim3(6, Mmax / 128), 256, 0, stream>>>(
          X, wq, qkv_b, Y, Mmax, 768, ssc, CHUNK, nullptr);
      attn1_k<SV><<<CHUNK, 16 * SV, 0, stream>>>(Y, ssc, O);
      gemm_ln_k<256><<<Mmax / 128, 512, 0, stream>>>(
          O, wo, out_b, X, 256, ln1_g, ln1_b, X, 256, Mmax, ssc, CHUNK, nullptr);
      gemm_bf16_k<256, 2><<<dim3(8, Mmax / 128), 256, 0, stream>>>(
          X, w1, ff1_b, Y, Mmax, 1024, ssc, CHUNK, nullptr);
      gemm_ln_k<1024><<<Mmax / 128, 512, 0, stream>>>(
          Y, w2, ff2_b, X, 256, ln2_g, ln2_b, X, 256, Mmax, ssc, CHUNK, nullptr);
      gemm_bf16_k<256, 1><<<dim3(4, Mmax / 128), 256, 0, stream>>>(
          X, wq + (i64)768 * 256 + (i64)256 * 256, qkv_b + 768 + 256,
          Y, Mmax, 512, ssc, CHUNK, nullptr);
      gemm_bf16_k<256, 1><<<dim3(2, CHUNK / 128), 256, 0, stream>>>(
          X, wq + (i64)768 * 256, qkv_b + 768, Qcls, CHUNK, 256,
          nullptr, 0, ssc);
      attn_cls_k<SV><<<CHUNK / 16, 256, 0, stream>>>(Qcls, Y, ssc, Ocls);
      gemm_ln_k<256><<<CHUNK / 128, 512, 0, stream>>>(
          Ocls, wo + (i64)256 * 256, out_b + 256, X, 256,
          ln1_g + 256, ln1_b + 256, X2, 256, CHUNK, nullptr, 0, ssc);
      gemm_bf16_k<256, 2><<<dim3(8, CHUNK / 128), 256, 0, stream>>>(
          X2, w1 + (i64)1024 * 256, ff1_b + 1024, Y, CHUNK, 1024,
          nullptr, 0, nullptr);
      gemm_ln_k<1024><<<CHUNK / 128, 512, 0, stream>>>(
          Y, w2 + (i64)256 * 1024, ff2_b + 256, X2, 256,
          ln2_g + 256, ln2_b + 256, ext + (i64)e0 * 256, 256, CHUNK,
          nullptr, 0, nullptr);
    }
    // ---- E2V ----
    if (k < 2) {
      // hedge-QKV dedup: QKV(ext[hid]) == (ext @ Wqkv + b)[hid]
      gemm_bf16_k<256, 1><<<dim3(6, EXTROWS / 128), 256, 0, stream>>>(
          ext, wq, qkv_b, qkvE, EXTROWS, 768, nullptr, 0, nullptr);
      for (int c = 0; c < NNODE / CHUNK; c++) {
        const int n0 = c * CHUNK;
        const int* ssc = ssE + n0;
        const int Mmax = CHUNK * SE;
        gather_e2v_k<<<Mmax / 4, 256, 0, stream>>>(ext, hid, tokE, ssc, CHUNK, X, gid);
        attn1g_k<SE><<<CHUNK, 16 * SE, 0, stream>>>(qkvE, gid, ssc, O);
        gemm_ln_k<256><<<Mmax / 128, 512, 0, stream>>>(
            O, wo, out_b, X, 256, ln1_g, ln1_b, X, 256, Mmax, ssc, CHUNK, nullptr);
        gemm_bf16_k<256, 2><<<dim3(8, Mmax / 128), 256, 0, stream>>>(
            X, w1, ff1_b, Y, Mmax, 1024, ssc, CHUNK, nullptr);
        gemm_ln_k<1024><<<Mmax / 128, 512, 0, stream>>>(
            Y, w2, ff2_b, X, 256, ln2_g, ln2_b, X, 256, Mmax, ssc, CHUNK, nullptr);
        gemm_bf16_k<256, 1><<<dim3(4, Mmax / 128), 256, 0, stream>>>(
            X, wq + (i64)768 * 256 + (i64)256 * 256, qkv_b + 768 + 256,
            Y, Mmax, 512, ssc, CHUNK, nullptr);
        gemm_bf16_k<256, 1><<<dim3(2, CHUNK / 128), 256, 0, stream>>>(
            X, wq + (i64)768 * 256, qkv_b + 768, Qcls, CHUNK, 256,
            nullptr, 0, ssc);
        attn_cls_k<SE><<<CHUNK / 16, 256, 0, stream>>>(Qcls, Y, ssc, Ocls);
        gemm_ln_k<256><<<CHUNK / 128, 512, 0, stream>>>(
            Ocls, wo + (i64)256 * 256, out_b + 256, X, 256,
            ln1_g + 256, ln1_b + 256, X2, 256, CHUNK, nullptr, 0, ssc);
        gemm_bf16_k<256, 2><<<dim3(8, CHUNK / 128), 256, 0, stream>>>(
            X2, w1 + (i64)1024 * 256, ff1_b + 1024, Y, CHUNK, 1024,
            nullptr, 0, nullptr);
        gemm_ln_k<1024><<<CHUNK / 128, 512, 0, stream>>>(
            Y, w2 + (i64)256 * 1024, ff2_b + 256, X2, 256,
            ln2_g + 256, ln2_b + 256, X3, 256, CHUNK, nullptr, 0, nullptr);
        scatter_k<<<CHUNK / 4, 256, 0, stream>>>(X3, subg, unity, n0);
      }
    }
  }
  out_gather_k<<<64, 256, 0, stream>>>(ext, pred, (float*)d_out);
}

// Round 11
// 15845.140 us; speedup vs baseline: 1.6477x; 1.1427x over previous
//
#include <hip/hip_runtime.h>
#include <stdint.h>

typedef long long i64;
typedef __attribute__((ext_vector_type(8))) short bf16x8;
typedef __attribute__((ext_vector_type(4))) float f32x4;

#define SV 11
#define SE 17
#define ARITY 10
#define NHEDGE 32768
#define NNODE 65536
#define NTOTAL 100000
#define EXTROWS 32896  // NHEDGE+2 padded to 128 multiple
#define NPRED 256
#define MPRED 2816     // NPRED * SV

__device__ __forceinline__ float b2f(ushort u) {
  union { uint32_t i; float f; } v; v.i = (uint32_t)u << 16; return v.f;
}
__device__ __forceinline__ ushort f2b(float f) {
  union { float f; uint32_t i; } v; v.f = f;
  uint32_t u = v.i + 0x7fffu + ((v.i >> 16) & 1u);
  return (ushort)(u >> 16);
}
__device__ __forceinline__ uint pack2(float a, float b) {
  return (uint)f2b(a) | ((uint)f2b(b) << 16);
}
__device__ __forceinline__ void cvt8(uint4 v, float* f) {
  f[0] = b2f((ushort)(v.x & 0xffff)); f[1] = b2f((ushort)(v.x >> 16));
  f[2] = b2f((ushort)(v.y & 0xffff)); f[3] = b2f((ushort)(v.y >> 16));
  f[4] = b2f((ushort)(v.z & 0xffff)); f[5] = b2f((ushort)(v.z >> 16));
  f[6] = b2f((ushort)(v.w & 0xffff)); f[7] = b2f((ushort)(v.w >> 16));
}

__device__ __forceinline__ void gload_lds16(const void* g, void* l) {
  __builtin_amdgcn_global_load_lds((const __attribute__((address_space(1))) void*)g,
                                   (__attribute__((address_space(3))) void*)l, 16, 0, 0);
}

__device__ __forceinline__ int xcd_swizzle(int orig, int nwg) {
  const int xcd = orig & 7, rest = orig >> 3;
  const int q = nwg >> 3, r = nwg & 7;
  return (xcd < r ? xcd * (q + 1) : r * (q + 1) + (xcd - r) * q) + rest;
}

// ================= compaction: count / scan / fill =============================
__global__ __launch_bounds__(256) void cnt_k(const int* __restrict__ mask, int width,
                                             int extra, int* __restrict__ cnt, int n) {
  const int i = blockIdx.x * 256 + threadIdx.x;
  if (i >= n) return;
  int c = extra;
  for (int j = 0; j < width; j++) c += (mask[(i64)i * width + j] != 0);
  cnt[i] = c;
}

__global__ __launch_bounds__(256) void scan1_k(const int* __restrict__ cnt,
                                               int* __restrict__ ss,
                                               int* __restrict__ part, int n) {
  __shared__ int sm[256];
  const int i = blockIdx.x * 256 + threadIdx.x;
  const int v = (i < n) ? cnt[i] : 0;
  sm[threadIdx.x] = v;
  __syncthreads();
  for (int o = 1; o < 256; o <<= 1) {
    const int t = (threadIdx.x >= o) ? sm[threadIdx.x - o] : 0;
    __syncthreads();
    sm[threadIdx.x] += t;
    __syncthreads();
  }
  if (i < n) ss[i] = sm[threadIdx.x] - v;  // exclusive
  if (threadIdx.x == 255) part[blockIdx.x] = sm[255];
}

__global__ __launch_bounds__(256) void scan2_k(int* __restrict__ part, int nb,
                                               int* __restrict__ ss, int n) {
  __shared__ int sm[256];
  const int v = (threadIdx.x < nb) ? part[threadIdx.x] : 0;
  sm[threadIdx.x] = v;
  __syncthreads();
  for (int o = 1; o < 256; o <<= 1) {
    const int t = (threadIdx.x >= o) ? sm[threadIdx.x - o] : 0;
    __syncthreads();
    sm[threadIdx.x] += t;
    __syncthreads();
  }
  if (threadIdx.x < nb) part[threadIdx.x] = sm[threadIdx.x] - v;
  if (threadIdx.x == 255) ss[n] = sm[255];
}

__global__ __launch_bounds__(256) void scan3_k(int* __restrict__ ss,
                                               const int* __restrict__ part,
                                               const int* __restrict__ mask, int width,
                                               int extra, int* __restrict__ tok, int n) {
  const int i = blockIdx.x * 256 + threadIdx.x;
  if (i >= n) return;
  int off = ss[i] + part[blockIdx.x];
  ss[i] = off;
  if (extra) {
    tok[off++] = (i << 5);
    for (int j = 0; j < width; j++)
      if (mask[(i64)i * width + j] != 0) tok[off++] = (i << 5) | (j + 1);
  } else {
    for (int j = 0; j < width; j++)
      if (mask[(i64)i * width + j] != 0) tok[off++] = (i << 5) | j;
  }
}

// ===== pred-pass compaction: 256 predicted edges, single block ================
__global__ __launch_bounds__(256) void predscan_k(const int* __restrict__ pred,
                                                  const int* __restrict__ cntV,
                                                  const int* __restrict__ vmask,
                                                  int* __restrict__ ssP,
                                                  int* __restrict__ tokP) {
  __shared__ int sm[256];
  const int tid = threadIdx.x;
  const int e = pred[tid];
  const int v = cntV[e];
  sm[tid] = v;
  __syncthreads();
  for (int o = 1; o < 256; o <<= 1) {
    const int t = (tid >= o) ? sm[tid - o] : 0;
    __syncthreads();
    sm[tid] += t;
    __syncthreads();
  }
  int off = sm[tid] - v;  // exclusive
  ssP[tid] = off;
  if (tid == 255) ssP[256] = sm[255];
  tokP[off++] = (e << 5);
  for (int j = 0; j < ARITY; j++)
    if (vmask[(i64)e * ARITY + j] != 0) tokP[off++] = (e << 5) | (j + 1);
}

// ================= 128x128 bf16 MFMA GEMM =====================================
template <int K, int MODE>
__global__ __launch_bounds__(256) void gemm_bf16_k(const ushort* __restrict__ A,
                                                   const ushort* __restrict__ W,
                                                   const float* __restrict__ bias,
                                                   ushort* __restrict__ C, int M, int N,
                                                   const int* ssn, int nseq,
                                                   const int* arp) {
  const int tid = threadIdx.x;
  const int wave = tid >> 6, lane = tid & 63;
  const int nwg = gridDim.x * gridDim.y;
  const int wg = xcd_swizzle(blockIdx.y * gridDim.x + blockIdx.x, nwg);
  const int bx = wg % gridDim.x, by = wg / gridDim.x;
  const int m0 = by << 7, n0 = bx << 7;
  if (ssn && m0 >= ssn[nseq] - ssn[0]) return;
  __shared__ ushort As[128 * 64];
  __shared__ ushort Ws[128 * 64];
  const int wr = wave >> 1, wc = wave & 1;

  f32x4 acc[4][4];
#pragma unroll
  for (int m = 0; m < 4; m++)
#pragma unroll
    for (int n = 0; n < 4; n++) acc[m][n] = (f32x4){0.f, 0.f, 0.f, 0.f};

  const int srow = (wave << 5) + (lane >> 3);
  const int kblk_g = (lane & 7) ^ (lane >> 3);
  const i64 arow = arp ? (i64)(arp[m0 + srow] - arp[0]) : (i64)(m0 + srow);
  const ushort* Ag = A + arow * K + (kblk_g << 3);
  const ushort* Wg = W + (i64)(n0 + srow) * K + (kblk_g << 3);
  char* lA = (char*)As + (wave << 12);
  char* lB = (char*)Ws + (wave << 12);

#pragma unroll
  for (int i = 0; i < 4; i++) {
    gload_lds16(Ag + (i64)(i * 8) * K, lA + i * 1024);
    gload_lds16(Wg + (i64)(i * 8) * K, lB + i * 1024);
  }

  for (int k0 = 0; k0 < K; k0 += 64) {
    __syncthreads();
    bf16x8 af[2][4], bf[2][4];
#pragma unroll
    for (int kh = 0; kh < 2; kh++) {
      const int kb = (kh << 2) + (lane >> 4);
#pragma unroll
      for (int m = 0; m < 4; m++) {
        const int row = (wr << 6) + (m << 4) + (lane & 15);
        af[kh][m] = *(const bf16x8*)&As[row * 64 + ((kb ^ (row & 7)) << 3)];
      }
#pragma unroll
      for (int n = 0; n < 4; n++) {
        const int row = (wc << 6) + (n << 4) + (lane & 15);
        bf[kh][n] = *(const bf16x8*)&Ws[row * 64 + ((kb ^ (row & 7)) << 3)];
      }
    }
    __syncthreads();
    if (k0 + 64 < K) {
#pragma unroll
      for (int i = 0; i < 4; i++) {
        gload_lds16(Ag + (k0 + 64) + (i64)(i * 8) * K, lA + i * 1024);
        gload_lds16(Wg + (k0 + 64) + (i64)(i * 8) * K, lB + i * 1024);
      }
    }
#pragma unroll
    for (int kh = 0; kh < 2; kh++)
#pragma unroll
      for (int m = 0; m < 4; m++)
#pragma unroll
        for (int n = 0; n < 4; n++)
          acc[m][n] = __builtin_amdgcn_mfma_f32_16x16x32_bf16(bf[kh][n], af[kh][m], acc[m][n], 0, 0, 0);
  }

#pragma unroll
  for (int m = 0; m < 4; m++) {
    const int row = m0 + (wr << 6) + (m << 4) + (lane & 15);
#pragma unroll
    for (int n = 0; n < 4; n++) {
      const int col = n0 + (wc << 6) + (n << 4) + ((lane >> 4) << 2);
      float v0 = acc[m][n][0], v1 = acc[m][n][1], v2 = acc[m][n][2], v3 = acc[m][n][3];
      if (MODE > 0) {
        const f32x4 bv = *(const f32x4*)&bias[col];
        v0 += bv[0]; v1 += bv[1]; v2 += bv[2]; v3 += bv[3];
      }
      if (MODE == 2) {
        v0 = fmaxf(v0, 0.f); v1 = fmaxf(v1, 0.f);
        v2 = fmaxf(v2, 0.f); v3 = fmaxf(v3, 0.f);
      }
      uint2 o; o.x = pack2(v0, v1); o.y = pack2(v2, v3);
      *(uint2*)&C[(i64)row * N + col] = o;
    }
  }
}

// ============ Fused GEMM + residual + LayerNorm (N = 256) ======================
template <int K>
__global__ __launch_bounds__(512) void gemm_ln_k(const ushort* __restrict__ A,
                                                 const ushort* __restrict__ W,
                                                 const float* __restrict__ bias,
                                                 const ushort* R, int rstride,
                                                 const float* __restrict__ g,
                                                 const float* __restrict__ b,
                                                 ushort* C, int cstride, int M,
                                                 const int* ssn, int nseq,
                                                 const int* rrp) {
  const int m0 = blockIdx.x << 7;
  if (ssn && m0 >= ssn[nseq] - ssn[0]) return;
  __shared__ ushort As[128 * 64];
  __shared__ ushort Ws[256 * 64];
  __shared__ float partS[128][4];
  __shared__ float partQ[128][4];
  const int tid = threadIdx.x;
  const int wave = tid >> 6, lane = tid & 63;
  const int wr = wave >> 2, wc = wave & 3;

  f32x4 acc[4][4];
#pragma unroll
  for (int m = 0; m < 4; m++)
#pragma unroll
    for (int n = 0; n < 4; n++) acc[m][n] = (f32x4){0.f, 0.f, 0.f, 0.f};

  int rowA[2], kgA[2];
#pragma unroll
  for (int i = 0; i < 2; i++) {
    const int u = wave * 128 + i * 64 + lane;
    rowA[i] = u >> 3; kgA[i] = (u & 7) ^ ((u >> 3) & 7);
  }
  int rowW[4], kgW[4];
#pragma unroll
  for (int i = 0; i < 4; i++) {
    const int u = wave * 256 + i * 64 + lane;
    rowW[i] = u >> 3; kgW[i] = (u & 7) ^ ((u >> 3) & 7);
  }

#pragma unroll
  for (int i = 0; i < 2; i++)
    gload_lds16(A + (i64)(m0 + rowA[i]) * K + (kgA[i] << 3),
                (char*)As + (wave * 128 + i * 64) * 16);
#pragma unroll
  for (int i = 0; i < 4; i++)
    gload_lds16(W + (i64)rowW[i] * K + (kgW[i] << 3),
                (char*)Ws + (wave * 256 + i * 64) * 16);

  for (int k0 = 0; k0 < K; k0 += 64) {
    __syncthreads();
    bf16x8 af[2][4], bf[2][4];
#pragma unroll
    for (int kh = 0; kh < 2; kh++) {
      const int kb = (kh << 2) + (lane >> 4);
#pragma unroll
      for (int m = 0; m < 4; m++) {
        const int row = (wr << 6) + (m << 4) + (lane & 15);
        af[kh][m] = *(const bf16x8*)&As[row * 64 + ((kb ^ (row & 7)) << 3)];
      }
#pragma unroll
      for (int n = 0; n < 4; n++) {
        const int row = (wc << 6) + (n << 4) + (lane & 15);
        bf[kh][n] = *(const bf16x8*)&Ws[row * 64 + ((kb ^ (row & 7)) << 3)];
      }
    }
    __syncthreads();
    if (k0 + 64 < K) {
#pragma unroll
      for (int i = 0; i < 2; i++)
        gload_lds16(A + (i64)(m0 + rowA[i]) * K + (k0 + 64) + (kgA[i] << 3),
                    (char*)As + (wave * 128 + i * 64) * 16);
#pragma unroll
      for (int i = 0; i < 4; i++)
        gload_lds16(W + (i64)rowW[i] * K + (k0 + 64) + (kgW[i] << 3),
                    (char*)Ws + (wave * 256 + i * 64) * 16);
    }
#pragma unroll
    for (int kh = 0; kh < 2; kh++)
#pragma unroll
      for (int m = 0; m < 4; m++)
#pragma unroll
        for (int n = 0; n < 4; n++)
          acc[m][n] = __builtin_amdgcn_mfma_f32_16x16x32_bf16(bf[kh][n], af[kh][m], acc[m][n], 0, 0, 0);
  }

#pragma unroll
  for (int m = 0; m < 4; m++) {
    const int tokl = (wr << 6) + (m << 4) + (lane & 15);
    const int row = m0 + tokl;
    const i64 rr = rrp ? (i64)(rrp[row] - rrp[0]) : (i64)row;
    float s = 0.f, q = 0.f;
#pragma unroll
    for (int n = 0; n < 4; n++) {
      const int col = (wc << 6) + (n << 4) + ((lane >> 4) << 2);
      const f32x4 bv = *(const f32x4*)&bias[col];
      const uint2 ru = *(const uint2*)&R[rr * rstride + col];
      float v0 = acc[m][n][0] + bv[0] + b2f((ushort)(ru.x & 0xffff));
      float v1 = acc[m][n][1] + bv[1] + b2f((ushort)(ru.x >> 16));
      float v2 = acc[m][n][2] + bv[2] + b2f((ushort)(ru.y & 0xffff));
      float v3 = acc[m][n][3] + bv[3] + b2f((ushort)(ru.y >> 16));
      acc[m][n][0] = v0; acc[m][n][1] = v1; acc[m][n][2] = v2; acc[m][n][3] = v3;
      s += v0 + v1 + v2 + v3;
      q += v0 * v0 + v1 * v1 + v2 * v2 + v3 * v3;
    }
    s += __shfl_xor(s, 16, 64); s += __shfl_xor(s, 32, 64);
    q += __shfl_xor(q, 16, 64); q += __shfl_xor(q, 32, 64);
    if (lane < 16) { partS[tokl][wc] = s; partQ[tokl][wc] = q; }
  }
  __syncthreads();
#pragma unroll
  for (int m = 0; m < 4; m++) {
    const int tokl = (wr << 6) + (m << 4) + (lane & 15);
    const i64 row = (i64)(m0 + tokl);
    const f32x4 s4 = *(const f32x4*)&partS[tokl][0];
    const f32x4 q4 = *(const f32x4*)&partQ[tokl][0];
    const float mean = (s4[0] + s4[1] + s4[2] + s4[3]) * (1.f / 256.f);
    const float var = (q4[0] + q4[1] + q4[2] + q4[3]) * (1.f / 256.f) - mean * mean;
    const float rs = rsqrtf(var + 1e-5f);
#pragma unroll
    for (int n = 0; n < 4; n++) {
      const int col = (wc << 6) + (n << 4) + ((lane >> 4) << 2);
      const f32x4 g4 = *(const f32x4*)&g[col];
      const f32x4 b4 = *(const f32x4*)&b[col];
      uint2 o;
      o.x = pack2((acc[m][n][0] - mean) * rs * g4[0] + b4[0],
                  (acc[m][n][1] - mean) * rs * g4[1] + b4[1]);
      o.y = pack2((acc[m][n][2] - mean) * rs * g4[2] + b4[2],
                  (acc[m][n][3] - mean) * rs * g4[3] + b4[3]);
      *(uint2*)&C[row * cstride + col] = o;
    }
  }
}

// ========= Layer-1 attention (compact, from per-token QKV rows) ===============
template <int S>
__global__ __launch_bounds__(16 * S) void attn1_k(const ushort* __restrict__ QKV,
                                                  const int* __restrict__ ss,
                                                  ushort* __restrict__ O) {
  __shared__ float KL[4][S][68];
  __shared__ float VL[4][S][68];
  const int tid = threadIdx.x;
  const int s0 = ss[0];
  const int base = ss[blockIdx.x] - s0;
  const int L = ss[blockIdx.x + 1] - ss[blockIdx.x];

  for (int u = tid; u < 128 * L; u += 16 * S) {
    const int d4 = u & 15, h = (u >> 4) & 3, mt = u >> 6;
    const int mat = (mt >= L), t = mat ? mt - L : mt;
    const ushort* gp = QKV + (i64)(base + t) * 768 + 256 + mat * 256 + h * 64 + d4 * 4;
    ushort4 raw = *(const ushort4*)gp;
    float* dst = (mat ? &VL[h][t][0] : &KL[h][t][0]) + d4 * 4;
    dst[0] = b2f(raw.x); dst[1] = b2f(raw.y); dst[2] = b2f(raw.z); dst[3] = b2f(raw.w);
  }
  __syncthreads();

  const int h = tid / (4 * S);
  const int r = tid - h * 4 * S;
  const int q = r >> 2, j = r & 3;
  if (q >= L) return;

  float qv[16];
  {
    const ushort* qp = QKV + (i64)(base + q) * 768 + h * 64 + j * 16;
    cvt8(*(const uint4*)qp, qv);
    cvt8(*(const uint4*)(qp + 8), qv + 8);
  }

  float w[S];
  float mx = -1e30f;
#pragma unroll
  for (int s = 0; s < S; s++) {
    float p = -1e30f;
    if (s < L) {
      const float* kr = &KL[h][s][j * 16];
      p = 0.f;
#pragma unroll
      for (int e = 0; e < 4; e++) {
        const float4 kv = *(const float4*)(kr + e * 4);
        p = fmaf(qv[e * 4 + 0], kv.x, p);
        p = fmaf(qv[e * 4 + 1], kv.y, p);
        p = fmaf(qv[e * 4 + 2], kv.z, p);
        p = fmaf(qv[e * 4 + 3], kv.w, p);
      }
      p += __shfl_xor(p, 1, 64);
      p += __shfl_xor(p, 2, 64);
      p *= 0.125f;
    }
    w[s] = p;
    mx = fmaxf(mx, p);
  }
  float sum = 0.f;
#pragma unroll
  for (int s = 0; s < S; s++) { w[s] = __expf(w[s] - mx); sum += w[s]; }
  const float inv = 1.f / sum;

  float o[16];
#pragma unroll
  for (int e = 0; e < 16; e++) o[e] = 0.f;
#pragma unroll
  for (int s = 0; s < S; s++) {
    if (s < L) {
      const float ws = w[s];
      const float* vr = &VL[h][s][j * 16];
#pragma unroll
      for (int e = 0; e < 4; e++) {
        const float4 vv = *(const float4*)(vr + e * 4);
        o[e * 4 + 0] = fmaf(ws, vv.x, o[e * 4 + 0]);
        o[e * 4 + 1] = fmaf(ws, vv.y, o[e * 4 + 1]);
        o[e * 4 + 2] = fmaf(ws, vv.z, o[e * 4 + 2]);
        o[e * 4 + 3] = fmaf(ws, vv.w, o[e * 4 + 3]);
      }
    }
  }
  uint4 st0, st1;
  st0.x = pack2(o[0] * inv, o[1] * inv);   st0.y = pack2(o[2] * inv, o[3] * inv);
  st0.z = pack2(o[4] * inv, o[5] * inv);   st0.w = pack2(o[6] * inv, o[7] * inv);
  st1.x = pack2(o[8] * inv, o[9] * inv);   st1.y = pack2(o[10] * inv, o[11] * inv);
  st1.z = pack2(o[12] * inv, o[13] * inv); st1.w = pack2(o[14] * inv, o[15] * inv);
  ushort* op = O + (i64)(base + q) * 256 + h * 64 + j * 16;
  *(uint4*)op = st0;
  *(uint4*)(op + 8) = st1;
}

// ========= Layer-1 attention, E2V: QKV gathered from hedge table ==============
template <int S>
__global__ __launch_bounds__(16 * S) void attn1g_k(const ushort* __restrict__ QKVE,
                                                   const int* __restrict__ gid,
                                                   const int* __restrict__ ss,
                                                   ushort* __restrict__ O) {
  __shared__ float KL[4][S][68];
  __shared__ float VL[4][S][68];
  __shared__ int ids[S];
  const int tid = threadIdx.x;
  const int s0 = ss[0];
  const int base = ss[blockIdx.x] - s0;
  const int L = ss[blockIdx.x + 1] - ss[blockIdx.x];

  if (tid < L) ids[tid] = gid[base + tid];
  __syncthreads();

  for (int u = tid; u < 128 * L; u += 16 * S) {
    const int d4 = u & 15, h = (u >> 4) & 3, mt = u >> 6;
    const int mat = (mt >= L), t = mat ? mt - L : mt;
    const ushort* gp = QKVE + (i64)ids[t] * 768 + 256 + mat * 256 + h * 64 + d4 * 4;
    ushort4 raw = *(const ushort4*)gp;
    float* dst = (mat ? &VL[h][t][0] : &KL[h][t][0]) + d4 * 4;
    dst[0] = b2f(raw.x); dst[1] = b2f(raw.y); dst[2] = b2f(raw.z); dst[3] = b2f(raw.w);
  }
  __syncthreads();

  const int h = tid / (4 * S);
  const int r = tid - h * 4 * S;
  const int q = r >> 2, j = r & 3;
  if (q >= L) return;

  float qv[16];
  {
    const ushort* qp = QKVE + (i64)ids[q] * 768 + h * 64 + j * 16;
    cvt8(*(const uint4*)qp, qv);
    cvt8(*(const uint4*)(qp + 8), qv + 8);
  }

  float w[S];
  float mx = -1e30f;
#pragma unroll
  for (int s = 0; s < S; s++) {
    float p = -1e30f;
    if (s < L) {
      const float* kr = &KL[h][s][j * 16];
      p = 0.f;
#pragma unroll
      for (int e = 0; e < 4; e++) {
        const float4 kv = *(const float4*)(kr + e * 4);
        p = fmaf(qv[e * 4 + 0], kv.x, p);
        p = fmaf(qv[e * 4 + 1], kv.y, p);
        p = fmaf(qv[e * 4 + 2], kv.z, p);
        p = fmaf(qv[e * 4 + 3], kv.w, p);
      }
      p += __shfl_xor(p, 1, 64);
      p += __shfl_xor(p, 2, 64);
      p *= 0.125f;
    }
    w[s] = p;
    mx = fmaxf(mx, p);
  }
  float sum = 0.f;
#pragma unroll
  for (int s = 0; s < S; s++) { w[s] = __expf(w[s] - mx); sum += w[s]; }
  const float inv = 1.f / sum;

  float o[16];
#pragma unroll
  for (int e = 0; e < 16; e++) o[e] = 0.f;
#pragma unroll
  for (int s = 0; s < S; s++) {
    if (s < L) {
      const float ws = w[s];
      const float* vr = &VL[h][s][j * 16];
#pragma unroll
      for (int e = 0; e < 4; e++) {
        const float4 vv = *(const float4*)(vr + e * 4);
        o[e * 4 + 0] = fmaf(ws, vv.x, o[e * 4 + 0]);
        o[e * 4 + 1] = fmaf(ws, vv.y, o[e * 4 + 1]);
        o[e * 4 + 2] = fmaf(ws, vv.z, o[e * 4 + 2]);
        o[e * 4 + 3] = fmaf(ws, vv.w, o[e * 4 + 3]);
      }
    }
  }
  uint4 st0, st1;
  st0.x = pack2(o[0] * inv, o[1] * inv);   st0.y = pack2(o[2] * inv, o[3] * inv);
  st0.z = pack2(o[4] * inv, o[5] * inv);   st0.w = pack2(o[6] * inv, o[7] * inv);
  st1.x = pack2(o[8] * inv, o[9] * inv);   st1.y = pack2(o[10] * inv, o[11] * inv);
  st1.z = pack2(o[12] * inv, o[13] * inv); st1.w = pack2(o[14] * inv, o[15] * inv);
  ushort* op = O + (i64)(base + q) * 256 + h * 64 + j * 16;
  *(uint4*)op = st0;
  *(uint4*)(op + 8) = st1;
}

// ===== Layer-2 attention, CLS query ===========================================
template <int S>
__global__ __launch_bounds__(256) void attn_cls_k(const ushort* __restrict__ Qc,
                                                  const ushort* __restrict__ KV,
                                                  const int* __restrict__ ss,
                                                  ushort* __restrict__ Ocls) {
  const int tid = threadIdx.x;
  const int sl = tid >> 4, h = (tid >> 2) & 3, j = tid & 3;
  const int seq = blockIdx.x * 16 + sl;
  const int base = ss[seq] - ss[0];
  const int L = ss[seq + 1] - ss[seq];

  float qv[16];
  {
    const ushort* qp = Qc + (i64)seq * 256 + h * 64 + j * 16;
    cvt8(*(const uint4*)qp, qv);
    cvt8(*(const uint4*)(qp + 8), qv + 8);
  }
  float w[S];
  float mx = -1e30f;
#pragma unroll
  for (int s = 0; s < S; s++) {
    float p = -1e30f;
    if (s < L) {
      float kf[16];
      const ushort* kp = KV + (i64)(base + s) * 512 + h * 64 + j * 16;
      cvt8(*(const uint4*)kp, kf);
      cvt8(*(const uint4*)(kp + 8), kf + 8);
      p = 0.f;
#pragma unroll
      for (int e = 0; e < 16; e++) p = fmaf(qv[e], kf[e], p);
      p += __shfl_xor(p, 1, 64);
      p += __shfl_xor(p, 2, 64);
      p *= 0.125f;
    }
    w[s] = p;
    mx = fmaxf(mx, p);
  }
  float sum = 0.f;
#pragma unroll
  for (int s = 0; s < S; s++) { w[s] = __expf(w[s] - mx); sum += w[s]; }
  const float inv = 1.f / sum;

  float o[16];
#pragma unroll
  for (int e = 0; e < 16; e++) o[e] = 0.f;
#pragma unroll
  for (int s = 0; s < S; s++) {
    if (s < L) {
      float vf[16];
      const ushort* vp = KV + (i64)(base + s) * 512 + 256 + h * 64 + j * 16;
      cvt8(*(const uint4*)vp, vf);
      cvt8(*(const uint4*)(vp + 8), vf + 8);
      const float ws = w[s];
#pragma unroll
      for (int e = 0; e < 16; e++) o[e] = fmaf(ws, vf[e], o[e]);
    }
  }
  uint4 st0, st1;
  st0.x = pack2(o[0] * inv, o[1] * inv);   st0.y = pack2(o[2] * inv, o[3] * inv);
  st0.z = pack2(o[4] * inv, o[5] * inv);   st0.w = pack2(o[6] * inv, o[7] * inv);
  st1.x = pack2(o[8] * inv, o[9] * inv);   st1.y = pack2(o[10] * inv, o[11] * inv);
  st1.z = pack2(o[12] * inv, o[13] * inv); st1.w = pack2(o[14] * inv, o[15] * inv);
  ushort* op = Ocls + (i64)seq * 256 + h * 64 + j * 16;
  *(uint4*)op = st0;
  *(uint4*)(op + 8) = st1;
}

// ================= gathers / scatters / conversion =============================
__global__ __launch_bounds__(256) void f2b_cvt_k(const float* __restrict__ in,
                                                 ushort* __restrict__ out, int n) {
  for (int i = blockIdx.x * 256 + threadIdx.x; i < n; i += gridDim.x * 256)
    out[i] = f2b(in[i]);
}

__global__ __launch_bounds__(256) void gather_v2e_k(const float* __restrict__ unity,
                                                    const float* __restrict__ pos,
                                                    const int* __restrict__ xid,
                                                    const int* __restrict__ xpos,
                                                    const int* __restrict__ tok,
                                                    const int* __restrict__ ss, int nseq,
                                                    ushort* __restrict__ X) {
  const int t = blockIdx.x * 4 + (threadIdx.x >> 6);
  const int lane = threadIdx.x & 63;
  const int s0 = ss[0];
  if (t >= ss[nseq] - s0) return;
  const int code = tok[s0 + t];
  const int e = code >> 5, slot = code & 31;
  float4 v = make_float4(0.f, 0.f, 0.f, 0.f);
  if (slot > 0) {
    const int id = xid[(i64)e * ARITY + (slot - 1)];
    v = *(const float4*)&unity[(i64)id * 256 + lane * 4];
  }
  const int pp = xpos[(i64)e * SV + slot];
  const float4 pv = *(const float4*)&pos[(i64)pp * 256 + lane * 4];
  uint2 o;
  o.x = pack2(v.x + pv.x, v.y + pv.y);
  o.y = pack2(v.z + pv.z, v.w + pv.w);
  *(uint2*)&X[(i64)t * 256 + lane * 4] = o;
}

__global__ __launch_bounds__(256) void gather_e2v_k(const ushort* __restrict__ ext,
                                                    const int* __restrict__ hid,
                                                    const int* __restrict__ tok,
                                                    const int* __restrict__ ss, int nseq,
                                                    ushort* __restrict__ X,
                                                    int* __restrict__ gid) {
  const int t = blockIdx.x * 4 + (threadIdx.x >> 6);
  const int lane = threadIdx.x & 63;
  const int s0 = ss[0];
  if (t >= ss[nseq] - s0) return;
  const int code = tok[s0 + t];
  const int n = code >> 5, slot = code & 31;
  const int id = hid[(i64)n * SE + slot];
  if (lane == 0) gid[t] = id;
  *(uint2*)&X[(i64)t * 256 + lane * 4] =
      *(const uint2*)&ext[(i64)id * 256 + lane * 4];
}

__global__ __launch_bounds__(256) void scatter_k(const ushort* __restrict__ Xc,
                                                 const int* __restrict__ subg,
                                                 float* __restrict__ unity, int n0) {
  const int nl = blockIdx.x * 4 + (threadIdx.x >> 6);
  const int lane = threadIdx.x & 63;
  const int dst = subg[n0 + nl];
  ushort4 v = *(const ushort4*)&Xc[(i64)nl * 256 + lane * 4];
  float4 o; o.x = b2f(v.x); o.y = b2f(v.y); o.z = b2f(v.z); o.w = b2f(v.w);
  *(float4*)&unity[(i64)dst * 256 + lane * 4] = o;
}

__global__ __launch_bounds__(256) void ext_init_k(ushort* __restrict__ ext,
                                                  const float* __restrict__ pad,
                                                  const float* __restrict__ cls) {
  const int d = threadIdx.x;
  ext[(i64)NHEDGE * 256 + d] = f2b(pad[d]);
  ext[(i64)(NHEDGE + 1) * 256 + d] = f2b(cls[d]);
  for (int r = NHEDGE + 2; r < EXTROWS; r += 1)
    ext[(i64)r * 256 + d] = 0;
}

// final: convert compact pred CLS bf16 rows to f32 output
__global__ __launch_bounds__(256) void out_cvt_k(const ushort* __restrict__ predHe,
                                                 float* __restrict__ out) {
  const int i = blockIdx.x * 4 + (threadIdx.x >> 6);
  const int lane = threadIdx.x & 63;
  ushort4 v = *(const ushort4*)&predHe[(i64)i * 256 + lane * 4];
  float4 o; o.x = b2f(v.x); o.y = b2f(v.y); o.z = b2f(v.z); o.w = b2f(v.w);
  *(float4*)&out[(i64)i * 256 + lane * 4] = o;
}

// ================= host orchestration ==========================================
extern "C" void kernel_launch(void* const* d_in, const int* in_sizes, int n_in,
                              void* d_out, int out_size, void* d_ws, size_t ws_size,
                              hipStream_t stream) {
  (void)in_sizes; (void)n_in; (void)out_size;
  const float* unity_in = (const float*)d_in[0];
  const float* cls_emb  = (const float*)d_in[1];
  const float* pad_emb  = (const float*)d_in[2];
  const float* pos_tab  = (const float*)d_in[3];
  const float* qkv_w    = (const float*)d_in[4];
  const float* qkv_b    = (const float*)d_in[5];
  const float* out_w    = (const float*)d_in[6];
  const float* out_b    = (const float*)d_in[7];
  const float* ln1_g    = (const float*)d_in[8];
  const float* ln1_b    = (const float*)d_in[9];
  const float* ln2_g    = (const float*)d_in[10];
  const float* ln2_b    = (const float*)d_in[11];
  const float* ff1_w    = (const float*)d_in[12];
  const float* ff1_b    = (const float*)d_in[13];
  const float* ff2_w    = (const float*)d_in[14];
  const float* ff2_b    = (const float*)d_in[15];
  const int* xid   = (const int*)d_in[16];
  const int* vmask = (const int*)d_in[17];
  const int* xpos  = (const int*)d_in[18];
  const int* hid   = (const int*)d_in[19];
  const int* hmask = (const int*)d_in[20];
  const int* subg  = (const int*)d_in[21];
  const int* pred  = (const int*)d_in[22];

  const i64 unity_b = (i64)NTOTAL * 256 * 4;
  const i64 ext_b   = (i64)EXTROWS * 256 * 2;
  const i64 qkvE_b  = (i64)EXTROWS * 768 * 2;
  const int nq = 2 * 768 * 256, no = 2 * 256 * 256,
            n1 = 2 * 1024 * 256, n2 = 2 * 256 * 1024;
  const i64 wts_b = (i64)(nq + no + n1 + n2) * 2;
  const i64 idx_b = ((i64)NNODE + NHEDGE + 512 +
                     (NNODE + 1) + (NHEDGE + 1) + 257 +
                     (i64)NNODE * SE + (i64)NHEDGE * SV + MPRED + NPRED * 256) * 4;
  const i64 per_elem = (i64)SE * (512 + 2048 + 512 + 4);
  int CHUNK = 8192;
  while (CHUNK > 256 &&
         unity_b + ext_b + qkvE_b + wts_b + idx_b + (i64)CHUNK * per_elem > (i64)ws_size)
    CHUNK >>= 1;

  char* w = (char*)d_ws;
  float*  unity = (float*)w;  w += unity_b;
  ushort* ext   = (ushort*)w; w += ext_b;
  ushort* qkvE  = (ushort*)w; w += qkvE_b;
  ushort* wq    = (ushort*)w; w += (i64)nq * 2;
  ushort* wo    = (ushort*)w; w += (i64)no * 2;
  ushort* w1    = (ushort*)w; w += (i64)n1 * 2;
  ushort* w2    = (ushort*)w; w += (i64)n2 * 2;
  ushort* X     = (ushort*)w; w += (i64)CHUNK * SE * 256 * 2;
  ushort* Y     = (ushort*)w; w += (i64)CHUNK * SE * 1024 * 2;
  ushort* O     = (ushort*)w; w += (i64)CHUNK * SE * 256 * 2;
  int* gid   = (int*)w; w += (i64)CHUNK * SE * 4;
  int* cntE  = (int*)w; w += (i64)NNODE * 4;
  int* cntV  = (int*)w; w += (i64)NHEDGE * 4;
  int* partE = (int*)w; w += 256 * 4;
  int* partV = (int*)w; w += 256 * 4;
  int* ssE   = (int*)w; w += (i64)(NNODE + 1) * 4;
  int* ssV   = (int*)w; w += (i64)(NHEDGE + 1) * 4;
  int* ssP   = (int*)w; w += 257 * 4;
  int* tokE  = (int*)w; w += (i64)NNODE * SE * 4;
  int* tokV  = (int*)w; w += (i64)NHEDGE * SV * 4;
  int* tokP  = (int*)w; w += MPRED * 4;
  ushort* predHe = (ushort*)w; w += (i64)NPRED * 256 * 2;
  ushort* Ocls = O;
  ushort* Qcls = O + (i64)CHUNK * 256;
  ushort* X2   = O + (i64)2 * CHUNK * 256;
  ushort* X3   = O + (i64)3 * CHUNK * 256;

  f2b_cvt_k<<<512, 256, 0, stream>>>(qkv_w, wq, nq);
  f2b_cvt_k<<<512, 256, 0, stream>>>(out_w, wo, no);
  f2b_cvt_k<<<512, 256, 0, stream>>>(ff1_w, w1, n1);
  f2b_cvt_k<<<512, 256, 0, stream>>>(ff2_w, w2, n2);
  hipMemcpyAsync(unity, unity_in, unity_b, hipMemcpyDeviceToDevice, stream);
  ext_init_k<<<1, 256, 0, stream>>>(ext, pad_emb, cls_emb);

  cnt_k<<<NHEDGE / 256, 256, 0, stream>>>(vmask, ARITY, 1, cntV, NHEDGE);
  scan1_k<<<NHEDGE / 256, 256, 0, stream>>>(cntV, ssV, partV, NHEDGE);
  scan2_k<<<1, 256, 0, stream>>>(partV, NHEDGE / 256, ssV, NHEDGE);
  scan3_k<<<NHEDGE / 256, 256, 0, stream>>>(ssV, partV, vmask, ARITY, 1, tokV, NHEDGE);
  cnt_k<<<NNODE / 256, 256, 0, stream>>>(hmask, SE, 0, cntE, NNODE);
  scan1_k<<<NNODE / 256, 256, 0, stream>>>(cntE, ssE, partE, NNODE);
  scan2_k<<<1, 256, 0, stream>>>(partE, NNODE / 256, ssE, NNODE);
  scan3_k<<<NNODE / 256, 256, 0, stream>>>(ssE, partE, hmask, SE, 0, tokE, NNODE);
  predscan_k<<<1, 256, 0, stream>>>(pred, cntV, vmask, ssP, tokP);

  for (int k = 0; k < 2; k++) {
    // ---- V2E (full: every hedge feeds next hop's E2V) ----
    for (int c = 0; c < NHEDGE / CHUNK; c++) {
      const int e0 = c * CHUNK;
      const int* ssc = ssV + e0;
      const int Mmax = CHUNK * SV;
      gather_v2e_k<<<Mmax / 4, 256, 0, stream>>>(unity, pos_tab, xid, xpos,
                                                 tokV, ssc, CHUNK, X);
      gemm_bf16_k<256, 1><<<dim3(6, Mmax / 128), 256, 0, stream>>>(
          X, wq, qkv_b, Y, Mmax, 768, ssc, CHUNK, nullptr);
      attn1_k<SV><<<CHUNK, 16 * SV, 0, stream>>>(Y, ssc, O);
      gemm_ln_k<256><<<Mmax / 128, 512, 0, stream>>>(
          O, wo, out_b, X, 256, ln1_g, ln1_b, X, 256, Mmax, ssc, CHUNK, nullptr);
      gemm_bf16_k<256, 2><<<dim3(8, Mmax / 128), 256, 0, stream>>>(
          X, w1, ff1_b, Y, Mmax, 1024, ssc, CHUNK, nullptr);
      gemm_ln_k<1024><<<Mmax / 128, 512, 0, stream>>>(
          Y, w2, ff2_b, X, 256, ln2_g, ln2_b, X, 256, Mmax, ssc, CHUNK, nullptr);
      gemm_bf16_k<256, 1><<<dim3(4, Mmax / 128), 256, 0, stream>>>(
          X, wq + (i64)768 * 256 + (i64)256 * 256, qkv_b + 768 + 256,
          Y, Mmax, 512, ssc, CHUNK, nullptr);
      gemm_bf16_k<256, 1><<<dim3(2, CHUNK / 128), 256, 0, stream>>>(
          X, wq + (i64)768 * 256, qkv_b + 768, Qcls, CHUNK, 256,
          nullptr, 0, ssc);
      attn_cls_k<SV><<<CHUNK / 16, 256, 0, stream>>>(Qcls, Y, ssc, Ocls);
      gemm_ln_k<256><<<CHUNK / 128, 512, 0, stream>>>(
          Ocls, wo + (i64)256 * 256, out_b + 256, X, 256,
          ln1_g + 256, ln1_b + 256, X2, 256, CHUNK, nullptr, 0, ssc);
      gemm_bf16_k<256, 2><<<dim3(8, CHUNK / 128), 256, 0, stream>>>(
          X2, w1 + (i64)1024 * 256, ff1_b + 1024, Y, CHUNK, 1024,
          nullptr, 0, nullptr);
      gemm_ln_k<1024><<<CHUNK / 128, 512, 0, stream>>>(
          Y, w2 + (i64)256 * 1024, ff2_b + 256, X2, 256,
          ln2_g + 256, ln2_b + 256, ext + (i64)e0 * 256, 256, CHUNK,
          nullptr, 0, nullptr);
    }
    // ---- E2V ----
    // hedge-QKV dedup: QKV(ext[hid]) == (ext @ Wqkv + b)[hid]
    gemm_bf16_k<256, 1><<<dim3(6, EXTROWS / 128), 256, 0, stream>>>(
        ext, wq, qkv_b, qkvE, EXTROWS, 768, nullptr, 0, nullptr);
    for (int c = 0; c < NNODE / CHUNK; c++) {
      const int n0 = c * CHUNK;
      const int* ssc = ssE + n0;
      const int Mmax = CHUNK * SE;
      gather_e2v_k<<<Mmax / 4, 256, 0, stream>>>(ext, hid, tokE, ssc, CHUNK, X, gid);
      attn1g_k<SE><<<CHUNK, 16 * SE, 0, stream>>>(qkvE, gid, ssc, O);
      gemm_ln_k<256><<<Mmax / 128, 512, 0, stream>>>(
          O, wo, out_b, X, 256, ln1_g, ln1_b, X, 256, Mmax, ssc, CHUNK, nullptr);
      gemm_bf16_k<256, 2><<<dim3(8, Mmax / 128), 256, 0, stream>>>(
          X, w1, ff1_b, Y, Mmax, 1024, ssc, CHUNK, nullptr);
      gemm_ln_k<1024><<<Mmax / 128, 512, 0, stream>>>(
          Y, w2, ff2_b, X, 256, ln2_g, ln2_b, X, 256, Mmax, ssc, CHUNK, nullptr);
      gemm_bf16_k<256, 1><<<dim3(4, Mmax / 128), 256, 0, stream>>>(
          X, wq + (i64)768 * 256 + (i64)256 * 256, qkv_b + 768 + 256,
          Y, Mmax, 512, ssc, CHUNK, nullptr);
      gemm_bf16_k<256, 1><<<dim3(2, CHUNK / 128), 256, 0, stream>>>(
          X, wq + (i64)768 * 256, qkv_b + 768, Qcls, CHUNK, 256,
          nullptr, 0, ssc);
      attn_cls_k<SE><<<CHUNK / 16, 256, 0, stream>>>(Qcls, Y, ssc, Ocls);
      gemm_ln_k<256><<<CHUNK / 128, 512, 0, stream>>>(
          Ocls, wo + (i64)256 * 256, out_b + 256, X, 256,
          ln1_g + 256, ln1_b + 256, X2, 256, CHUNK, nullptr, 0, ssc);
      gemm_bf16_k<256, 2><<<dim3(8, CHUNK / 128), 256, 0, stream>>>(
          X2, w1 + (i64)1024 * 256, ff1_b + 1024, Y, CHUNK, 1024,
          nullptr, 0, nullptr);
      gemm_ln_k<1024><<<CHUNK / 128, 512, 0, stream>>>(
          Y, w2 + (i64)256 * 1024, ff2_b + 256, X2, 256,
          ln2_g + 256, ln2_b + 256, X3, 256, CHUNK, nullptr, 0, nullptr);
      scatter_k<<<CHUNK / 4, 256, 0, stream>>>(X3, subg, unity, n0);
    }
  }

  // ---- hop-2 V2E: ONLY the 256 predicted hedges (exact; per-seq independent) --
  {
    const int* ssc = ssP;
    gather_v2e_k<<<MPRED / 4, 256, 0, stream>>>(unity, pos_tab, xid, xpos,
                                                tokP, ssc, NPRED, X);
    gemm_bf16_k<256, 1><<<dim3(6, MPRED / 128), 256, 0, stream>>>(
        X, wq, qkv_b, Y, MPRED, 768, ssc, NPRED, nullptr);
    attn1_k<SV><<<NPRED, 16 * SV, 0, stream>>>(Y, ssc, O);
    gemm_ln_k<256><<<MPRED / 128, 512, 0, stream>>>(
        O, wo, out_b, X, 256, ln1_g, ln1_b, X, 256, MPRED, ssc, NPRED, nullptr);
    gemm_bf16_k<256, 2><<<dim3(8, MPRED / 128), 256, 0, stream>>>(
        X, w1, ff1_b, Y, MPRED, 1024, ssc, NPRED, nullptr);
    gemm_ln_k<1024><<<MPRED / 128, 512, 0, stream>>>(
        Y, w2, ff2_b, X, 256, ln2_g, ln2_b, X, 256, MPRED, ssc, NPRED, nullptr);
    gemm_bf16_k<256, 1><<<dim3(4, MPRED / 128), 256, 0, stream>>>(
        X, wq + (i64)768 * 256 + (i64)256 * 256, qkv_b + 768 + 256,
        Y, MPRED, 512, ssc, NPRED, nullptr);
    gemm_bf16_k<256, 1><<<dim3(2, NPRED / 128), 256, 0, stream>>>(
        X, wq + (i64)768 * 256, qkv_b + 768, Qcls, NPRED, 256,
        nullptr, 0, ssc);
    attn_cls_k<SV><<<NPRED / 16, 256, 0, stream>>>(Qcls, Y, ssc, Ocls);
    gemm_ln_k<256><<<NPRED / 128, 512, 0, stream>>>(
        Ocls, wo + (i64)256 * 256, out_b + 256, X, 256,
        ln1_g + 256, ln1_b + 256, X2, 256, NPRED, nullptr, 0, ssc);
    gemm_bf16_k<256, 2><<<dim3(8, NPRED / 128), 256, 0, stream>>>(
        X2, w1 + (i64)1024 * 256, ff1_b + 1024, Y, NPRED, 1024,
        nullptr, 0, nullptr);
    gemm_ln_k<1024><<<NPRED / 128, 512, 0, stream>>>(
        Y, w2 + (i64)256 * 1024, ff2_b + 256, X2, 256,
        ln2_g + 256, ln2_b + 256, predHe, 256, NPRED, nullptr, 0, nullptr);
  }
  out_cvt_k<<<NPRED / 4, 256, 0, stream>>>(predHe, (float*)d_out);
}

// Round 12
// 10764.233 us; speedup vs baseline: 2.4254x; 1.4720x over previous
//
#include <hip/hip_runtime.h>
#include <stdint.h>

typedef long long i64;
typedef __attribute__((ext_vector_type(8))) short bf16x8;
typedef __attribute__((ext_vector_type(4))) float f32x4;

#define SV 11
#define SE 17
#define ARITY 10
#define NHEDGE 32768
#define NNODE 65536
#define NTOTAL 100000
#define EXTROWS 32896  // NHEDGE+2 padded to 128 multiple
#define NPRED 256
#define MPRED 2816     // NPRED * SV
#define NN1 2560       // NPRED * ARITY  (hop-1 E2V node slots, dup-tolerant)
#define MN1 43520      // NN1 * SE (max tokens, 340*128)

__device__ __forceinline__ float b2f(ushort u) {
  union { uint32_t i; float f; } v; v.i = (uint32_t)u << 16; return v.f;
}
__device__ __forceinline__ ushort f2b(float f) {
  union { float f; uint32_t i; } v; v.f = f;
  uint32_t u = v.i + 0x7fffu + ((v.i >> 16) & 1u);
  return (ushort)(u >> 16);
}
__device__ __forceinline__ uint pack2(float a, float b) {
  return (uint)f2b(a) | ((uint)f2b(b) << 16);
}
__device__ __forceinline__ void cvt8(uint4 v, float* f) {
  f[0] = b2f((ushort)(v.x & 0xffff)); f[1] = b2f((ushort)(v.x >> 16));
  f[2] = b2f((ushort)(v.y & 0xffff)); f[3] = b2f((ushort)(v.y >> 16));
  f[4] = b2f((ushort)(v.z & 0xffff)); f[5] = b2f((ushort)(v.z >> 16));
  f[6] = b2f((ushort)(v.w & 0xffff)); f[7] = b2f((ushort)(v.w >> 16));
}

__device__ __forceinline__ void gload_lds16(const void* g, void* l) {
  __builtin_amdgcn_global_load_lds((const __attribute__((address_space(1))) void*)g,
                                   (__attribute__((address_space(3))) void*)l, 16, 0, 0);
}

__device__ __forceinline__ int xcd_swizzle(int orig, int nwg) {
  const int xcd = orig & 7, rest = orig >> 3;
  const int q = nwg >> 3, r = nwg & 7;
  return (xcd < r ? xcd * (q + 1) : r * (q + 1) + (xcd - r) * q) + rest;
}

// ================= compaction: count / scan / fill =============================
__global__ __launch_bounds__(256) void cnt_k(const int* __restrict__ mask, int width,
                                             int extra, int* __restrict__ cnt, int n) {
  const int i = blockIdx.x * 256 + threadIdx.x;
  if (i >= n) return;
  int c = extra;
  for (int j = 0; j < width; j++) c += (mask[(i64)i * width + j] != 0);
  cnt[i] = c;
}

__global__ __launch_bounds__(256) void scan1_k(const int* __restrict__ cnt,
                                               int* __restrict__ ss,
                                               int* __restrict__ part, int n) {
  __shared__ int sm[256];
  const int i = blockIdx.x * 256 + threadIdx.x;
  const int v = (i < n) ? cnt[i] : 0;
  sm[threadIdx.x] = v;
  __syncthreads();
  for (int o = 1; o < 256; o <<= 1) {
    const int t = (threadIdx.x >= o) ? sm[threadIdx.x - o] : 0;
    __syncthreads();
    sm[threadIdx.x] += t;
    __syncthreads();
  }
  if (i < n) ss[i] = sm[threadIdx.x] - v;  // exclusive
  if (threadIdx.x == 255) part[blockIdx.x] = sm[255];
}

__global__ __launch_bounds__(256) void scan2_k(int* __restrict__ part, int nb,
                                               int* __restrict__ ss, int n) {
  __shared__ int sm[256];
  const int v = (threadIdx.x < nb) ? part[threadIdx.x] : 0;
  sm[threadIdx.x] = v;
  __syncthreads();
  for (int o = 1; o < 256; o <<= 1) {
    const int t = (threadIdx.x >= o) ? sm[threadIdx.x - o] : 0;
    __syncthreads();
    sm[threadIdx.x] += t;
    __syncthreads();
  }
  if (threadIdx.x < nb) part[threadIdx.x] = sm[threadIdx.x] - v;
  if (threadIdx.x == 255) ss[n] = sm[255];
}

__global__ __launch_bounds__(256) void scan3_k(int* __restrict__ ss,
                                               const int* __restrict__ part,
                                               const int* __restrict__ mask, int width,
                                               int extra, int* __restrict__ tok, int n) {
  const int i = blockIdx.x * 256 + threadIdx.x;
  if (i >= n) return;
  int off = ss[i] + part[blockIdx.x];
  ss[i] = off;
  if (extra) {
    tok[off++] = (i << 5);
    for (int j = 0; j < width; j++)
      if (mask[(i64)i * width + j] != 0) tok[off++] = (i << 5) | (j + 1);
  } else {
    for (int j = 0; j < width; j++)
      if (mask[(i64)i * width + j] != 0) tok[off++] = (i << 5) | j;
  }
}

// ===== pred-pass compaction: 256 predicted edges, single block ================
__global__ __launch_bounds__(256) void predscan_k(const int* __restrict__ pred,
                                                  const int* __restrict__ cntV,
                                                  const int* __restrict__ vmask,
                                                  int* __restrict__ ssP,
                                                  int* __restrict__ tokP) {
  __shared__ int sm[256];
  const int tid = threadIdx.x;
  const int e = pred[tid];
  const int v = cntV[e];
  sm[tid] = v;
  __syncthreads();
  for (int o = 1; o < 256; o <<= 1) {
    const int t = (tid >= o) ? sm[tid - o] : 0;
    __syncthreads();
    sm[tid] += t;
    __syncthreads();
  }
  int off = sm[tid] - v;  // exclusive
  ssP[tid] = off;
  if (tid == 255) ssP[256] = sm[255];
  tokP[off++] = (e << 5);
  for (int j = 0; j < ARITY; j++)
    if (vmask[(i64)e * ARITY + j] != 0) tokP[off++] = (e << 5) | (j + 1);
}

// ===== hop-1 E2V dependency-cone pruning ======================================
__global__ __launch_bounds__(256) void inv_init_k(int* __restrict__ inv, int n) {
  const int i = blockIdx.x * 256 + threadIdx.x;
  if (i < n) inv[i] = -1;
}
__global__ __launch_bounds__(256) void inv_fill_k(const int* __restrict__ subg,
                                                  int* __restrict__ inv, int n) {
  const int i = blockIdx.x * 256 + threadIdx.x;
  if (i < n) inv[subg[i]] = i;
}
// nodeL[i] = node whose hop-1 embedding feeds pred-edge slot i (dup/dummy ok)
__global__ __launch_bounds__(256) void prednode_k(const int* __restrict__ pred,
                                                  const int* __restrict__ xid,
                                                  const int* __restrict__ vmask,
                                                  const int* __restrict__ inv,
                                                  const int* __restrict__ cntE,
                                                  int* __restrict__ nodeL,
                                                  int* __restrict__ cntN) {
  const int i = blockIdx.x * 256 + threadIdx.x;
  if (i >= NN1) return;
  const int e = pred[i / ARITY], j = i - (i / ARITY) * ARITY;
  int nd = 0;
  if (vmask[(i64)e * ARITY + j] != 0) {
    const int v = inv[xid[(i64)e * ARITY + j]];
    if (v >= 0) nd = v;
  }
  nodeL[i] = nd;
  cntN[i] = cntE[nd];
}
__global__ __launch_bounds__(256) void scan3n_k(int* __restrict__ ss,
                                                const int* __restrict__ part,
                                                const int* __restrict__ hmask,
                                                const int* __restrict__ nodeL,
                                                int* __restrict__ tok) {
  const int i = blockIdx.x * 256 + threadIdx.x;
  if (i >= NN1) return;
  int off = ss[i] + part[blockIdx.x];
  ss[i] = off;
  const int nd = nodeL[i];
  for (int j = 0; j < SE; j++)
    if (hmask[(i64)nd * SE + j] != 0) tok[off++] = (i << 5) | j;
}

// ================= 128x128 bf16 MFMA GEMM =====================================
template <int K, int MODE>
__global__ __launch_bounds__(256) void gemm_bf16_k(const ushort* __restrict__ A,
                                                   const ushort* __restrict__ W,
                                                   const float* __restrict__ bias,
                                                   ushort* __restrict__ C, int M, int N,
                                                   const int* ssn, int nseq,
                                                   const int* arp) {
  const int tid = threadIdx.x;
  const int wave = tid >> 6, lane = tid & 63;
  const int nwg = gridDim.x * gridDim.y;
  const int wg = xcd_swizzle(blockIdx.y * gridDim.x + blockIdx.x, nwg);
  const int bx = wg % gridDim.x, by = wg / gridDim.x;
  const int m0 = by << 7, n0 = bx << 7;
  if (ssn && m0 >= ssn[nseq] - ssn[0]) return;
  __shared__ ushort As[128 * 64];
  __shared__ ushort Ws[128 * 64];
  const int wr = wave >> 1, wc = wave & 1;

  f32x4 acc[4][4];
#pragma unroll
  for (int m = 0; m < 4; m++)
#pragma unroll
    for (int n = 0; n < 4; n++) acc[m][n] = (f32x4){0.f, 0.f, 0.f, 0.f};

  const int srow = (wave << 5) + (lane >> 3);
  const int kblk_g = (lane & 7) ^ (lane >> 3);
  const i64 arow = arp ? (i64)(arp[m0 + srow] - arp[0]) : (i64)(m0 + srow);
  const ushort* Ag = A + arow * K + (kblk_g << 3);
  const ushort* Wg = W + (i64)(n0 + srow) * K + (kblk_g << 3);
  char* lA = (char*)As + (wave << 12);
  char* lB = (char*)Ws + (wave << 12);

#pragma unroll
  for (int i = 0; i < 4; i++) {
    gload_lds16(Ag + (i64)(i * 8) * K, lA + i * 1024);
    gload_lds16(Wg + (i64)(i * 8) * K, lB + i * 1024);
  }

  for (int k0 = 0; k0 < K; k0 += 64) {
    __syncthreads();
    bf16x8 af[2][4], bf[2][4];
#pragma unroll
    for (int kh = 0; kh < 2; kh++) {
      const int kb = (kh << 2) + (lane >> 4);
#pragma unroll
      for (int m = 0; m < 4; m++) {
        const int row = (wr << 6) + (m << 4) + (lane & 15);
        af[kh][m] = *(const bf16x8*)&As[row * 64 + ((kb ^ (row & 7)) << 3)];
      }
#pragma unroll
      for (int n = 0; n < 4; n++) {
        const int row = (wc << 6) + (n << 4) + (lane & 15);
        bf[kh][n] = *(const bf16x8*)&Ws[row * 64 + ((kb ^ (row & 7)) << 3)];
      }
    }
    __syncthreads();
    if (k0 + 64 < K) {
#pragma unroll
      for (int i = 0; i < 4; i++) {
        gload_lds16(Ag + (k0 + 64) + (i64)(i * 8) * K, lA + i * 1024);
        gload_lds16(Wg + (k0 + 64) + (i64)(i * 8) * K, lB + i * 1024);
      }
    }
#pragma unroll
    for (int kh = 0; kh < 2; kh++)
#pragma unroll
      for (int m = 0; m < 4; m++)
#pragma unroll
        for (int n = 0; n < 4; n++)
          acc[m][n] = __builtin_amdgcn_mfma_f32_16x16x32_bf16(bf[kh][n], af[kh][m], acc[m][n], 0, 0, 0);
  }

#pragma unroll
  for (int m = 0; m < 4; m++) {
    const int row = m0 + (wr << 6) + (m << 4) + (lane & 15);
#pragma unroll
    for (int n = 0; n < 4; n++) {
      const int col = n0 + (wc << 6) + (n << 4) + ((lane >> 4) << 2);
      float v0 = acc[m][n][0], v1 = acc[m][n][1], v2 = acc[m][n][2], v3 = acc[m][n][3];
      if (MODE > 0) {
        const f32x4 bv = *(const f32x4*)&bias[col];
        v0 += bv[0]; v1 += bv[1]; v2 += bv[2]; v3 += bv[3];
      }
      if (MODE == 2) {
        v0 = fmaxf(v0, 0.f); v1 = fmaxf(v1, 0.f);
        v2 = fmaxf(v2, 0.f); v3 = fmaxf(v3, 0.f);
      }
      uint2 o; o.x = pack2(v0, v1); o.y = pack2(v2, v3);
      *(uint2*)&C[(i64)row * N + col] = o;
    }
  }
}

// ============ Fused GEMM + residual + LayerNorm (N = 256) ======================
template <int K>
__global__ __launch_bounds__(512) void gemm_ln_k(const ushort* __restrict__ A,
                                                 const ushort* __restrict__ W,
                                                 const float* __restrict__ bias,
                                                 const ushort* R, int rstride,
                                                 const float* __restrict__ g,
                                                 const float* __restrict__ b,
                                                 ushort* C, int cstride, int M,
                                                 const int* ssn, int nseq,
                                                 const int* rrp) {
  const int m0 = blockIdx.x << 7;
  if (ssn && m0 >= ssn[nseq] - ssn[0]) return;
  __shared__ ushort As[128 * 64];
  __shared__ ushort Ws[256 * 64];
  __shared__ float partS[128][4];
  __shared__ float partQ[128][4];
  const int tid = threadIdx.x;
  const int wave = tid >> 6, lane = tid & 63;
  const int wr = wave >> 2, wc = wave & 3;

  f32x4 acc[4][4];
#pragma unroll
  for (int m = 0; m < 4; m++)
#pragma unroll
    for (int n = 0; n < 4; n++) acc[m][n] = (f32x4){0.f, 0.f, 0.f, 0.f};

  int rowA[2], kgA[2];
#pragma unroll
  for (int i = 0; i < 2; i++) {
    const int u = wave * 128 + i * 64 + lane;
    rowA[i] = u >> 3; kgA[i] = (u & 7) ^ ((u >> 3) & 7);
  }
  int rowW[4], kgW[4];
#pragma unroll
  for (int i = 0; i < 4; i++) {
    const int u = wave * 256 + i * 64 + lane;
    rowW[i] = u >> 3; kgW[i] = (u & 7) ^ ((u >> 3) & 7);
  }

#pragma unroll
  for (int i = 0; i < 2; i++)
    gload_lds16(A + (i64)(m0 + rowA[i]) * K + (kgA[i] << 3),
                (char*)As + (wave * 128 + i * 64) * 16);
#pragma unroll
  for (int i = 0; i < 4; i++)
    gload_lds16(W + (i64)rowW[i] * K + (kgW[i] << 3),
                (char*)Ws + (wave * 256 + i * 64) * 16);

  for (int k0 = 0; k0 < K; k0 += 64) {
    __syncthreads();
    bf16x8 af[2][4], bf[2][4];
#pragma unroll
    for (int kh = 0; kh < 2; kh++) {
      const int kb = (kh << 2) + (lane >> 4);
#pragma unroll
      for (int m = 0; m < 4; m++) {
        const int row = (wr << 6) + (m << 4) + (lane & 15);
        af[kh][m] = *(const bf16x8*)&As[row * 64 + ((kb ^ (row & 7)) << 3)];
      }
#pragma unroll
      for (int n = 0; n < 4; n++) {
        const int row = (wc << 6) + (n << 4) + (lane & 15);
        bf[kh][n] = *(const bf16x8*)&Ws[row * 64 + ((kb ^ (row & 7)) << 3)];
      }
    }
    __syncthreads();
    if (k0 + 64 < K) {
#pragma unroll
      for (int i = 0; i < 2; i++)
        gload_lds16(A + (i64)(m0 + rowA[i]) * K + (k0 + 64) + (kgA[i] << 3),
                    (char*)As + (wave * 128 + i * 64) * 16);
#pragma unroll
      for (int i = 0; i < 4; i++)
        gload_lds16(W + (i64)rowW[i] * K + (k0 + 64) + (kgW[i] << 3),
                    (char*)Ws + (wave * 256 + i * 64) * 16);
    }
#pragma unroll
    for (int kh = 0; kh < 2; kh++)
#pragma unroll
      for (int m = 0; m < 4; m++)
#pragma unroll
        for (int n = 0; n < 4; n++)
          acc[m][n] = __builtin_amdgcn_mfma_f32_16x16x32_bf16(bf[kh][n], af[kh][m], acc[m][n], 0, 0, 0);
  }

#pragma unroll
  for (int m = 0; m < 4; m++) {
    const int tokl = (wr << 6) + (m << 4) + (lane & 15);
    const int row = m0 + tokl;
    const i64 rr = rrp ? (i64)(rrp[row] - rrp[0]) : (i64)row;
    float s = 0.f, q = 0.f;
#pragma unroll
    for (int n = 0; n < 4; n++) {
      const int col = (wc << 6) + (n << 4) + ((lane >> 4) << 2);
      const f32x4 bv = *(const f32x4*)&bias[col];
      const uint2 ru = *(const uint2*)&R[rr * rstride + col];
      float v0 = acc[m][n][0] + bv[0] + b2f((ushort)(ru.x & 0xffff));
      float v1 = acc[m][n][1] + bv[1] + b2f((ushort)(ru.x >> 16));
      float v2 = acc[m][n][2] + bv[2] + b2f((ushort)(ru.y & 0xffff));
      float v3 = acc[m][n][3] + bv[3] + b2f((ushort)(ru.y >> 16));
      acc[m][n][0] = v0; acc[m][n][1] = v1; acc[m][n][2] = v2; acc[m][n][3] = v3;
      s += v0 + v1 + v2 + v3;
      q += v0 * v0 + v1 * v1 + v2 * v2 + v3 * v3;
    }
    s += __shfl_xor(s, 16, 64); s += __shfl_xor(s, 32, 64);
    q += __shfl_xor(q, 16, 64); q += __shfl_xor(q, 32, 64);
    if (lane < 16) { partS[tokl][wc] = s; partQ[tokl][wc] = q; }
  }
  __syncthreads();
#pragma unroll
  for (int m = 0; m < 4; m++) {
    const int tokl = (wr << 6) + (m << 4) + (lane & 15);
    const i64 row = (i64)(m0 + tokl);
    const f32x4 s4 = *(const f32x4*)&partS[tokl][0];
    const f32x4 q4 = *(const f32x4*)&partQ[tokl][0];
    const float mean = (s4[0] + s4[1] + s4[2] + s4[3]) * (1.f / 256.f);
    const float var = (q4[0] + q4[1] + q4[2] + q4[3]) * (1.f / 256.f) - mean * mean;
    const float rs = rsqrtf(var + 1e-5f);
#pragma unroll
    for (int n = 0; n < 4; n++) {
      const int col = (wc << 6) + (n << 4) + ((lane >> 4) << 2);
      const f32x4 g4 = *(const f32x4*)&g[col];
      const f32x4 b4 = *(const f32x4*)&b[col];
      uint2 o;
      o.x = pack2((acc[m][n][0] - mean) * rs * g4[0] + b4[0],
                  (acc[m][n][1] - mean) * rs * g4[1] + b4[1]);
      o.y = pack2((acc[m][n][2] - mean) * rs * g4[2] + b4[2],
                  (acc[m][n][3] - mean) * rs * g4[3] + b4[3]);
      *(uint2*)&C[row * cstride + col] = o;
    }
  }
}

// ========= Layer-1 attention (compact, from per-token QKV rows) ===============
template <int S>
__global__ __launch_bounds__(16 * S) void attn1_k(const ushort* __restrict__ QKV,
                                                  const int* __restrict__ ss,
                                                  ushort* __restrict__ O) {
  __shared__ float KL[4][S][68];
  __shared__ float VL[4][S][68];
  const int tid = threadIdx.x;
  const int s0 = ss[0];
  const int base = ss[blockIdx.x] - s0;
  const int L = ss[blockIdx.x + 1] - ss[blockIdx.x];

  for (int u = tid; u < 128 * L; u += 16 * S) {
    const int d4 = u & 15, h = (u >> 4) & 3, mt = u >> 6;
    const int mat = (mt >= L), t = mat ? mt - L : mt;
    const ushort* gp = QKV + (i64)(base + t) * 768 + 256 + mat * 256 + h * 64 + d4 * 4;
    ushort4 raw = *(const ushort4*)gp;
    float* dst = (mat ? &VL[h][t][0] : &KL[h][t][0]) + d4 * 4;
    dst[0] = b2f(raw.x); dst[1] = b2f(raw.y); dst[2] = b2f(raw.z); dst[3] = b2f(raw.w);
  }
  __syncthreads();

  const int h = tid / (4 * S);
  const int r = tid - h * 4 * S;
  const int q = r >> 2, j = r & 3;
  if (q >= L) return;

  float qv[16];
  {
    const ushort* qp = QKV + (i64)(base + q) * 768 + h * 64 + j * 16;
    cvt8(*(const uint4*)qp, qv);
    cvt8(*(const uint4*)(qp + 8), qv + 8);
  }

  float w[S];
  float mx = -1e30f;
#pragma unroll
  for (int s = 0; s < S; s++) {
    float p = -1e30f;
    if (s < L) {
      const float* kr = &KL[h][s][j * 16];
      p = 0.f;
#pragma unroll
      for (int e = 0; e < 4; e++) {
        const float4 kv = *(const float4*)(kr + e * 4);
        p = fmaf(qv[e * 4 + 0], kv.x, p);
        p = fmaf(qv[e * 4 + 1], kv.y, p);
        p = fmaf(qv[e * 4 + 2], kv.z, p);
        p = fmaf(qv[e * 4 + 3], kv.w, p);
      }
      p += __shfl_xor(p, 1, 64);
      p += __shfl_xor(p, 2, 64);
      p *= 0.125f;
    }
    w[s] = p;
    mx = fmaxf(mx, p);
  }
  float sum = 0.f;
#pragma unroll
  for (int s = 0; s < S; s++) { w[s] = __expf(w[s] - mx); sum += w[s]; }
  const float inv = 1.f / sum;

  float o[16];
#pragma unroll
  for (int e = 0; e < 16; e++) o[e] = 0.f;
#pragma unroll
  for (int s = 0; s < S; s++) {
    if (s < L) {
      const float ws = w[s];
      const float* vr = &VL[h][s][j * 16];
#pragma unroll
      for (int e = 0; e < 4; e++) {
        const float4 vv = *(const float4*)(vr + e * 4);
        o[e * 4 + 0] = fmaf(ws, vv.x, o[e * 4 + 0]);
        o[e * 4 + 1] = fmaf(ws, vv.y, o[e * 4 + 1]);
        o[e * 4 + 2] = fmaf(ws, vv.z, o[e * 4 + 2]);
        o[e * 4 + 3] = fmaf(ws, vv.w, o[e * 4 + 3]);
      }
    }
  }
  uint4 st0, st1;
  st0.x = pack2(o[0] * inv, o[1] * inv);   st0.y = pack2(o[2] * inv, o[3] * inv);
  st0.z = pack2(o[4] * inv, o[5] * inv);   st0.w = pack2(o[6] * inv, o[7] * inv);
  st1.x = pack2(o[8] * inv, o[9] * inv);   st1.y = pack2(o[10] * inv, o[11] * inv);
  st1.z = pack2(o[12] * inv, o[13] * inv); st1.w = pack2(o[14] * inv, o[15] * inv);
  ushort* op = O + (i64)(base + q) * 256 + h * 64 + j * 16;
  *(uint4*)op = st0;
  *(uint4*)(op + 8) = st1;
}

// ========= Layer-1 attention, E2V: QKV gathered from hedge table ==============
template <int S>
__global__ __launch_bounds__(16 * S) void attn1g_k(const ushort* __restrict__ QKVE,
                                                   const int* __restrict__ gid,
                                                   const int* __restrict__ ss,
                                                   ushort* __restrict__ O) {
  __shared__ float KL[4][S][68];
  __shared__ float VL[4][S][68];
  __shared__ int ids[S];
  const int tid = threadIdx.x;
  const int s0 = ss[0];
  const int base = ss[blockIdx.x] - s0;
  const int L = ss[blockIdx.x + 1] - ss[blockIdx.x];

  if (tid < L) ids[tid] = gid[base + tid];
  __syncthreads();

  for (int u = tid; u < 128 * L; u += 16 * S) {
    const int d4 = u & 15, h = (u >> 4) & 3, mt = u >> 6;
    const int mat = (mt >= L), t = mat ? mt - L : mt;
    const ushort* gp = QKVE + (i64)ids[t] * 768 + 256 + mat * 256 + h * 64 + d4 * 4;
    ushort4 raw = *(const ushort4*)gp;
    float* dst = (mat ? &VL[h][t][0] : &KL[h][t][0]) + d4 * 4;
    dst[0] = b2f(raw.x); dst[1] = b2f(raw.y); dst[2] = b2f(raw.z); dst[3] = b2f(raw.w);
  }
  __syncthreads();

  const int h = tid / (4 * S);
  const int r = tid - h * 4 * S;
  const int q = r >> 2, j = r & 3;
  if (q >= L) return;

  float qv[16];
  {
    const ushort* qp = QKVE + (i64)ids[q] * 768 + h * 64 + j * 16;
    cvt8(*(const uint4*)qp, qv);
    cvt8(*(const uint4*)(qp + 8), qv + 8);
  }

  float w[S];
  float mx = -1e30f;
#pragma unroll
  for (int s = 0; s < S; s++) {
    float p = -1e30f;
    if (s < L) {
      const float* kr = &KL[h][s][j * 16];
      p = 0.f;
#pragma unroll
      for (int e = 0; e < 4; e++) {
        const float4 kv = *(const float4*)(kr + e * 4);
        p = fmaf(qv[e * 4 + 0], kv.x, p);
        p = fmaf(qv[e * 4 + 1], kv.y, p);
        p = fmaf(qv[e * 4 + 2], kv.z, p);
        p = fmaf(qv[e * 4 + 3], kv.w, p);
      }
      p += __shfl_xor(p, 1, 64);
      p += __shfl_xor(p, 2, 64);
      p *= 0.125f;
    }
    w[s] = p;
    mx = fmaxf(mx, p);
  }
  float sum = 0.f;
#pragma unroll
  for (int s = 0; s < S; s++) { w[s] = __expf(w[s] - mx); sum += w[s]; }
  const float inv = 1.f / sum;

  float o[16];
#pragma unroll
  for (int e = 0; e < 16; e++) o[e] = 0.f;
#pragma unroll
  for (int s = 0; s < S; s++) {
    if (s < L) {
      const float ws = w[s];
      const float* vr = &VL[h][s][j * 16];
#pragma unroll
      for (int e = 0; e < 4; e++) {
        const float4 vv = *(const float4*)(vr + e * 4);
        o[e * 4 + 0] = fmaf(ws, vv.x, o[e * 4 + 0]);
        o[e * 4 + 1] = fmaf(ws, vv.y, o[e * 4 + 1]);
        o[e * 4 + 2] = fmaf(ws, vv.z, o[e * 4 + 2]);
        o[e * 4 + 3] = fmaf(ws, vv.w, o[e * 4 + 3]);
      }
    }
  }
  uint4 st0, st1;
  st0.x = pack2(o[0] * inv, o[1] * inv);   st0.y = pack2(o[2] * inv, o[3] * inv);
  st0.z = pack2(o[4] * inv, o[5] * inv);   st0.w = pack2(o[6] * inv, o[7] * inv);
  st1.x = pack2(o[8] * inv, o[9] * inv);   st1.y = pack2(o[10] * inv, o[11] * inv);
  st1.z = pack2(o[12] * inv, o[13] * inv); st1.w = pack2(o[14] * inv, o[15] * inv);
  ushort* op = O + (i64)(base + q) * 256 + h * 64 + j * 16;
  *(uint4*)op = st0;
  *(uint4*)(op + 8) = st1;
}

// ===== Layer-2 attention, CLS query ===========================================
template <int S>
__global__ __launch_bounds__(256) void attn_cls_k(const ushort* __restrict__ Qc,
                                                  const ushort* __restrict__ KV,
                                                  const int* __restrict__ ss,
                                                  ushort* __restrict__ Ocls) {
  const int tid = threadIdx.x;
  const int sl = tid >> 4, h = (tid >> 2) & 3, j = tid & 3;
  const int seq = blockIdx.x * 16 + sl;
  const int base = ss[seq] - ss[0];
  const int L = ss[seq + 1] - ss[seq];

  float qv[16];
  {
    const ushort* qp = Qc + (i64)seq * 256 + h * 64 + j * 16;
    cvt8(*(const uint4*)qp, qv);
    cvt8(*(const uint4*)(qp + 8), qv + 8);
  }
  float w[S];
  float mx = -1e30f;
#pragma unroll
  for (int s = 0; s < S; s++) {
    float p = -1e30f;
    if (s < L) {
      float kf[16];
      const ushort* kp = KV + (i64)(base + s) * 512 + h * 64 + j * 16;
      cvt8(*(const uint4*)kp, kf);
      cvt8(*(const uint4*)(kp + 8), kf + 8);
      p = 0.f;
#pragma unroll
      for (int e = 0; e < 16; e++) p = fmaf(qv[e], kf[e], p);
      p += __shfl_xor(p, 1, 64);
      p += __shfl_xor(p, 2, 64);
      p *= 0.125f;
    }
    w[s] = p;
    mx = fmaxf(mx, p);
  }
  float sum = 0.f;
#pragma unroll
  for (int s = 0; s < S; s++) { w[s] = __expf(w[s] - mx); sum += w[s]; }
  const float inv = 1.f / sum;

  float o[16];
#pragma unroll
  for (int e = 0; e < 16; e++) o[e] = 0.f;
#pragma unroll
  for (int s = 0; s < S; s++) {
    if (s < L) {
      float vf[16];
      const ushort* vp = KV + (i64)(base + s) * 512 + 256 + h * 64 + j * 16;
      cvt8(*(const uint4*)vp, vf);
      cvt8(*(const uint4*)(vp + 8), vf + 8);
      const float ws = w[s];
#pragma unroll
      for (int e = 0; e < 16; e++) o[e] = fmaf(ws, vf[e], o[e]);
    }
  }
  uint4 st0, st1;
  st0.x = pack2(o[0] * inv, o[1] * inv);   st0.y = pack2(o[2] * inv, o[3] * inv);
  st0.z = pack2(o[4] * inv, o[5] * inv);   st0.w = pack2(o[6] * inv, o[7] * inv);
  st1.x = pack2(o[8] * inv, o[9] * inv);   st1.y = pack2(o[10] * inv, o[11] * inv);
  st1.z = pack2(o[12] * inv, o[13] * inv); st1.w = pack2(o[14] * inv, o[15] * inv);
  ushort* op = Ocls + (i64)seq * 256 + h * 64 + j * 16;
  *(uint4*)op = st0;
  *(uint4*)(op + 8) = st1;
}

// ================= gathers / scatters / conversion =============================
__global__ __launch_bounds__(256) void f2b_cvt_k(const float* __restrict__ in,
                                                 ushort* __restrict__ out, int n) {
  for (int i = blockIdx.x * 256 + threadIdx.x; i < n; i += gridDim.x * 256)
    out[i] = f2b(in[i]);
}

__global__ __launch_bounds__(256) void gather_v2e_k(const float* __restrict__ unity,
                                                    const float* __restrict__ pos,
                                                    const int* __restrict__ xid,
                                                    const int* __restrict__ xpos,
                                                    const int* __restrict__ tok,
                                                    const int* __restrict__ ss, int nseq,
                                                    ushort* __restrict__ X) {
  const int t = blockIdx.x * 4 + (threadIdx.x >> 6);
  const int lane = threadIdx.x & 63;
  const int s0 = ss[0];
  if (t >= ss[nseq] - s0) return;
  const int code = tok[s0 + t];
  const int e = code >> 5, slot = code & 31;
  float4 v = make_float4(0.f, 0.f, 0.f, 0.f);
  if (slot > 0) {
    const int id = xid[(i64)e * ARITY + (slot - 1)];
    v = *(const float4*)&unity[(i64)id * 256 + lane * 4];
  }
  const int pp = xpos[(i64)e * SV + slot];
  const float4 pv = *(const float4*)&pos[(i64)pp * 256 + lane * 4];
  uint2 o;
  o.x = pack2(v.x + pv.x, v.y + pv.y);
  o.y = pack2(v.z + pv.z, v.w + pv.w);
  *(uint2*)&X[(i64)t * 256 + lane * 4] = o;
}

__global__ __launch_bounds__(256) void gather_e2v_k(const ushort* __restrict__ ext,
                                                    const int* __restrict__ hid,
                                                    const int* __restrict__ tok,
                                                    const int* __restrict__ ss, int nseq,
                                                    ushort* __restrict__ X,
                                                    int* __restrict__ gid) {
  const int t = blockIdx.x * 4 + (threadIdx.x >> 6);
  const int lane = threadIdx.x & 63;
  const int s0 = ss[0];
  if (t >= ss[nseq] - s0) return;
  const int code = tok[s0 + t];
  const int n = code >> 5, slot = code & 31;
  const int id = hid[(i64)n * SE + slot];
  if (lane == 0) gid[t] = id;
  *(uint2*)&X[(i64)t * 256 + lane * 4] =
      *(const uint2*)&ext[(i64)id * 256 + lane * 4];
}

// hop-1 restricted E2V gather: sequence index -> node via nodeL
__global__ __launch_bounds__(256) void gather_e2vn_k(const ushort* __restrict__ ext,
                                                     const int* __restrict__ hid,
                                                     const int* __restrict__ nodeL,
                                                     const int* __restrict__ tok,
                                                     const int* __restrict__ ss,
                                                     ushort* __restrict__ X,
                                                     int* __restrict__ gid) {
  const int t = blockIdx.x * 4 + (threadIdx.x >> 6);
  const int lane = threadIdx.x & 63;
  if (t >= ss[NN1] - ss[0]) return;
  const int code = tok[t];
  const int i = code >> 5, slot = code & 31;
  const int id = hid[(i64)nodeL[i] * SE + slot];
  if (lane == 0) gid[t] = id;
  *(uint2*)&X[(i64)t * 256 + lane * 4] =
      *(const uint2*)&ext[(i64)id * 256 + lane * 4];
}

__global__ __launch_bounds__(256) void scatter_k(const ushort* __restrict__ Xc,
                                                 const int* __restrict__ subg,
                                                 float* __restrict__ unity, int n0) {
  const int nl = blockIdx.x * 4 + (threadIdx.x >> 6);
  const int lane = threadIdx.x & 63;
  const int dst = subg[n0 + nl];
  ushort4 v = *(const ushort4*)&Xc[(i64)nl * 256 + lane * 4];
  float4 o; o.x = b2f(v.x); o.y = b2f(v.y); o.z = b2f(v.z); o.w = b2f(v.w);
  *(float4*)&unity[(i64)dst * 256 + lane * 4] = o;
}

// restricted scatter (duplicates write identical values -> benign)
__global__ __launch_bounds__(256) void scatter_n_k(const ushort* __restrict__ Xc,
                                                   const int* __restrict__ subg,
                                                   const int* __restrict__ nodeL,
                                                   float* __restrict__ unity) {
  const int nl = blockIdx.x * 4 + (threadIdx.x >> 6);
  const int lane = threadIdx.x & 63;
  const int dst = subg[nodeL[nl]];
  ushort4 v = *(const ushort4*)&Xc[(i64)nl * 256 + lane * 4];
  float4 o; o.x = b2f(v.x); o.y = b2f(v.y); o.z = b2f(v.z); o.w = b2f(v.w);
  *(float4*)&unity[(i64)dst * 256 + lane * 4] = o;
}

__global__ __launch_bounds__(256) void ext_init_k(ushort* __restrict__ ext,
                                                  const float* __restrict__ pad,
                                                  const float* __restrict__ cls) {
  const int d = threadIdx.x;
  ext[(i64)NHEDGE * 256 + d] = f2b(pad[d]);
  ext[(i64)(NHEDGE + 1) * 256 + d] = f2b(cls[d]);
  for (int r = NHEDGE + 2; r < EXTROWS; r += 1)
    ext[(i64)r * 256 + d] = 0;
}

__global__ __launch_bounds__(256) void out_cvt_k(const ushort* __restrict__ predHe,
                                                 float* __restrict__ out) {
  const int i = blockIdx.x * 4 + (threadIdx.x >> 6);
  const int lane = threadIdx.x & 63;
  ushort4 v = *(const ushort4*)&predHe[(i64)i * 256 + lane * 4];
  float4 o; o.x = b2f(v.x); o.y = b2f(v.y); o.z = b2f(v.z); o.w = b2f(v.w);
  *(float4*)&out[(i64)i * 256 + lane * 4] = o;
}

// ================= host orchestration ==========================================
extern "C" void kernel_launch(void* const* d_in, const int* in_sizes, int n_in,
                              void* d_out, int out_size, void* d_ws, size_t ws_size,
                              hipStream_t stream) {
  (void)in_sizes; (void)n_in; (void)out_size;
  const float* unity_in = (const float*)d_in[0];
  const float* cls_emb  = (const float*)d_in[1];
  const float* pad_emb  = (const float*)d_in[2];
  const float* pos_tab  = (const float*)d_in[3];
  const float* qkv_w    = (const float*)d_in[4];
  const float* qkv_b    = (const float*)d_in[5];
  const float* out_w    = (const float*)d_in[6];
  const float* out_b    = (const float*)d_in[7];
  const float* ln1_g    = (const float*)d_in[8];
  const float* ln1_b    = (const float*)d_in[9];
  const float* ln2_g    = (const float*)d_in[10];
  const float* ln2_b    = (const float*)d_in[11];
  const float* ff1_w    = (const float*)d_in[12];
  const float* ff1_b    = (const float*)d_in[13];
  const float* ff2_w    = (const float*)d_in[14];
  const float* ff2_b    = (const float*)d_in[15];
  const int* xid   = (const int*)d_in[16];
  const int* vmask = (const int*)d_in[17];
  const int* xpos  = (const int*)d_in[18];
  const int* hid   = (const int*)d_in[19];
  const int* hmask = (const int*)d_in[20];
  const int* subg  = (const int*)d_in[21];
  const int* pred  = (const int*)d_in[22];

  const i64 unity_b = (i64)NTOTAL * 256 * 4;
  const i64 ext_b   = (i64)EXTROWS * 256 * 2;
  const i64 qkvE_b  = (i64)EXTROWS * 768 * 2;
  const int nq = 2 * 768 * 256, no = 2 * 256 * 256,
            n1 = 2 * 1024 * 256, n2 = 2 * 256 * 1024;
  const i64 wts_b = (i64)(nq + no + n1 + n2) * 2;
  const i64 idx_b = ((i64)NTOTAL + NNODE + NHEDGE + 1024 +
                     (NNODE + 1) + (NHEDGE + 1) + 257 + (NN1 + 1) + 2 * NN1 +
                     (i64)NNODE * SE + (i64)NHEDGE * SV + MPRED + 2 * MN1 +
                     NPRED * 256) * 4;
  const i64 per_elem = (i64)SE * (512 + 2048 + 512 + 4);
  int CHUNK = 8192;
  while (CHUNK > 4096 &&
         unity_b + ext_b + qkvE_b + wts_b + idx_b + (i64)CHUNK * per_elem > (i64)ws_size)
    CHUNK >>= 1;

  char* w = (char*)d_ws;
  float*  unity = (float*)w;  w += unity_b;
  ushort* ext   = (ushort*)w; w += ext_b;
  ushort* qkvE  = (ushort*)w; w += qkvE_b;
  ushort* wq    = (ushort*)w; w += (i64)nq * 2;
  ushort* wo    = (ushort*)w; w += (i64)no * 2;
  ushort* w1    = (ushort*)w; w += (i64)n1 * 2;
  ushort* w2    = (ushort*)w; w += (i64)n2 * 2;
  ushort* X     = (ushort*)w; w += (i64)CHUNK * SE * 256 * 2;
  ushort* Y     = (ushort*)w; w += (i64)CHUNK * SE * 1024 * 2;
  ushort* O     = (ushort*)w; w += (i64)CHUNK * SE * 256 * 2;
  int* gid   = (int*)w; w += (i64)CHUNK * SE * 4;
  int* inv   = (int*)w; w += (i64)NTOTAL * 4;
  int* cntE  = (int*)w; w += (i64)NNODE * 4;
  int* cntV  = (int*)w; w += (i64)NHEDGE * 4;
  int* partE = (int*)w; w += 256 * 4;
  int* partV = (int*)w; w += 256 * 4;
  int* partN = (int*)w; w += 256 * 4;
  int* ssE   = (int*)w; w += (i64)(NNODE + 1) * 4;
  int* ssV   = (int*)w; w += (i64)(NHEDGE + 1) * 4;
  int* ssP   = (int*)w; w += 257 * 4;
  int* ssN   = (int*)w; w += (i64)(NN1 + 1) * 4;
  int* nodeL = (int*)w; w += (i64)NN1 * 4;
  int* cntN  = (int*)w; w += (i64)NN1 * 4;
  int* tokE  = (int*)w; w += (i64)NNODE * SE * 4;
  int* tokV  = (int*)w; w += (i64)NHEDGE * SV * 4;
  int* tokP  = (int*)w; w += MPRED * 4;
  int* tokN  = (int*)w; w += (i64)MN1 * 4;
  int* gidN  = (int*)w; w += (i64)MN1 * 4;
  ushort* predHe = (ushort*)w; w += (i64)NPRED * 256 * 2;
  ushort* Ocls = O;
  ushort* Qcls = O + (i64)CHUNK * 256;
  ushort* X2   = O + (i64)2 * CHUNK * 256;
  ushort* X3   = O + (i64)3 * CHUNK * 256;

  f2b_cvt_k<<<512, 256, 0, stream>>>(qkv_w, wq, nq);
  f2b_cvt_k<<<512, 256, 0, stream>>>(out_w, wo, no);
  f2b_cvt_k<<<512, 256, 0, stream>>>(ff1_w, w1, n1);
  f2b_cvt_k<<<512, 256, 0, stream>>>(ff2_w, w2, n2);
  hipMemcpyAsync(unity, unity_in, unity_b, hipMemcpyDeviceToDevice, stream);
  ext_init_k<<<1, 256, 0, stream>>>(ext, pad_emb, cls_emb);

  cnt_k<<<NHEDGE / 256, 256, 0, stream>>>(vmask, ARITY, 1, cntV, NHEDGE);
  scan1_k<<<NHEDGE / 256, 256, 0, stream>>>(cntV, ssV, partV, NHEDGE);
  scan2_k<<<1, 256, 0, stream>>>(partV, NHEDGE / 256, ssV, NHEDGE);
  scan3_k<<<NHEDGE / 256, 256, 0, stream>>>(ssV, partV, vmask, ARITY, 1, tokV, NHEDGE);
  cnt_k<<<NNODE / 256, 256, 0, stream>>>(hmask, SE, 0, cntE, NNODE);
  scan1_k<<<NNODE / 256, 256, 0, stream>>>(cntE, ssE, partE, NNODE);
  scan2_k<<<1, 256, 0, stream>>>(partE, NNODE / 256, ssE, NNODE);
  scan3_k<<<NNODE / 256, 256, 0, stream>>>(ssE, partE, hmask, SE, 0, tokE, NNODE);
  predscan_k<<<1, 256, 0, stream>>>(pred, cntV, vmask, ssP, tokP);
  // hop-1 E2V cone: entity->node inverse, pred-referenced nodes, token CSR
  inv_init_k<<<(NTOTAL + 255) / 256, 256, 0, stream>>>(inv, NTOTAL);
  inv_fill_k<<<NNODE / 256, 256, 0, stream>>>(subg, inv, NNODE);
  prednode_k<<<NN1 / 256, 256, 0, stream>>>(pred, xid, vmask, inv, cntE, nodeL, cntN);
  scan1_k<<<NN1 / 256, 256, 0, stream>>>(cntN, ssN, partN, NN1);
  scan2_k<<<1, 256, 0, stream>>>(partN, NN1 / 256, ssN, NN1);
  scan3n_k<<<NN1 / 256, 256, 0, stream>>>(ssN, partN, hmask, nodeL, tokN);

  for (int k = 0; k < 2; k++) {
    // ---- V2E (full: all hedges feed E2V gathers) ----
    for (int c = 0; c < NHEDGE / CHUNK; c++) {
      const int e0 = c * CHUNK;
      const int* ssc = ssV + e0;
      const int Mmax = CHUNK * SV;
      gather_v2e_k<<<Mmax / 4, 256, 0, stream>>>(unity, pos_tab, xid, xpos,
                                                 tokV, ssc, CHUNK, X);
      gemm_bf16_k<256, 1><<<dim3(6, Mmax / 128), 256, 0, stream>>>(
          X, wq, qkv_b, Y, Mmax, 768, ssc, CHUNK, nullptr);
      attn1_k<SV><<<CHUNK, 16 * SV, 0, stream>>>(Y, ssc, O);
      gemm_ln_k<256><<<Mmax / 128, 512, 0, stream>>>(
          O, wo, out_b, X, 256, ln1_g, ln1_b, X, 256, Mmax, ssc, CHUNK, nullptr);
      gemm_bf16_k<256, 2><<<dim3(8, Mmax / 128), 256, 0, stream>>>(
          X, w1, ff1_b, Y, Mmax, 1024, ssc, CHUNK, nullptr);
      gemm_ln_k<1024><<<Mmax / 128, 512, 0, stream>>>(
          Y, w2, ff2_b, X, 256, ln2_g, ln2_b, X, 256, Mmax, ssc, CHUNK, nullptr);
      gemm_bf16_k<256, 1><<<dim3(4, Mmax / 128), 256, 0, stream>>>(
          X, wq + (i64)768 * 256 + (i64)256 * 256, qkv_b + 768 + 256,
          Y, Mmax, 512, ssc, CHUNK, nullptr);
      gemm_bf16_k<256, 1><<<dim3(2, CHUNK / 128), 256, 0, stream>>>(
          X, wq + (i64)768 * 256, qkv_b + 768, Qcls, CHUNK, 256,
          nullptr, 0, ssc);
      attn_cls_k<SV><<<CHUNK / 16, 256, 0, stream>>>(Qcls, Y, ssc, Ocls);
      gemm_ln_k<256><<<CHUNK / 128, 512, 0, stream>>>(
          Ocls, wo + (i64)256 * 256, out_b + 256, X, 256,
          ln1_g + 256, ln1_b + 256, X2, 256, CHUNK, nullptr, 0, ssc);
      gemm_bf16_k<256, 2><<<dim3(8, CHUNK / 128), 256, 0, stream>>>(
          X2, w1 + (i64)1024 * 256, ff1_b + 1024, Y, CHUNK, 1024,
          nullptr, 0, nullptr);
      gemm_ln_k<1024><<<CHUNK / 128, 512, 0, stream>>>(
          Y, w2 + (i64)256 * 1024, ff2_b + 256, X2, 256,
          ln2_g + 256, ln2_b + 256, ext + (i64)e0 * 256, 256, CHUNK,
          nullptr, 0, nullptr);
    }
    // hedge-QKV dedup table
    gemm_bf16_k<256, 1><<<dim3(6, EXTROWS / 128), 256, 0, stream>>>(
        ext, wq, qkv_b, qkvE, EXTROWS, 768, nullptr, 0, nullptr);
    if (k == 0) {
      // ---- hop-0 E2V: full (all nodes feed hop-1 V2E) ----
      for (int c = 0; c < NNODE / CHUNK; c++) {
        const int n0 = c * CHUNK;
        const int* ssc = ssE + n0;
        const int Mmax = CHUNK * SE;
        gather_e2v_k<<<Mmax / 4, 256, 0, stream>>>(ext, hid, tokE, ssc, CHUNK, X, gid);
        attn1g_k<SE><<<CHUNK, 16 * SE, 0, stream>>>(qkvE, gid, ssc, O);
        gemm_ln_k<256><<<Mmax / 128, 512, 0, stream>>>(
            O, wo, out_b, X, 256, ln1_g, ln1_b, X, 256, Mmax, ssc, CHUNK, nullptr);
        gemm_bf16_k<256, 2><<<dim3(8, Mmax / 128), 256, 0, stream>>>(
            X, w1, ff1_b, Y, Mmax, 1024, ssc, CHUNK, nullptr);
        gemm_ln_k<1024><<<Mmax / 128, 512, 0, stream>>>(
            Y, w2, ff2_b, X, 256, ln2_g, ln2_b, X, 256, Mmax, ssc, CHUNK, nullptr);
        gemm_bf16_k<256, 1><<<dim3(4, Mmax / 128), 256, 0, stream>>>(
            X, wq + (i64)768 * 256 + (i64)256 * 256, qkv_b + 768 + 256,
            Y, Mmax, 512, ssc, CHUNK, nullptr);
        gemm_bf16_k<256, 1><<<dim3(2, CHUNK / 128), 256, 0, stream>>>(
            X, wq + (i64)768 * 256, qkv_b + 768, Qcls, CHUNK, 256,
            nullptr, 0, ssc);
        attn_cls_k<SE><<<CHUNK / 16, 256, 0, stream>>>(Qcls, Y, ssc, Ocls);
        gemm_ln_k<256><<<CHUNK / 128, 512, 0, stream>>>(
            Ocls, wo + (i64)256 * 256, out_b + 256, X, 256,
            ln1_g + 256, ln1_b + 256, X2, 256, CHUNK, nullptr, 0, ssc);
        gemm_bf16_k<256, 2><<<dim3(8, CHUNK / 128), 256, 0, stream>>>(
            X2, w1 + (i64)1024 * 256, ff1_b + 1024, Y, CHUNK, 1024,
            nullptr, 0, nullptr);
        gemm_ln_k<1024><<<CHUNK / 128, 512, 0, stream>>>(
            Y, w2 + (i64)256 * 1024, ff2_b + 256, X2, 256,
            ln2_g + 256, ln2_b + 256, X3, 256, CHUNK, nullptr, 0, nullptr);
        scatter_k<<<CHUNK / 4, 256, 0, stream>>>(X3, subg, unity, n0);
      }
    } else {
      // ---- hop-1 E2V: restricted to the ~2560 nodes in the pred cone ----
      gather_e2vn_k<<<MN1 / 4, 256, 0, stream>>>(ext, hid, nodeL, tokN, ssN, X, gidN);
      attn1g_k<SE><<<NN1, 16 * SE, 0, stream>>>(qkvE, gidN, ssN, O);
      gemm_ln_k<256><<<MN1 / 128, 512, 0, stream>>>(
          O, wo, out_b, X, 256, ln1_g, ln1_b, X, 256, MN1, ssN, NN1, nullptr);
      gemm_bf16_k<256, 2><<<dim3(8, MN1 / 128), 256, 0, stream>>>(
          X, w1, ff1_b, Y, MN1, 1024, ssN, NN1, nullptr);
      gemm_ln_k<1024><<<MN1 / 128, 512, 0, stream>>>(
          Y, w2, ff2_b, X, 256, ln2_g, ln2_b, X, 256, MN1, ssN, NN1, nullptr);
      gemm_bf16_k<256, 1><<<dim3(4, MN1 / 128), 256, 0, stream>>>(
          X, wq + (i64)768 * 256 + (i64)256 * 256, qkv_b + 768 + 256,
          Y, MN1, 512, ssN, NN1, nullptr);
      gemm_bf16_k<256, 1><<<dim3(2, NN1 / 128), 256, 0, stream>>>(
          X, wq + (i64)768 * 256, qkv_b + 768, Qcls, NN1, 256,
          nullptr, 0, ssN);
      attn_cls_k<SE><<<NN1 / 16, 256, 0, stream>>>(Qcls, Y, ssN, Ocls);
      gemm_ln_k<256><<<NN1 / 128, 512, 0, stream>>>(
          Ocls, wo + (i64)256 * 256, out_b + 256, X, 256,
          ln1_g + 256, ln1_b + 256, X2, 256, NN1, nullptr, 0, ssN);
      gemm_bf16_k<256, 2><<<dim3(8, NN1 / 128), 256, 0, stream>>>(
          X2, w1 + (i64)1024 * 256, ff1_b + 1024, Y, NN1, 1024,
          nullptr, 0, nullptr);
      gemm_ln_k<1024><<<NN1 / 128, 512, 0, stream>>>(
          Y, w2 + (i64)256 * 1024, ff2_b + 256, X2, 256,
          ln2_g + 256, ln2_b + 256, X3, 256, NN1, nullptr, 0, nullptr);
      scatter_n_k<<<NN1 / 4, 256, 0, stream>>>(X3, subg, nodeL, unity);
    }
  }

  // ---- hop-2 V2E: ONLY the 256 predicted hedges ----
  {
    const int* ssc = ssP;
    gather_v2e_k<<<MPRED / 4, 256, 0, stream>>>(unity, pos_tab, xid, xpos,
                                                tokP, ssc, NPRED, X);
    gemm_bf16_k<256, 1><<<dim3(6, MPRED / 128), 256, 0, stream>>>(
        X, wq, qkv_b, Y, MPRED, 768, ssc, NPRED, nullptr);
    attn1_k<SV><<<NPRED, 16 * SV, 0, stream>>>(Y, ssc, O);
    gemm_ln_k<256><<<MPRED / 128, 512, 0, stream>>>(
        O, wo, out_b, X, 256, ln1_g, ln1_b, X, 256, MPRED, ssc, NPRED, nullptr);
    gemm_bf16_k<256, 2><<<dim3(8, MPRED / 128), 256, 0, stream>>>(
        X, w1, ff1_b, Y, MPRED, 1024, ssc, NPRED, nullptr);
    gemm_ln_k<1024><<<MPRED / 128, 512, 0, stream>>>(
        Y, w2, ff2_b, X, 256, ln2_g, ln2_b, X, 256, MPRED, ssc, NPRED, nullptr);
    gemm_bf16_k<256, 1><<<dim3(4, MPRED / 128), 256, 0, stream>>>(
        X, wq + (i64)768 * 256 + (i64)256 * 256, qkv_b + 768 + 256,
        Y, MPRED, 512, ssc, NPRED, nullptr);
    gemm_bf16_k<256, 1><<<dim3(2, NPRED / 128), 256, 0, stream>>>(
        X, wq + (i64)768 * 256, qkv_b + 768, Qcls, NPRED, 256,
        nullptr, 0, ssc);
    attn_cls_k<SV><<<NPRED / 16, 256, 0, stream>>>(Qcls, Y, ssc, Ocls);
    gemm_ln_k<256><<<NPRED / 128, 512, 0, stream>>>(
        Ocls, wo + (i64)256 * 256, out_b + 256, X, 256,
        ln1_g + 256, ln1_b + 256, X2, 256, NPRED, nullptr, 0, ssc);
    gemm_bf16_k<256, 2><<<dim3(8, NPRED / 128), 256, 0, stream>>>(
        X2, w1 + (i64)1024 * 256, ff1_b + 1024, Y, NPRED, 1024,
        nullptr, 0, nullptr);
    gemm_ln_k<1024><<<NPRED / 128, 512, 0, stream>>>(
        Y, w2 + (i64)256 * 1024, ff2_b + 256, X2, 256,
        ln2_g + 256, ln2_b + 256, predHe, 256, NPRED, nullptr, 0, nullptr);
  }
  out_cvt_k<<<NPRED / 4, 256, 0, stream>>>(predHe, (float*)d_out);
}

// Round 13
// 7269.366 us; speedup vs baseline: 3.5914x; 1.4808x over previous
//
#include <hip/hip_runtime.h>
#include <stdint.h>

typedef long long i64;
typedef __attribute__((ext_vector_type(8))) short bf16x8;
typedef __attribute__((ext_vector_type(4))) float f32x4;

#define SV 11
#define SE 17
#define ARITY 10
#define NHEDGE 32768
#define NNODE 65536
#define NTOTAL 100000
#define EXTROWS 32896  // NHEDGE+2 padded to 128 multiple
#define NPRED 256
#define MPRED 2816     // NPRED * SV
#define NN1 2560       // NPRED * ARITY  (hop-1 E2V node slots, dup-tolerant)
#define MN1 43520      // NN1 * SE

__device__ __forceinline__ float b2f(ushort u) {
  union { uint32_t i; float f; } v; v.i = (uint32_t)u << 16; return v.f;
}
__device__ __forceinline__ ushort f2b(float f) {
  union { float f; uint32_t i; } v; v.f = f;
  uint32_t u = v.i + 0x7fffu + ((v.i >> 16) & 1u);
  return (ushort)(u >> 16);
}
__device__ __forceinline__ uint pack2(float a, float b) {
  return (uint)f2b(a) | ((uint)f2b(b) << 16);
}
__device__ __forceinline__ void cvt8(uint4 v, float* f) {
  f[0] = b2f((ushort)(v.x & 0xffff)); f[1] = b2f((ushort)(v.x >> 16));
  f[2] = b2f((ushort)(v.y & 0xffff)); f[3] = b2f((ushort)(v.y >> 16));
  f[4] = b2f((ushort)(v.z & 0xffff)); f[5] = b2f((ushort)(v.z >> 16));
  f[6] = b2f((ushort)(v.w & 0xffff)); f[7] = b2f((ushort)(v.w >> 16));
}

__device__ __forceinline__ void gload_lds16(const void* g, void* l) {
  __builtin_amdgcn_global_load_lds((const __attribute__((address_space(1))) void*)g,
                                   (__attribute__((address_space(3))) void*)l, 16, 0, 0);
}

__device__ __forceinline__ int xcd_swizzle(int orig, int nwg) {
  const int xcd = orig & 7, rest = orig >> 3;
  const int q = nwg >> 3, r = nwg & 7;
  return (xcd < r ? xcd * (q + 1) : r * (q + 1) + (xcd - r) * q) + rest;
}

// ================= compaction: count / scan / fill =============================
__global__ __launch_bounds__(256) void zero_k(int* __restrict__ p, int n) {
  const int i = blockIdx.x * 256 + threadIdx.x;
  if (i < n) p[i] = 0;
}

__global__ __launch_bounds__(256) void cnt_k(const int* __restrict__ mask, int width,
                                             int extra, int* __restrict__ cnt, int n) {
  const int i = blockIdx.x * 256 + threadIdx.x;
  if (i >= n) return;
  int c = extra;
  for (int j = 0; j < width; j++) c += (mask[(i64)i * width + j] != 0);
  cnt[i] = c;
}

__global__ __launch_bounds__(256) void scan1_k(const int* __restrict__ cnt,
                                               int* __restrict__ ss,
                                               int* __restrict__ part, int n) {
  __shared__ int sm[256];
  const int i = blockIdx.x * 256 + threadIdx.x;
  const int v = (i < n) ? cnt[i] : 0;
  sm[threadIdx.x] = v;
  __syncthreads();
  for (int o = 1; o < 256; o <<= 1) {
    const int t = (threadIdx.x >= o) ? sm[threadIdx.x - o] : 0;
    __syncthreads();
    sm[threadIdx.x] += t;
    __syncthreads();
  }
  if (i < n) ss[i] = sm[threadIdx.x] - v;  // exclusive, block-local
  if (threadIdx.x == 255) part[blockIdx.x] = sm[255];
}

__global__ __launch_bounds__(256) void scan2_k(int* __restrict__ part, int nb,
                                               int* __restrict__ ss, int n) {
  __shared__ int sm[256];
  const int v = (threadIdx.x < nb) ? part[threadIdx.x] : 0;
  sm[threadIdx.x] = v;
  __syncthreads();
  for (int o = 1; o < 256; o <<= 1) {
    const int t = (threadIdx.x >= o) ? sm[threadIdx.x - o] : 0;
    __syncthreads();
    sm[threadIdx.x] += t;
    __syncthreads();
  }
  if (threadIdx.x < nb) part[threadIdx.x] = sm[threadIdx.x] - v;
  if (threadIdx.x == 255) ss[n] = sm[255];  // absolute total
}

__global__ __launch_bounds__(256) void scan3_k(int* __restrict__ ss,
                                               const int* __restrict__ part,
                                               const int* __restrict__ mask, int width,
                                               int extra, int* __restrict__ tok, int n) {
  const int i = blockIdx.x * 256 + threadIdx.x;
  if (i >= n) return;
  int off = ss[i] + part[blockIdx.x];
  ss[i] = off;
  if (extra) {
    tok[off++] = (i << 5);
    for (int j = 0; j < width; j++)
      if (mask[(i64)i * width + j] != 0) tok[off++] = (i << 5) | (j + 1);
  } else {
    for (int j = 0; j < width; j++)
      if (mask[(i64)i * width + j] != 0) tok[off++] = (i << 5) | j;
  }
}

// ===== pred-pass compaction: 256 predicted edges, single block ================
__global__ __launch_bounds__(256) void predscan_k(const int* __restrict__ pred,
                                                  const int* __restrict__ cntV,
                                                  const int* __restrict__ vmask,
                                                  int* __restrict__ ssP,
                                                  int* __restrict__ tokP) {
  __shared__ int sm[256];
  const int tid = threadIdx.x;
  const int e = pred[tid];
  const int v = cntV[e];
  sm[tid] = v;
  __syncthreads();
  for (int o = 1; o < 256; o <<= 1) {
    const int t = (tid >= o) ? sm[tid - o] : 0;
    __syncthreads();
    sm[tid] += t;
    __syncthreads();
  }
  int off = sm[tid] - v;
  ssP[tid] = off;
  if (tid == 255) ssP[256] = sm[255];
  tokP[off++] = (e << 5);
  for (int j = 0; j < ARITY; j++)
    if (vmask[(i64)e * ARITY + j] != 0) tokP[off++] = (e << 5) | (j + 1);
}

// ===== dependency-cone flags ==================================================
__global__ __launch_bounds__(256) void inv_init_k(int* __restrict__ inv, int n) {
  const int i = blockIdx.x * 256 + threadIdx.x;
  if (i < n) inv[i] = -1;
}
__global__ __launch_bounds__(256) void inv_fill_k(const int* __restrict__ subg,
                                                  int* __restrict__ inv, int n) {
  const int i = blockIdx.x * 256 + threadIdx.x;
  if (i < n) inv[subg[i]] = i;
}
__global__ __launch_bounds__(256) void prednode_k(const int* __restrict__ pred,
                                                  const int* __restrict__ xid,
                                                  const int* __restrict__ vmask,
                                                  const int* __restrict__ inv,
                                                  const int* __restrict__ cntE,
                                                  int* __restrict__ nodeL,
                                                  int* __restrict__ cntN) {
  const int i = blockIdx.x * 256 + threadIdx.x;
  if (i >= NN1) return;
  const int e = pred[i / ARITY], j = i - (i / ARITY) * ARITY;
  int nd = 0;
  if (vmask[(i64)e * ARITY + j] != 0) {
    const int v = inv[xid[(i64)e * ARITY + j]];
    if (v >= 0) nd = v;
  }
  nodeL[i] = nd;
  cntN[i] = cntE[nd];
}
__global__ __launch_bounds__(256) void scan3n_k(int* __restrict__ ss,
                                                const int* __restrict__ part,
                                                const int* __restrict__ hmask,
                                                const int* __restrict__ nodeL,
                                                int* __restrict__ tok) {
  const int i = blockIdx.x * 256 + threadIdx.x;
  if (i >= NN1) return;
  int off = ss[i] + part[blockIdx.x];
  ss[i] = off;
  const int nd = nodeL[i];
  for (int j = 0; j < SE; j++)
    if (hmask[(i64)nd * SE + j] != 0) tok[off++] = (i << 5) | j;
}

// flag hedges needed by hop-1 E2V (races write constant 1 -> benign)
__global__ __launch_bounds__(256) void flagH_k(const int* __restrict__ nodeL,
                                               const int* __restrict__ hmask,
                                               const int* __restrict__ hid,
                                               int* __restrict__ flagH) {
  const int i = blockIdx.x * 256 + threadIdx.x;
  if (i >= NN1 * SE) return;
  const int s = i / SE, j = i - s * SE;
  const int nd = nodeL[s];
  if (hmask[(i64)nd * SE + j] != 0) {
    const int h = hid[(i64)nd * SE + j];
    if (h < NHEDGE) flagH[h] = 1;
  }
}
// flag entities referenced by flagged hedges
__global__ __launch_bounds__(256) void flagE_k(const int* __restrict__ flagH,
                                               const int* __restrict__ vmask,
                                               const int* __restrict__ xid,
                                               int* __restrict__ flagE) {
  const int i = blockIdx.x * 256 + threadIdx.x;
  if (i >= NHEDGE * ARITY) return;
  const int e = i / ARITY, j = i - e * ARITY;
  if (flagH[e] && vmask[(i64)e * ARITY + j] != 0) flagE[xid[(i64)e * ARITY + j]] = 1;
}
__global__ __launch_bounds__(256) void flagN_k(const int* __restrict__ flagE,
                                               const int* __restrict__ subg,
                                               int* __restrict__ cntC) {
  const int n = blockIdx.x * 256 + threadIdx.x;
  if (n < NNODE) cntC[n] = flagE[subg[n]];
}

__global__ __launch_bounds__(256) void fill_list_k(const int* __restrict__ flag,
                                                   const int* __restrict__ pos,
                                                   const int* __restrict__ part,
                                                   int* __restrict__ list, int n) {
  const int i = blockIdx.x * 256 + threadIdx.x;
  if (i < n && flag[i]) list[pos[i] + part[blockIdx.x]] = i;
}

__global__ __launch_bounds__(256) void cnt_list_k(const int* __restrict__ list,
                                                  const int* __restrict__ tot,
                                                  const int* __restrict__ cs,
                                                  int* __restrict__ cd, int n) {
  const int i = blockIdx.x * 256 + threadIdx.x;
  if (i >= n) return;
  cd[i] = (i < tot[0]) ? cs[list[i]] : 0;
}

// token fill for compact hedge list (V2E style: CLS + valid slots)
__global__ __launch_bounds__(256) void tok_hedge_k(int* __restrict__ ss,
                                                   const int* __restrict__ part,
                                                   const int* __restrict__ tot,
                                                   const int* __restrict__ hedgeL,
                                                   const int* __restrict__ vmask,
                                                   int* __restrict__ tok) {
  const int i = blockIdx.x * 256 + threadIdx.x;
  if (i >= NHEDGE) return;
  int off = ss[i] + part[blockIdx.x];
  ss[i] = off;
  if (i >= tot[0]) return;
  const int e = hedgeL[i];
  tok[off++] = (i << 5);
  for (int j = 0; j < ARITY; j++)
    if (vmask[(i64)e * ARITY + j] != 0) tok[off++] = (i << 5) | (j + 1);
}

// token fill for compact node list (E2V style)
__global__ __launch_bounds__(256) void tok_node_k(int* __restrict__ ss,
                                                  const int* __restrict__ part,
                                                  const int* __restrict__ tot,
                                                  const int* __restrict__ nodeL0,
                                                  const int* __restrict__ hmask,
                                                  int* __restrict__ tok) {
  const int i = blockIdx.x * 256 + threadIdx.x;
  if (i >= NNODE) return;
  int off = ss[i] + part[blockIdx.x];
  ss[i] = off;
  if (i >= tot[0]) return;
  const int nd = nodeL0[i];
  for (int j = 0; j < SE; j++)
    if (hmask[(i64)nd * SE + j] != 0) tok[off++] = (i << 5) | j;
}

// per-chunk sequence limits: out[c] = min(total, c*chunk)
__global__ __launch_bounds__(64) void seqlim_k(const int* __restrict__ tot, int chunk,
                                               int nch, int* __restrict__ out) {
  const int c = threadIdx.x;
  if (c <= nch) out[c] = min(tot[0], c * chunk);
}

// ================= 128x128 bf16 MFMA GEMM =====================================
template <int K, int MODE>
__global__ __launch_bounds__(256) void gemm_bf16_k(const ushort* __restrict__ A,
                                                   const ushort* __restrict__ W,
                                                   const float* __restrict__ bias,
                                                   ushort* __restrict__ C, int M, int N,
                                                   const int* ssn, int nseq,
                                                   const int* arp) {
  const int tid = threadIdx.x;
  const int wave = tid >> 6, lane = tid & 63;
  const int nwg = gridDim.x * gridDim.y;
  const int wg = xcd_swizzle(blockIdx.y * gridDim.x + blockIdx.x, nwg);
  const int bx = wg % gridDim.x, by = wg / gridDim.x;
  const int m0 = by << 7, n0 = bx << 7;
  if (ssn && m0 >= ssn[nseq] - ssn[0]) return;
  __shared__ ushort As[128 * 64];
  __shared__ ushort Ws[128 * 64];
  const int wr = wave >> 1, wc = wave & 1;

  f32x4 acc[4][4];
#pragma unroll
  for (int m = 0; m < 4; m++)
#pragma unroll
    for (int n = 0; n < 4; n++) acc[m][n] = (f32x4){0.f, 0.f, 0.f, 0.f};

  const int srow = (wave << 5) + (lane >> 3);
  const int kblk_g = (lane & 7) ^ (lane >> 3);
  const i64 arow = arp ? (i64)(arp[m0 + srow] - arp[0]) : (i64)(m0 + srow);
  const ushort* Ag = A + arow * K + (kblk_g << 3);
  const ushort* Wg = W + (i64)(n0 + srow) * K + (kblk_g << 3);
  char* lA = (char*)As + (wave << 12);
  char* lB = (char*)Ws + (wave << 12);

#pragma unroll
  for (int i = 0; i < 4; i++) {
    gload_lds16(Ag + (i64)(i * 8) * K, lA + i * 1024);
    gload_lds16(Wg + (i64)(i * 8) * K, lB + i * 1024);
  }

  for (int k0 = 0; k0 < K; k0 += 64) {
    __syncthreads();
    bf16x8 af[2][4], bf[2][4];
#pragma unroll
    for (int kh = 0; kh < 2; kh++) {
      const int kb = (kh << 2) + (lane >> 4);
#pragma unroll
      for (int m = 0; m < 4; m++) {
        const int row = (wr << 6) + (m << 4) + (lane & 15);
        af[kh][m] = *(const bf16x8*)&As[row * 64 + ((kb ^ (row & 7)) << 3)];
      }
#pragma unroll
      for (int n = 0; n < 4; n++) {
        const int row = (wc << 6) + (n << 4) + (lane & 15);
        bf[kh][n] = *(const bf16x8*)&Ws[row * 64 + ((kb ^ (row & 7)) << 3)];
      }
    }
    __syncthreads();
    if (k0 + 64 < K) {
#pragma unroll
      for (int i = 0; i < 4; i++) {
        gload_lds16(Ag + (k0 + 64) + (i64)(i * 8) * K, lA + i * 1024);
        gload_lds16(Wg + (k0 + 64) + (i64)(i * 8) * K, lB + i * 1024);
      }
    }
#pragma unroll
    for (int kh = 0; kh < 2; kh++)
#pragma unroll
      for (int m = 0; m < 4; m++)
#pragma unroll
        for (int n = 0; n < 4; n++)
          acc[m][n] = __builtin_amdgcn_mfma_f32_16x16x32_bf16(bf[kh][n], af[kh][m], acc[m][n], 0, 0, 0);
  }

#pragma unroll
  for (int m = 0; m < 4; m++) {
    const int row = m0 + (wr << 6) + (m << 4) + (lane & 15);
#pragma unroll
    for (int n = 0; n < 4; n++) {
      const int col = n0 + (wc << 6) + (n << 4) + ((lane >> 4) << 2);
      float v0 = acc[m][n][0], v1 = acc[m][n][1], v2 = acc[m][n][2], v3 = acc[m][n][3];
      if (MODE > 0) {
        const f32x4 bv = *(const f32x4*)&bias[col];
        v0 += bv[0]; v1 += bv[1]; v2 += bv[2]; v3 += bv[3];
      }
      if (MODE == 2) {
        v0 = fmaxf(v0, 0.f); v1 = fmaxf(v1, 0.f);
        v2 = fmaxf(v2, 0.f); v3 = fmaxf(v3, 0.f);
      }
      uint2 o; o.x = pack2(v0, v1); o.y = pack2(v2, v3);
      *(uint2*)&C[(i64)row * N + col] = o;
    }
  }
}

// ============ Fused GEMM + residual + LayerNorm (N = 256) ======================
template <int K>
__global__ __launch_bounds__(512) void gemm_ln_k(const ushort* __restrict__ A,
                                                 const ushort* __restrict__ W,
                                                 const float* __restrict__ bias,
                                                 const ushort* R, int rstride,
                                                 const float* __restrict__ g,
                                                 const float* __restrict__ b,
                                                 ushort* C, int cstride, int M,
                                                 const int* ssn, int nseq,
                                                 const int* rrp) {
  const int m0 = blockIdx.x << 7;
  if (ssn && m0 >= ssn[nseq] - ssn[0]) return;
  __shared__ ushort As[128 * 64];
  __shared__ ushort Ws[256 * 64];
  __shared__ float partS[128][4];
  __shared__ float partQ[128][4];
  const int tid = threadIdx.x;
  const int wave = tid >> 6, lane = tid & 63;
  const int wr = wave >> 2, wc = wave & 3;

  f32x4 acc[4][4];
#pragma unroll
  for (int m = 0; m < 4; m++)
#pragma unroll
    for (int n = 0; n < 4; n++) acc[m][n] = (f32x4){0.f, 0.f, 0.f, 0.f};

  int rowA[2], kgA[2];
#pragma unroll
  for (int i = 0; i < 2; i++) {
    const int u = wave * 128 + i * 64 + lane;
    rowA[i] = u >> 3; kgA[i] = (u & 7) ^ ((u >> 3) & 7);
  }
  int rowW[4], kgW[4];
#pragma unroll
  for (int i = 0; i < 4; i++) {
    const int u = wave * 256 + i * 64 + lane;
    rowW[i] = u >> 3; kgW[i] = (u & 7) ^ ((u >> 3) & 7);
  }

#pragma unroll
  for (int i = 0; i < 2; i++)
    gload_lds16(A + (i64)(m0 + rowA[i]) * K + (kgA[i] << 3),
                (char*)As + (wave * 128 + i * 64) * 16);
#pragma unroll
  for (int i = 0; i < 4; i++)
    gload_lds16(W + (i64)rowW[i] * K + (kgW[i] << 3),
                (char*)Ws + (wave * 256 + i * 64) * 16);

  for (int k0 = 0; k0 < K; k0 += 64) {
    __syncthreads();
    bf16x8 af[2][4], bf[2][4];
#pragma unroll
    for (int kh = 0; kh < 2; kh++) {
      const int kb = (kh << 2) + (lane >> 4);
#pragma unroll
      for (int m = 0; m < 4; m++) {
        const int row = (wr << 6) + (m << 4) + (lane & 15);
        af[kh][m] = *(const bf16x8*)&As[row * 64 + ((kb ^ (row & 7)) << 3)];
      }
#pragma unroll
      for (int n = 0; n < 4; n++) {
        const int row = (wc << 6) + (n << 4) + (lane & 15);
        bf[kh][n] = *(const bf16x8*)&Ws[row * 64 + ((kb ^ (row & 7)) << 3)];
      }
    }
    __syncthreads();
    if (k0 + 64 < K) {
#pragma unroll
      for (int i = 0; i < 2; i++)
        gload_lds16(A + (i64)(m0 + rowA[i]) * K + (k0 + 64) + (kgA[i] << 3),
                    (char*)As + (wave * 128 + i * 64) * 16);
#pragma unroll
      for (int i = 0; i < 4; i++)
        gload_lds16(W + (i64)rowW[i] * K + (k0 + 64) + (kgW[i] << 3),
                    (char*)Ws + (wave * 256 + i * 64) * 16);
    }
#pragma unroll
    for (int kh = 0; kh < 2; kh++)
#pragma unroll
      for (int m = 0; m < 4; m++)
#pragma unroll
        for (int n = 0; n < 4; n++)
          acc[m][n] = __builtin_amdgcn_mfma_f32_16x16x32_bf16(bf[kh][n], af[kh][m], acc[m][n], 0, 0, 0);
  }

#pragma unroll
  for (int m = 0; m < 4; m++) {
    const int tokl = (wr << 6) + (m << 4) + (lane & 15);
    const int row = m0 + tokl;
    const i64 rr = rrp ? (i64)(rrp[row] - rrp[0]) : (i64)row;
    float s = 0.f, q = 0.f;
#pragma unroll
    for (int n = 0; n < 4; n++) {
      const int col = (wc << 6) + (n << 4) + ((lane >> 4) << 2);
      const f32x4 bv = *(const f32x4*)&bias[col];
      const uint2 ru = *(const uint2*)&R[rr * rstride + col];
      float v0 = acc[m][n][0] + bv[0] + b2f((ushort)(ru.x & 0xffff));
      float v1 = acc[m][n][1] + bv[1] + b2f((ushort)(ru.x >> 16));
      float v2 = acc[m][n][2] + bv[2] + b2f((ushort)(ru.y & 0xffff));
      float v3 = acc[m][n][3] + bv[3] + b2f((ushort)(ru.y >> 16));
      acc[m][n][0] = v0; acc[m][n][1] = v1; acc[m][n][2] = v2; acc[m][n][3] = v3;
      s += v0 + v1 + v2 + v3;
      q += v0 * v0 + v1 * v1 + v2 * v2 + v3 * v3;
    }
    s += __shfl_xor(s, 16, 64); s += __shfl_xor(s, 32, 64);
    q += __shfl_xor(q, 16, 64); q += __shfl_xor(q, 32, 64);
    if (lane < 16) { partS[tokl][wc] = s; partQ[tokl][wc] = q; }
  }
  __syncthreads();
#pragma unroll
  for (int m = 0; m < 4; m++) {
    const int tokl = (wr << 6) + (m << 4) + (lane & 15);
    const i64 row = (i64)(m0 + tokl);
    const f32x4 s4 = *(const f32x4*)&partS[tokl][0];
    const f32x4 q4 = *(const f32x4*)&partQ[tokl][0];
    const float mean = (s4[0] + s4[1] + s4[2] + s4[3]) * (1.f / 256.f);
    const float var = (q4[0] + q4[1] + q4[2] + q4[3]) * (1.f / 256.f) - mean * mean;
    const float rs = rsqrtf(var + 1e-5f);
#pragma unroll
    for (int n = 0; n < 4; n++) {
      const int col = (wc << 6) + (n << 4) + ((lane >> 4) << 2);
      const f32x4 g4 = *(const f32x4*)&g[col];
      const f32x4 b4 = *(const f32x4*)&b[col];
      uint2 o;
      o.x = pack2((acc[m][n][0] - mean) * rs * g4[0] + b4[0],
                  (acc[m][n][1] - mean) * rs * g4[1] + b4[1]);
      o.y = pack2((acc[m][n][2] - mean) * rs * g4[2] + b4[2],
                  (acc[m][n][3] - mean) * rs * g4[3] + b4[3]);
      *(uint2*)&C[row * cstride + col] = o;
    }
  }
}

// ========= Layer-1 attention (compact token rows) =============================
template <int S>
__global__ __launch_bounds__(16 * S) void attn1_k(const ushort* __restrict__ QKV,
                                                  const int* __restrict__ ss,
                                                  ushort* __restrict__ O) {
  __shared__ float KL[4][S][68];
  __shared__ float VL[4][S][68];
  const int tid = threadIdx.x;
  const int s0 = ss[0];
  const int base = ss[blockIdx.x] - s0;
  const int L = ss[blockIdx.x + 1] - ss[blockIdx.x];

  for (int u = tid; u < 128 * L; u += 16 * S) {
    const int d4 = u & 15, h = (u >> 4) & 3, mt = u >> 6;
    const int mat = (mt >= L), t = mat ? mt - L : mt;
    const ushort* gp = QKV + (i64)(base + t) * 768 + 256 + mat * 256 + h * 64 + d4 * 4;
    ushort4 raw = *(const ushort4*)gp;
    float* dst = (mat ? &VL[h][t][0] : &KL[h][t][0]) + d4 * 4;
    dst[0] = b2f(raw.x); dst[1] = b2f(raw.y); dst[2] = b2f(raw.z); dst[3] = b2f(raw.w);
  }
  __syncthreads();

  const int h = tid / (4 * S);
  const int r = tid - h * 4 * S;
  const int q = r >> 2, j = r & 3;
  if (q >= L) return;

  float qv[16];
  {
    const ushort* qp = QKV + (i64)(base + q) * 768 + h * 64 + j * 16;
    cvt8(*(const uint4*)qp, qv);
    cvt8(*(const uint4*)(qp + 8), qv + 8);
  }

  float w[S];
  float mx = -1e30f;
#pragma unroll
  for (int s = 0; s < S; s++) {
    float p = -1e30f;
    if (s < L) {
      const float* kr = &KL[h][s][j * 16];
      p = 0.f;
#pragma unroll
      for (int e = 0; e < 4; e++) {
        const float4 kv = *(const float4*)(kr + e * 4);
        p = fmaf(qv[e * 4 + 0], kv.x, p);
        p = fmaf(qv[e * 4 + 1], kv.y, p);
        p = fmaf(qv[e * 4 + 2], kv.z, p);
        p = fmaf(qv[e * 4 + 3], kv.w, p);
      }
      p += __shfl_xor(p, 1, 64);
      p += __shfl_xor(p, 2, 64);
      p *= 0.125f;
    }
    w[s] = p;
    mx = fmaxf(mx, p);
  }
  float sum = 0.f;
#pragma unroll
  for (int s = 0; s < S; s++) { w[s] = __expf(w[s] - mx); sum += w[s]; }
  const float inv = 1.f / sum;

  float o[16];
#pragma unroll
  for (int e = 0; e < 16; e++) o[e] = 0.f;
#pragma unroll
  for (int s = 0; s < S; s++) {
    if (s < L) {
      const float ws = w[s];
      const float* vr = &VL[h][s][j * 16];
#pragma unroll
      for (int e = 0; e < 4; e++) {
        const float4 vv = *(const float4*)(vr + e * 4);
        o[e * 4 + 0] = fmaf(ws, vv.x, o[e * 4 + 0]);
        o[e * 4 + 1] = fmaf(ws, vv.y, o[e * 4 + 1]);
        o[e * 4 + 2] = fmaf(ws, vv.z, o[e * 4 + 2]);
        o[e * 4 + 3] = fmaf(ws, vv.w, o[e * 4 + 3]);
      }
    }
  }
  uint4 st0, st1;
  st0.x = pack2(o[0] * inv, o[1] * inv);   st0.y = pack2(o[2] * inv, o[3] * inv);
  st0.z = pack2(o[4] * inv, o[5] * inv);   st0.w = pack2(o[6] * inv, o[7] * inv);
  st1.x = pack2(o[8] * inv, o[9] * inv);   st1.y = pack2(o[10] * inv, o[11] * inv);
  st1.z = pack2(o[12] * inv, o[13] * inv); st1.w = pack2(o[14] * inv, o[15] * inv);
  ushort* op = O + (i64)(base + q) * 256 + h * 64 + j * 16;
  *(uint4*)op = st0;
  *(uint4*)(op + 8) = st1;
}

// ========= Layer-1 attention, E2V: QKV gathered from hedge table ==============
template <int S>
__global__ __launch_bounds__(16 * S) void attn1g_k(const ushort* __restrict__ QKVE,
                                                   const int* __restrict__ gid,
                                                   const int* __restrict__ ss,
                                                   ushort* __restrict__ O) {
  __shared__ float KL[4][S][68];
  __shared__ float VL[4][S][68];
  __shared__ int ids[S];
  const int tid = threadIdx.x;
  const int s0 = ss[0];
  const int base = ss[blockIdx.x] - s0;
  const int L = ss[blockIdx.x + 1] - ss[blockIdx.x];

  if (tid < L) ids[tid] = gid[base + tid];
  __syncthreads();

  for (int u = tid; u < 128 * L; u += 16 * S) {
    const int d4 = u & 15, h = (u >> 4) & 3, mt = u >> 6;
    const int mat = (mt >= L), t = mat ? mt - L : mt;
    const ushort* gp = QKVE + (i64)ids[t] * 768 + 256 + mat * 256 + h * 64 + d4 * 4;
    ushort4 raw = *(const ushort4*)gp;
    float* dst = (mat ? &VL[h][t][0] : &KL[h][t][0]) + d4 * 4;
    dst[0] = b2f(raw.x); dst[1] = b2f(raw.y); dst[2] = b2f(raw.z); dst[3] = b2f(raw.w);
  }
  __syncthreads();

  const int h = tid / (4 * S);
  const int r = tid - h * 4 * S;
  const int q = r >> 2, j = r & 3;
  if (q >= L) return;

  float qv[16];
  {
    const ushort* qp = QKVE + (i64)ids[q] * 768 + h * 64 + j * 16;
    cvt8(*(const uint4*)qp, qv);
    cvt8(*(const uint4*)(qp + 8), qv + 8);
  }

  float w[S];
  float mx = -1e30f;
#pragma unroll
  for (int s = 0; s < S; s++) {
    float p = -1e30f;
    if (s < L) {
      const float* kr = &KL[h][s][j * 16];
      p = 0.f;
#pragma unroll
      for (int e = 0; e < 4; e++) {
        const float4 kv = *(const float4*)(kr + e * 4);
        p = fmaf(qv[e * 4 + 0], kv.x, p);
        p = fmaf(qv[e * 4 + 1], kv.y, p);
        p = fmaf(qv[e * 4 + 2], kv.z, p);
        p = fmaf(qv[e * 4 + 3], kv.w, p);
      }
      p += __shfl_xor(p, 1, 64);
      p += __shfl_xor(p, 2, 64);
      p *= 0.125f;
    }
    w[s] = p;
    mx = fmaxf(mx, p);
  }
  float sum = 0.f;
#pragma unroll
  for (int s = 0; s < S; s++) { w[s] = __expf(w[s] - mx); sum += w[s]; }
  const float inv = 1.f / sum;

  float o[16];
#pragma unroll
  for (int e = 0; e < 16; e++) o[e] = 0.f;
#pragma unroll
  for (int s = 0; s < S; s++) {
    if (s < L) {
      const float ws = w[s];
      const float* vr = &VL[h][s][j * 16];
#pragma unroll
      for (int e = 0; e < 4; e++) {
        const float4 vv = *(const float4*)(vr + e * 4);
        o[e * 4 + 0] = fmaf(ws, vv.x, o[e * 4 + 0]);
        o[e * 4 + 1] = fmaf(ws, vv.y, o[e * 4 + 1]);
        o[e * 4 + 2] = fmaf(ws, vv.z, o[e * 4 + 2]);
        o[e * 4 + 3] = fmaf(ws, vv.w, o[e * 4 + 3]);
      }
    }
  }
  uint4 st0, st1;
  st0.x = pack2(o[0] * inv, o[1] * inv);   st0.y = pack2(o[2] * inv, o[3] * inv);
  st0.z = pack2(o[4] * inv, o[5] * inv);   st0.w = pack2(o[6] * inv, o[7] * inv);
  st1.x = pack2(o[8] * inv, o[9] * inv);   st1.y = pack2(o[10] * inv, o[11] * inv);
  st1.z = pack2(o[12] * inv, o[13] * inv); st1.w = pack2(o[14] * inv, o[15] * inv);
  ushort* op = O + (i64)(base + q) * 256 + h * 64 + j * 16;
  *(uint4*)op = st0;
  *(uint4*)(op + 8) = st1;
}

// ===== Layer-2 attention, CLS query ===========================================
template <int S>
__global__ __launch_bounds__(256) void attn_cls_k(const ushort* __restrict__ Qc,
                                                  const ushort* __restrict__ KV,
                                                  const int* __restrict__ ss,
                                                  ushort* __restrict__ Ocls) {
  const int tid = threadIdx.x;
  const int sl = tid >> 4, h = (tid >> 2) & 3, j = tid & 3;
  const int seq = blockIdx.x * 16 + sl;
  const int base = ss[seq] - ss[0];
  const int L = ss[seq + 1] - ss[seq];

  float qv[16];
  {
    const ushort* qp = Qc + (i64)seq * 256 + h * 64 + j * 16;
    cvt8(*(const uint4*)qp, qv);
    cvt8(*(const uint4*)(qp + 8), qv + 8);
  }
  float w[S];
  float mx = -1e30f;
#pragma unroll
  for (int s = 0; s < S; s++) {
    float p = -1e30f;
    if (s < L) {
      float kf[16];
      const ushort* kp = KV + (i64)(base + s) * 512 + h * 64 + j * 16;
      cvt8(*(const uint4*)kp, kf);
      cvt8(*(const uint4*)(kp + 8), kf + 8);
      p = 0.f;
#pragma unroll
      for (int e = 0; e < 16; e++) p = fmaf(qv[e], kf[e], p);
      p += __shfl_xor(p, 1, 64);
      p += __shfl_xor(p, 2, 64);
      p *= 0.125f;
    }
    w[s] = p;
    mx = fmaxf(mx, p);
  }
  float sum = 0.f;
#pragma unroll
  for (int s = 0; s < S; s++) { w[s] = __expf(w[s] - mx); sum += w[s]; }
  const float inv = 1.f / sum;

  float o[16];
#pragma unroll
  for (int e = 0; e < 16; e++) o[e] = 0.f;
#pragma unroll
  for (int s = 0; s < S; s++) {
    if (s < L) {
      float vf[16];
      const ushort* vp = KV + (i64)(base + s) * 512 + 256 + h * 64 + j * 16;
      cvt8(*(const uint4*)vp, vf);
      cvt8(*(const uint4*)(vp + 8), vf + 8);
      const float ws = w[s];
#pragma unroll
      for (int e = 0; e < 16; e++) o[e] = fmaf(ws, vf[e], o[e]);
    }
  }
  uint4 st0, st1;
  st0.x = pack2(o[0] * inv, o[1] * inv);   st0.y = pack2(o[2] * inv, o[3] * inv);
  st0.z = pack2(o[4] * inv, o[5] * inv);   st0.w = pack2(o[6] * inv, o[7] * inv);
  st1.x = pack2(o[8] * inv, o[9] * inv);   st1.y = pack2(o[10] * inv, o[11] * inv);
  st1.z = pack2(o[12] * inv, o[13] * inv); st1.w = pack2(o[14] * inv, o[15] * inv);
  ushort* op = Ocls + (i64)seq * 256 + h * 64 + j * 16;
  *(uint4*)op = st0;
  *(uint4*)(op + 8) = st1;
}

// ================= gathers / scatters / conversion =============================
__global__ __launch_bounds__(256) void f2b_cvt_k(const float* __restrict__ in,
                                                 ushort* __restrict__ out, int n) {
  for (int i = blockIdx.x * 256 + threadIdx.x; i < n; i += gridDim.x * 256)
    out[i] = f2b(in[i]);
}

__global__ __launch_bounds__(256) void gather_v2e_k(const float* __restrict__ unity,
                                                    const float* __restrict__ pos,
                                                    const int* __restrict__ xid,
                                                    const int* __restrict__ xpos,
                                                    const int* __restrict__ tok,
                                                    const int* __restrict__ ss, int nseq,
                                                    ushort* __restrict__ X) {
  const int t = blockIdx.x * 4 + (threadIdx.x >> 6);
  const int lane = threadIdx.x & 63;
  const int s0 = ss[0];
  if (t >= ss[nseq] - s0) return;
  const int code = tok[s0 + t];
  const int e = code >> 5, slot = code & 31;
  float4 v = make_float4(0.f, 0.f, 0.f, 0.f);
  if (slot > 0) {
    const int id = xid[(i64)e * ARITY + (slot - 1)];
    v = *(const float4*)&unity[(i64)id * 256 + lane * 4];
  }
  const int pp = xpos[(i64)e * SV + slot];
  const float4 pv = *(const float4*)&pos[(i64)pp * 256 + lane * 4];
  uint2 o;
  o.x = pack2(v.x + pv.x, v.y + pv.y);
  o.y = pack2(v.z + pv.z, v.w + pv.w);
  *(uint2*)&X[(i64)t * 256 + lane * 4] = o;
}

// restricted V2E gather: compact seq -> hedge via hedgeL
__global__ __launch_bounds__(256) void gather_v2eh_k(const float* __restrict__ unity,
                                                     const float* __restrict__ pos,
                                                     const int* __restrict__ xid,
                                                     const int* __restrict__ xpos,
                                                     const int* __restrict__ hedgeL,
                                                     const int* __restrict__ tok,
                                                     const int* __restrict__ ss, int nseq,
                                                     ushort* __restrict__ X) {
  const int t = blockIdx.x * 4 + (threadIdx.x >> 6);
  const int lane = threadIdx.x & 63;
  const int s0 = ss[0];
  if (t >= ss[nseq] - s0) return;
  const int code = tok[s0 + t];
  const int e = hedgeL[code >> 5], slot = code & 31;
  float4 v = make_float4(0.f, 0.f, 0.f, 0.f);
  if (slot > 0) {
    const int id = xid[(i64)e * ARITY + (slot - 1)];
    v = *(const float4*)&unity[(i64)id * 256 + lane * 4];
  }
  const int pp = xpos[(i64)e * SV + slot];
  const float4 pv = *(const float4*)&pos[(i64)pp * 256 + lane * 4];
  uint2 o;
  o.x = pack2(v.x + pv.x, v.y + pv.y);
  o.y = pack2(v.z + pv.z, v.w + pv.w);
  *(uint2*)&X[(i64)t * 256 + lane * 4] = o;
}

// restricted E2V gather: compact seq -> node via nodeL0 (or nodeL for hop-1)
__global__ __launch_bounds__(256) void gather_e2vc_k(const ushort* __restrict__ ext,
                                                     const int* __restrict__ hid,
                                                     const int* __restrict__ nodeL,
                                                     const int* __restrict__ tok,
                                                     const int* __restrict__ ss, int nseq,
                                                     ushort* __restrict__ X,
                                                     int* __restrict__ gid) {
  const int t = blockIdx.x * 4 + (threadIdx.x >> 6);
  const int lane = threadIdx.x & 63;
  const int s0 = ss[0];
  if (t >= ss[nseq] - s0) return;
  const int code = tok[s0 + t];
  const int id = hid[(i64)nodeL[code >> 5] * SE + (code & 31)];
  if (lane == 0) gid[t] = id;
  *(uint2*)&X[(i64)t * 256 + lane * 4] =
      *(const uint2*)&ext[(i64)id * 256 + lane * 4];
}

// scatter compact he rows into ext (restricted hop-1 V2E)
__global__ __launch_bounds__(256) void scatter_ext_k(const ushort* __restrict__ Xc,
                                                     const int* __restrict__ hedgeL,
                                                     const int* __restrict__ tot,
                                                     ushort* __restrict__ ext, int base) {
  const int il = blockIdx.x * 4 + (threadIdx.x >> 6);
  const int lane = threadIdx.x & 63;
  const int i = base + il;
  if (i >= tot[0]) return;
  *(uint2*)&ext[(i64)hedgeL[i] * 256 + lane * 4] =
      *(const uint2*)&Xc[(i64)il * 256 + lane * 4];
}

// scatter compact node rows into unity (restricted E2V)
__global__ __launch_bounds__(256) void scatter_nc_k(const ushort* __restrict__ Xc,
                                                    const int* __restrict__ subg,
                                                    const int* __restrict__ nodeL,
                                                    const int* __restrict__ tot,
                                                    float* __restrict__ unity, int base) {
  const int il = blockIdx.x * 4 + (threadIdx.x >> 6);
  const int lane = threadIdx.x & 63;
  const int i = base + il;
  if (tot && i >= tot[0]) return;
  const int dst = subg[nodeL[i]];
  ushort4 v = *(const ushort4*)&Xc[(i64)il * 256 + lane * 4];
  float4 o; o.x = b2f(v.x); o.y = b2f(v.y); o.z = b2f(v.z); o.w = b2f(v.w);
  *(float4*)&unity[(i64)dst * 256 + lane * 4] = o;
}

__global__ __launch_bounds__(256) void ext_init_k(ushort* __restrict__ ext,
                                                  const float* __restrict__ pad,
                                                  const float* __restrict__ cls) {
  const int d = threadIdx.x;
  ext[(i64)NHEDGE * 256 + d] = f2b(pad[d]);
  ext[(i64)(NHEDGE + 1) * 256 + d] = f2b(cls[d]);
  for (int r = NHEDGE + 2; r < EXTROWS; r += 1)
    ext[(i64)r * 256 + d] = 0;
}

__global__ __launch_bounds__(256) void out_cvt_k(const ushort* __restrict__ predHe,
                                                 float* __restrict__ out) {
  const int i = blockIdx.x * 4 + (threadIdx.x >> 6);
  const int lane = threadIdx.x & 63;
  ushort4 v = *(const ushort4*)&predHe[(i64)i * 256 + lane * 4];
  float4 o; o.x = b2f(v.x); o.y = b2f(v.y); o.z = b2f(v.z); o.w = b2f(v.w);
  *(float4*)&out[(i64)i * 256 + lane * 4] = o;
}

// ================= host orchestration ==========================================
extern "C" void kernel_launch(void* const* d_in, const int* in_sizes, int n_in,
                              void* d_out, int out_size, void* d_ws, size_t ws_size,
                              hipStream_t stream) {
  (void)in_sizes; (void)n_in; (void)out_size;
  const float* unity_in = (const float*)d_in[0];
  const float* cls_emb  = (const float*)d_in[1];
  const float* pad_emb  = (const float*)d_in[2];
  const float* pos_tab  = (const float*)d_in[3];
  const float* qkv_w    = (const float*)d_in[4];
  const float* qkv_b    = (const float*)d_in[5];
  const float* out_w    = (const float*)d_in[6];
  const float* out_b    = (const float*)d_in[7];
  const float* ln1_g    = (const float*)d_in[8];
  const float* ln1_b    = (const float*)d_in[9];
  const float* ln2_g    = (const float*)d_in[10];
  const float* ln2_b    = (const float*)d_in[11];
  const float* ff1_w    = (const float*)d_in[12];
  const float* ff1_b    = (const float*)d_in[13];
  const float* ff2_w    = (const float*)d_in[14];
  const float* ff2_b    = (const float*)d_in[15];
  const int* xid   = (const int*)d_in[16];
  const int* vmask = (const int*)d_in[17];
  const int* xpos  = (const int*)d_in[18];
  const int* hid   = (const int*)d_in[19];
  const int* hmask = (const int*)d_in[20];
  const int* subg  = (const int*)d_in[21];
  const int* pred  = (const int*)d_in[22];

  const i64 unity_b = (i64)NTOTAL * 256 * 4;
  const i64 ext_b   = (i64)EXTROWS * 256 * 2;
  const i64 qkvE_b  = (i64)EXTROWS * 768 * 2;
  const int nq = 2 * 768 * 256, no = 2 * 256 * 256,
            n1 = 2 * 1024 * 256, n2 = 2 * 256 * 1024;
  const i64 wts_b = (i64)(nq + no + n1 + n2) * 2;
  const i64 idx_b = 16 * 1024 * 1024;  // generous bound for all index arrays
  const i64 per_elem = (i64)SE * (512 + 2048 + 512 + 4);
  int CHUNK = 8192;
  while (CHUNK > 4096 &&
         unity_b + ext_b + qkvE_b + wts_b + idx_b + (i64)CHUNK * per_elem > (i64)ws_size)
    CHUNK >>= 1;
  const int NCH_H = NHEDGE / CHUNK;   // V2E chunks
  const int NCH_N = NNODE / CHUNK;    // E2V chunks

  char* w = (char*)d_ws;
  float*  unity = (float*)w;  w += unity_b;
  ushort* ext   = (ushort*)w; w += ext_b;
  ushort* qkvE  = (ushort*)w; w += qkvE_b;
  ushort* wq    = (ushort*)w; w += (i64)nq * 2;
  ushort* wo    = (ushort*)w; w += (i64)no * 2;
  ushort* w1    = (ushort*)w; w += (i64)n1 * 2;
  ushort* w2    = (ushort*)w; w += (i64)n2 * 2;
  ushort* X     = (ushort*)w; w += (i64)CHUNK * SE * 256 * 2;
  ushort* Y     = (ushort*)w; w += (i64)CHUNK * SE * 1024 * 2;
  ushort* O     = (ushort*)w; w += (i64)CHUNK * SE * 256 * 2;
  int* gid    = (int*)w; w += (i64)CHUNK * SE * 4;
  int* inv    = (int*)w; w += (i64)NTOTAL * 4;
  int* cntE   = (int*)w; w += (i64)NNODE * 4;
  int* cntV   = (int*)w; w += (i64)NHEDGE * 4;
  int* partV  = (int*)w; w += 256 * 4;
  int* partN  = (int*)w; w += 256 * 4;
  int* partA  = (int*)w; w += 256 * 4;
  int* partB  = (int*)w; w += 256 * 4;
  int* ssV    = (int*)w; w += (i64)(NHEDGE + 1) * 4;
  int* ssP    = (int*)w; w += 257 * 4;
  int* ssN    = (int*)w; w += (i64)(NN1 + 1) * 4;
  int* nodeL  = (int*)w; w += (i64)NN1 * 4;
  int* cntN   = (int*)w; w += (i64)NN1 * 4;
  int* tokV   = (int*)w; w += (i64)NHEDGE * SV * 4;
  int* tokP   = (int*)w; w += MPRED * 4;
  int* tokN   = (int*)w; w += (i64)MN1 * 4;
  int* gidN   = (int*)w; w += (i64)MN1 * 4;
  int* flagH  = (int*)w; w += (i64)NHEDGE * 4;
  int* flagE  = (int*)w; w += (i64)NTOTAL * 4;
  int* posH   = (int*)w; w += (i64)(NHEDGE + 1) * 4;
  int* posN   = (int*)w; w += (i64)(NNODE + 1) * 4;
  int* hedgeL = (int*)w; w += (i64)NHEDGE * 4;
  int* nodeL0 = (int*)w; w += (i64)NNODE * 4;
  int* cntB   = (int*)w; w += (i64)NHEDGE * 4;
  int* cntC   = (int*)w; w += (i64)NNODE * 4;
  int* cntD   = (int*)w; w += (i64)NNODE * 4;
  int* ssH    = (int*)w; w += (i64)(NHEDGE + 1) * 4;
  int* ssN0   = (int*)w; w += (i64)(NNODE + 1) * 4;
  int* tokH   = (int*)w; w += (i64)NHEDGE * SV * 4;
  int* tokN0  = (int*)w; w += (i64)NNODE * SE * 4;
  int* ssHseq = (int*)w; w += 16 * 4;
  int* ssNseq = (int*)w; w += 16 * 4;
  ushort* predHe = (ushort*)w; w += (i64)NPRED * 256 * 2;
  ushort* Ocls = O;
  ushort* Qcls = O + (i64)CHUNK * 256;
  ushort* X2   = O + (i64)2 * CHUNK * 256;
  ushort* X3   = O + (i64)3 * CHUNK * 256;

  f2b_cvt_k<<<512, 256, 0, stream>>>(qkv_w, wq, nq);
  f2b_cvt_k<<<512, 256, 0, stream>>>(out_w, wo, no);
  f2b_cvt_k<<<512, 256, 0, stream>>>(ff1_w, w1, n1);
  f2b_cvt_k<<<512, 256, 0, stream>>>(ff2_w, w2, n2);
  hipMemcpyAsync(unity, unity_in, unity_b, hipMemcpyDeviceToDevice, stream);
  ext_init_k<<<1, 256, 0, stream>>>(ext, pad_emb, cls_emb);

  // ---- index prep (all from static inputs) ----
  cnt_k<<<NHEDGE / 256, 256, 0, stream>>>(vmask, ARITY, 1, cntV, NHEDGE);
  scan1_k<<<NHEDGE / 256, 256, 0, stream>>>(cntV, ssV, partV, NHEDGE);
  scan2_k<<<1, 256, 0, stream>>>(partV, NHEDGE / 256, ssV, NHEDGE);
  scan3_k<<<NHEDGE / 256, 256, 0, stream>>>(ssV, partV, vmask, ARITY, 1, tokV, NHEDGE);
  cnt_k<<<NNODE / 256, 256, 0, stream>>>(hmask, SE, 0, cntE, NNODE);
  predscan_k<<<1, 256, 0, stream>>>(pred, cntV, vmask, ssP, tokP);
  inv_init_k<<<(NTOTAL + 255) / 256, 256, 0, stream>>>(inv, NTOTAL);
  inv_fill_k<<<NNODE / 256, 256, 0, stream>>>(subg, inv, NNODE);
  prednode_k<<<NN1 / 256, 256, 0, stream>>>(pred, xid, vmask, inv, cntE, nodeL, cntN);
  scan1_k<<<NN1 / 256, 256, 0, stream>>>(cntN, ssN, partN, NN1);
  scan2_k<<<1, 256, 0, stream>>>(partN, NN1 / 256, ssN, NN1);
  scan3n_k<<<NN1 / 256, 256, 0, stream>>>(ssN, partN, hmask, nodeL, tokN);
  // cascade flags: hedges needed by hop-1 E2V; nodes needed by hop-1 V2E
  zero_k<<<NHEDGE / 256, 256, 0, stream>>>(flagH, NHEDGE);
  zero_k<<<(NTOTAL + 255) / 256, 256, 0, stream>>>(flagE, NTOTAL);
  flagH_k<<<(NN1 * SE + 255) / 256, 256, 0, stream>>>(nodeL, hmask, hid, flagH);
  flagE_k<<<NHEDGE * ARITY / 256, 256, 0, stream>>>(flagH, vmask, xid, flagE);
  flagN_k<<<NNODE / 256, 256, 0, stream>>>(flagE, subg, cntC);
  // compact hedge list + CSR
  scan1_k<<<NHEDGE / 256, 256, 0, stream>>>(flagH, posH, partA, NHEDGE);
  scan2_k<<<1, 256, 0, stream>>>(partA, NHEDGE / 256, posH, NHEDGE);
  fill_list_k<<<NHEDGE / 256, 256, 0, stream>>>(flagH, posH, partA, hedgeL, NHEDGE);
  cnt_list_k<<<NHEDGE / 256, 256, 0, stream>>>(hedgeL, posH + NHEDGE, cntV, cntB, NHEDGE);
  scan1_k<<<NHEDGE / 256, 256, 0, stream>>>(cntB, ssH, partA, NHEDGE);
  scan2_k<<<1, 256, 0, stream>>>(partA, NHEDGE / 256, ssH, NHEDGE);
  tok_hedge_k<<<NHEDGE / 256, 256, 0, stream>>>(ssH, partA, posH + NHEDGE, hedgeL, vmask, tokH);
  // compact node list + CSR
  scan1_k<<<NNODE / 256, 256, 0, stream>>>(cntC, posN, partB, NNODE);
  scan2_k<<<1, 256, 0, stream>>>(partB, NNODE / 256, posN, NNODE);
  fill_list_k<<<NNODE / 256, 256, 0, stream>>>(cntC, posN, partB, nodeL0, NNODE);
  cnt_list_k<<<NNODE / 256, 256, 0, stream>>>(nodeL0, posN + NNODE, cntE, cntD, NNODE);
  scan1_k<<<NNODE / 256, 256, 0, stream>>>(cntD, ssN0, partB, NNODE);
  scan2_k<<<1, 256, 0, stream>>>(partB, NNODE / 256, ssN0, NNODE);
  tok_node_k<<<NNODE / 256, 256, 0, stream>>>(ssN0, partB, posN + NNODE, nodeL0, hmask, tokN0);
  seqlim_k<<<1, 64, 0, stream>>>(posH + NHEDGE, CHUNK, NCH_H, ssHseq);
  seqlim_k<<<1, 64, 0, stream>>>(posN + NNODE, CHUNK, NCH_N, ssNseq);

  const i64 KVo = (i64)768 * 256 + (i64)256 * 256;
  const i64 Qo  = (i64)768 * 256;

  // ================= hop 0: full V2E =================
  for (int c = 0; c < NCH_H; c++) {
    const int e0 = c * CHUNK;
    const int* ssc = ssV + e0;
    const int Mmax = CHUNK * SV;
    gather_v2e_k<<<Mmax / 4, 256, 0, stream>>>(unity, pos_tab, xid, xpos,
                                               tokV, ssc, CHUNK, X);
    gemm_bf16_k<256, 1><<<dim3(6, Mmax / 128), 256, 0, stream>>>(
        X, wq, qkv_b, Y, Mmax, 768, ssc, CHUNK, nullptr);
    attn1_k<SV><<<CHUNK, 16 * SV, 0, stream>>>(Y, ssc, O);
    gemm_ln_k<256><<<Mmax / 128, 512, 0, stream>>>(
        O, wo, out_b, X, 256, ln1_g, ln1_b, X, 256, Mmax, ssc, CHUNK, nullptr);
    gemm_bf16_k<256, 2><<<dim3(8, Mmax / 128), 256, 0, stream>>>(
        X, w1, ff1_b, Y, Mmax, 1024, ssc, CHUNK, nullptr);
    gemm_ln_k<1024><<<Mmax / 128, 512, 0, stream>>>(
        Y, w2, ff2_b, X, 256, ln2_g, ln2_b, X, 256, Mmax, ssc, CHUNK, nullptr);
    gemm_bf16_k<256, 1><<<dim3(4, Mmax / 128), 256, 0, stream>>>(
        X, wq + KVo, qkv_b + 768 + 256, Y, Mmax, 512, ssc, CHUNK, nullptr);
    gemm_bf16_k<256, 1><<<dim3(2, CHUNK / 128), 256, 0, stream>>>(
        X, wq + Qo, qkv_b + 768, Qcls, CHUNK, 256, nullptr, 0, ssc);
    attn_cls_k<SV><<<CHUNK / 16, 256, 0, stream>>>(Qcls, Y, ssc, Ocls);
    gemm_ln_k<256><<<CHUNK / 128, 512, 0, stream>>>(
        Ocls, wo + (i64)256 * 256, out_b + 256, X, 256,
        ln1_g + 256, ln1_b + 256, X2, 256, CHUNK, nullptr, 0, ssc);
    gemm_bf16_k<256, 2><<<dim3(8, CHUNK / 128), 256, 0, stream>>>(
        X2, w1 + (i64)1024 * 256, ff1_b + 1024, Y, CHUNK, 1024, nullptr, 0, nullptr);
    gemm_ln_k<1024><<<CHUNK / 128, 512, 0, stream>>>(
        Y, w2 + (i64)256 * 1024, ff2_b + 256, X2, 256,
        ln2_g + 256, ln2_b + 256, ext + (i64)e0 * 256, 256, CHUNK, nullptr, 0, nullptr);
  }
  gemm_bf16_k<256, 1><<<dim3(6, EXTROWS / 128), 256, 0, stream>>>(
      ext, wq, qkv_b, qkvE, EXTROWS, 768, nullptr, 0, nullptr);

  // ================= hop 0: E2V restricted to flagged nodes =================
  for (int c = 0; c < NCH_N; c++) {
    const int base = c * CHUNK;
    const int* ssc = ssN0 + base;
    const int* sqc = ssNseq + c;
    const int Mmax = CHUNK * SE;
    gather_e2vc_k<<<Mmax / 4, 256, 0, stream>>>(ext, hid, nodeL0, tokN0, ssc, CHUNK, X, gid);
    attn1g_k<SE><<<CHUNK, 16 * SE, 0, stream>>>(qkvE, gid, ssc, O);
    gemm_ln_k<256><<<Mmax / 128, 512, 0, stream>>>(
        O, wo, out_b, X, 256, ln1_g, ln1_b, X, 256, Mmax, ssc, CHUNK, nullptr);
    gemm_bf16_k<256, 2><<<dim3(8, Mmax / 128), 256, 0, stream>>>(
        X, w1, ff1_b, Y, Mmax, 1024, ssc, CHUNK, nullptr);
    gemm_ln_k<1024><<<Mmax / 128, 512, 0, stream>>>(
        Y, w2, ff2_b, X, 256, ln2_g, ln2_b, X, 256, Mmax, ssc, CHUNK, nullptr);
    gemm_bf16_k<256, 1><<<dim3(4, Mmax / 128), 256, 0, stream>>>(
        X, wq + KVo, qkv_b + 768 + 256, Y, Mmax, 512, ssc, CHUNK, nullptr);
    gemm_bf16_k<256, 1><<<dim3(2, CHUNK / 128), 256, 0, stream>>>(
        X, wq + Qo, qkv_b + 768, Qcls, CHUNK, 256, sqc, 1, ssc);
    attn_cls_k<SE><<<CHUNK / 16, 256, 0, stream>>>(Qcls, Y, ssc, Ocls);
    gemm_ln_k<256><<<CHUNK / 128, 512, 0, stream>>>(
        Ocls, wo + (i64)256 * 256, out_b + 256, X, 256,
        ln1_g + 256, ln1_b + 256, X2, 256, CHUNK, sqc, 1, ssc);
    gemm_bf16_k<256, 2><<<dim3(8, CHUNK / 128), 256, 0, stream>>>(
        X2, w1 + (i64)1024 * 256, ff1_b + 1024, Y, CHUNK, 1024, sqc, 1, nullptr);
    gemm_ln_k<1024><<<CHUNK / 128, 512, 0, stream>>>(
        Y, w2 + (i64)256 * 1024, ff2_b + 256, X2, 256,
        ln2_g + 256, ln2_b + 256, X3, 256, CHUNK, sqc, 1, nullptr);
    scatter_nc_k<<<CHUNK / 4, 256, 0, stream>>>(X3, subg, nodeL0, posN + NNODE,
                                                unity, base);
  }

  // ================= hop 1: V2E restricted to flagged hedges =================
  for (int c = 0; c < NCH_H; c++) {
    const int base = c * CHUNK;
    const int* ssc = ssH + base;
    const int* sqc = ssHseq + c;
    const int Mmax = CHUNK * SV;
    gather_v2eh_k<<<Mmax / 4, 256, 0, stream>>>(unity, pos_tab, xid, xpos,
                                                hedgeL, tokH, ssc, CHUNK, X);
    gemm_bf16_k<256, 1><<<dim3(6, Mmax / 128), 256, 0, stream>>>(
        X, wq, qkv_b, Y, Mmax, 768, ssc, CHUNK, nullptr);
    attn1_k<SV><<<CHUNK, 16 * SV, 0, stream>>>(Y, ssc, O);
    gemm_ln_k<256><<<Mmax / 128, 512, 0, stream>>>(
        O, wo, out_b, X, 256, ln1_g, ln1_b, X, 256, Mmax, ssc, CHUNK, nullptr);
    gemm_bf16_k<256, 2><<<dim3(8, Mmax / 128), 256, 0, stream>>>(
        X, w1, ff1_b, Y, Mmax, 1024, ssc, CHUNK, nullptr);
    gemm_ln_k<1024><<<Mmax / 128, 512, 0, stream>>>(
        Y, w2, ff2_b, X, 256, ln2_g, ln2_b, X, 256, Mmax, ssc, CHUNK, nullptr);
    gemm_bf16_k<256, 1><<<dim3(4, Mmax / 128), 256, 0, stream>>>(
        X, wq + KVo, qkv_b + 768 + 256, Y, Mmax, 512, ssc, CHUNK, nullptr);
    gemm_bf16_k<256, 1><<<dim3(2, CHUNK / 128), 256, 0, stream>>>(
        X, wq + Qo, qkv_b + 768, Qcls, CHUNK, 256, sqc, 1, ssc);
    attn_cls_k<SV><<<CHUNK / 16, 256, 0, stream>>>(Qcls, Y, ssc, Ocls);
    gemm_ln_k<256><<<CHUNK / 128, 512, 0, stream>>>(
        Ocls, wo + (i64)256 * 256, out_b + 256, X, 256,
        ln1_g + 256, ln1_b + 256, X2, 256, CHUNK, sqc, 1, ssc);
    gemm_bf16_k<256, 2><<<dim3(8, CHUNK / 128), 256, 0, stream>>>(
        X2, w1 + (i64)1024 * 256, ff1_b + 1024, Y, CHUNK, 1024, sqc, 1, nullptr);
    gemm_ln_k<1024><<<CHUNK / 128, 512, 0, stream>>>(
        Y, w2 + (i64)256 * 1024, ff2_b + 256, X2, 256,
        ln2_g + 256, ln2_b + 256, X3, 256, CHUNK, sqc, 1, nullptr);
    scatter_ext_k<<<CHUNK / 4, 256, 0, stream>>>(X3, hedgeL, posH + NHEDGE, ext, base);
  }
  gemm_bf16_k<256, 1><<<dim3(6, EXTROWS / 128), 256, 0, stream>>>(
      ext, wq, qkv_b, qkvE, EXTROWS, 768, nullptr, 0, nullptr);

  // ================= hop 1: E2V restricted to pred cone (nodeL) =================
  {
    gather_e2vc_k<<<MN1 / 4, 256, 0, stream>>>(ext, hid, nodeL, tokN, ssN, NN1, X, gidN);
    attn1g_k<SE><<<NN1, 16 * SE, 0, stream>>>(qkvE, gidN, ssN, O);
    gemm_ln_k<256><<<MN1 / 128, 512, 0, stream>>>(
        O, wo, out_b, X, 256, ln1_g, ln1_b, X, 256, MN1, ssN, NN1, nullptr);
    gemm_bf16_k<256, 2><<<dim3(8, MN1 / 128), 256, 0, stream>>>(
        X, w1, ff1_b, Y, MN1, 1024, ssN, NN1, nullptr);
    gemm_ln_k<1024><<<MN1 / 128, 512, 0, stream>>>(
        Y, w2, ff2_b, X, 256, ln2_g, ln2_b, X, 256, MN1, ssN, NN1, nullptr);
    gemm_bf16_k<256, 1><<<dim3(4, MN1 / 128), 256, 0, stream>>>(
        X, wq + KVo, qkv_b + 768 + 256, Y, MN1, 512, ssN, NN1, nullptr);
    gemm_bf16_k<256, 1><<<dim3(2, NN1 / 128), 256, 0, stream>>>(
        X, wq + Qo, qkv_b + 768, Qcls, NN1, 256, nullptr, 0, ssN);
    attn_cls_k<SE><<<NN1 / 16, 256, 0, stream>>>(Qcls, Y, ssN, Ocls);
    gemm_ln_k<256><<<NN1 / 128, 512, 0, stream>>>(
        Ocls, wo + (i64)256 * 256, out_b + 256, X, 256,
        ln1_g + 256, ln1_b + 256, X2, 256, NN1, nullptr, 0, ssN);
    gemm_bf16_k<256, 2><<<dim3(8, NN1 / 128), 256, 0, stream>>>(
        X2, w1 + (i64)1024 * 256, ff1_b + 1024, Y, NN1, 1024, nullptr, 0, nullptr);
    gemm_ln_k<1024><<<NN1 / 128, 512, 0, stream>>>(
        Y, w2 + (i64)256 * 1024, ff2_b + 256, X2, 256,
        ln2_g + 256, ln2_b + 256, X3, 256, NN1, nullptr, 0, nullptr);
    scatter_nc_k<<<NN1 / 4, 256, 0, stream>>>(X3, subg, nodeL, nullptr, unity, 0);
  }

  // ================= hop 2: V2E on the 256 predicted hedges =================
  {
    const int* ssc = ssP;
    gather_v2e_k<<<MPRED / 4, 256, 0, stream>>>(unity, pos_tab, xid, xpos,
                                                tokP, ssc, NPRED, X);
    gemm_bf16_k<256, 1><<<dim3(6, MPRED / 128), 256, 0, stream>>>(
        X, wq, qkv_b, Y, MPRED, 768, ssc, NPRED, nullptr);
    attn1_k<SV><<<NPRED, 16 * SV, 0, stream>>>(Y, ssc, O);
    gemm_ln_k<256><<<MPRED / 128, 512, 0, stream>>>(
        O, wo, out_b, X, 256, ln1_g, ln1_b, X, 256, MPRED, ssc, NPRED, nullptr);
    gemm_bf16_k<256, 2><<<dim3(8, MPRED / 128), 256, 0, stream>>>(
        X, w1, ff1_b, Y, MPRED, 1024, ssc, NPRED, nullptr);
    gemm_ln_k<1024><<<MPRED / 128, 512, 0, stream>>>(
        Y, w2, ff2_b, X, 256, ln2_g, ln2_b, X, 256, MPRED, ssc, NPRED, nullptr);
    gemm_bf16_k<256, 1><<<dim3(4, MPRED / 128), 256, 0, stream>>>(
        X, wq + KVo, qkv_b + 768 + 256, Y, MPRED, 512, ssc, NPRED, nullptr);
    gemm_bf16_k<256, 1><<<dim3(2, NPRED / 128), 256, 0, stream>>>(
        X, wq + Qo, qkv_b + 768, Qcls, NPRED, 256, nullptr, 0, ssc);
    attn_cls_k<SV><<<NPRED / 16, 256, 0, stream>>>(Qcls, Y, ssc, Ocls);
    gemm_ln_k<256><<<NPRED / 128, 512, 0, stream>>>(
        Ocls, wo + (i64)256 * 256, out_b + 256, X, 256,
        ln1_g + 256, ln1_b + 256, X2, 256, NPRED, nullptr, 0, ssc);
    gemm_bf16_k<256, 2><<<dim3(8, NPRED / 128), 256, 0, stream>>>(
        X2, w1 + (i64)1024 * 256, ff1_b + 1024, Y, NPRED, 1024, nullptr, 0, nullptr);
    gemm_ln_k<1024><<<NPRED / 128, 512, 0, stream>>>(
        Y, w2 + (i64)256 * 1024, ff2_b + 256, X2, 256,
        ln2_g + 256, ln2_b + 256, predHe, 256, NPRED, nullptr, 0, nullptr);
  }
  out_cvt_k<<<NPRED / 4, 256, 0, stream>>>(predHe, (float*)d_out);
}

// Round 14
// 7089.934 us; speedup vs baseline: 3.6823x; 1.0253x over previous
//
#include <hip/hip_runtime.h>
#include <stdint.h>

typedef long long i64;
typedef __attribute__((ext_vector_type(8))) short bf16x8;
typedef __attribute__((ext_vector_type(4))) float f32x4;

#define SV 11
#define SE 17
#define ARITY 10
#define NHEDGE 32768
#define NNODE 65536
#define NTOTAL 100000
#define EXTROWS 32896
#define NPRED 256
#define MPRED 2816
#define NN1 2560
#define MN1 43520

__device__ __forceinline__ float b2f(ushort u) {
  union { uint32_t i; float f; } v; v.i = (uint32_t)u << 16; return v.f;
}
__device__ __forceinline__ ushort f2b(float f) {
  union { float f; uint32_t i; } v; v.f = f;
  uint32_t u = v.i + 0x7fffu + ((v.i >> 16) & 1u);
  return (ushort)(u >> 16);
}
__device__ __forceinline__ uint pack2(float a, float b) {
  return (uint)f2b(a) | ((uint)f2b(b) << 16);
}
__device__ __forceinline__ void cvt8(uint4 v, float* f) {
  f[0] = b2f((ushort)(v.x & 0xffff)); f[1] = b2f((ushort)(v.x >> 16));
  f[2] = b2f((ushort)(v.y & 0xffff)); f[3] = b2f((ushort)(v.y >> 16));
  f[4] = b2f((ushort)(v.z & 0xffff)); f[5] = b2f((ushort)(v.z >> 16));
  f[6] = b2f((ushort)(v.w & 0xffff)); f[7] = b2f((ushort)(v.w >> 16));
}

__device__ __forceinline__ void gload_lds16(const void* g, void* l) {
  __builtin_amdgcn_global_load_lds((const __attribute__((address_space(1))) void*)g,
                                   (__attribute__((address_space(3))) void*)l, 16, 0, 0);
}

__device__ __forceinline__ int xcd_swizzle(int orig, int nwg) {
  const int xcd = orig & 7, rest = orig >> 3;
  const int q = nwg >> 3, r = nwg & 7;
  return (xcd < r ? xcd * (q + 1) : r * (q + 1) + (xcd - r) * q) + rest;
}

// ================= compaction: count / scan / fill =============================
__global__ __launch_bounds__(256) void zero_k(int* __restrict__ p, int n) {
  const int i = blockIdx.x * 256 + threadIdx.x;
  if (i < n) p[i] = 0;
}

__global__ __launch_bounds__(256) void cnt_k(const int* __restrict__ mask, int width,
                                             int extra, int* __restrict__ cnt, int n) {
  const int i = blockIdx.x * 256 + threadIdx.x;
  if (i >= n) return;
  int c = extra;
  for (int j = 0; j < width; j++) c += (mask[(i64)i * width + j] != 0);
  cnt[i] = c;
}

__global__ __launch_bounds__(256) void scan1_k(const int* __restrict__ cnt,
                                               int* __restrict__ ss,
                                               int* __restrict__ part, int n) {
  __shared__ int sm[256];
  const int i = blockIdx.x * 256 + threadIdx.x;
  const int v = (i < n) ? cnt[i] : 0;
  sm[threadIdx.x] = v;
  __syncthreads();
  for (int o = 1; o < 256; o <<= 1) {
    const int t = (threadIdx.x >= o) ? sm[threadIdx.x - o] : 0;
    __syncthreads();
    sm[threadIdx.x] += t;
    __syncthreads();
  }
  if (i < n) ss[i] = sm[threadIdx.x] - v;
  if (threadIdx.x == 255) part[blockIdx.x] = sm[255];
}

__global__ __launch_bounds__(256) void scan2_k(int* __restrict__ part, int nb,
                                               int* __restrict__ ss, int n) {
  __shared__ int sm[256];
  const int v = (threadIdx.x < nb) ? part[threadIdx.x] : 0;
  sm[threadIdx.x] = v;
  __syncthreads();
  for (int o = 1; o < 256; o <<= 1) {
    const int t = (threadIdx.x >= o) ? sm[threadIdx.x - o] : 0;
    __syncthreads();
    sm[threadIdx.x] += t;
    __syncthreads();
  }
  if (threadIdx.x < nb) part[threadIdx.x] = sm[threadIdx.x] - v;
  if (threadIdx.x == 255) ss[n] = sm[255];
}

__global__ __launch_bounds__(256) void scan3_k(int* __restrict__ ss,
                                               const int* __restrict__ part,
                                               const int* __restrict__ mask, int width,
                                               int extra, int* __restrict__ tok, int n) {
  const int i = blockIdx.x * 256 + threadIdx.x;
  if (i >= n) return;
  int off = ss[i] + part[blockIdx.x];
  ss[i] = off;
  if (extra) {
    tok[off++] = (i << 5);
    for (int j = 0; j < width; j++)
      if (mask[(i64)i * width + j] != 0) tok[off++] = (i << 5) | (j + 1);
  } else {
    for (int j = 0; j < width; j++)
      if (mask[(i64)i * width + j] != 0) tok[off++] = (i << 5) | j;
  }
}

__global__ __launch_bounds__(256) void predscan_k(const int* __restrict__ pred,
                                                  const int* __restrict__ cntV,
                                                  const int* __restrict__ vmask,
                                                  int* __restrict__ ssP,
                                                  int* __restrict__ tokP) {
  __shared__ int sm[256];
  const int tid = threadIdx.x;
  const int e = pred[tid];
  const int v = cntV[e];
  sm[tid] = v;
  __syncthreads();
  for (int o = 1; o < 256; o <<= 1) {
    const int t = (tid >= o) ? sm[tid - o] : 0;
    __syncthreads();
    sm[tid] += t;
    __syncthreads();
  }
  int off = sm[tid] - v;
  ssP[tid] = off;
  if (tid == 255) ssP[256] = sm[255];
  tokP[off++] = (e << 5);
  for (int j = 0; j < ARITY; j++)
    if (vmask[(i64)e * ARITY + j] != 0) tokP[off++] = (e << 5) | (j + 1);
}

// ===== dependency-cone flags ==================================================
__global__ __launch_bounds__(256) void inv_init_k(int* __restrict__ inv, int n) {
  const int i = blockIdx.x * 256 + threadIdx.x;
  if (i < n) inv[i] = -1;
}
__global__ __launch_bounds__(256) void inv_fill_k(const int* __restrict__ subg,
                                                  int* __restrict__ inv, int n) {
  const int i = blockIdx.x * 256 + threadIdx.x;
  if (i < n) inv[subg[i]] = i;
}
__global__ __launch_bounds__(256) void prednode_k(const int* __restrict__ pred,
                                                  const int* __restrict__ xid,
                                                  const int* __restrict__ vmask,
                                                  const int* __restrict__ inv,
                                                  const int* __restrict__ cntE,
                                                  int* __restrict__ nodeL,
                                                  int* __restrict__ cntN) {
  const int i = blockIdx.x * 256 + threadIdx.x;
  if (i >= NN1) return;
  const int e = pred[i / ARITY], j = i - (i / ARITY) * ARITY;
  int nd = 0;
  if (vmask[(i64)e * ARITY + j] != 0) {
    const int v = inv[xid[(i64)e * ARITY + j]];
    if (v >= 0) nd = v;
  }
  nodeL[i] = nd;
  cntN[i] = cntE[nd];
}
__global__ __launch_bounds__(256) void scan3n_k(int* __restrict__ ss,
                                                const int* __restrict__ part,
                                                const int* __restrict__ hmask,
                                                const int* __restrict__ nodeL,
                                                int* __restrict__ tok) {
  const int i = blockIdx.x * 256 + threadIdx.x;
  if (i >= NN1) return;
  int off = ss[i] + part[blockIdx.x];
  ss[i] = off;
  const int nd = nodeL[i];
  for (int j = 0; j < SE; j++)
    if (hmask[(i64)nd * SE + j] != 0) tok[off++] = (i << 5) | j;
}

__global__ __launch_bounds__(256) void flagH_k(const int* __restrict__ nodeL,
                                               const int* __restrict__ hmask,
                                               const int* __restrict__ hid,
                                               int* __restrict__ flagH) {
  const int i = blockIdx.x * 256 + threadIdx.x;
  if (i >= NN1 * SE) return;
  const int s = i / SE, j = i - s * SE;
  const int nd = nodeL[s];
  if (hmask[(i64)nd * SE + j] != 0) {
    const int h = hid[(i64)nd * SE + j];
    if (h < NHEDGE) flagH[h] = 1;
  }
}
__global__ __launch_bounds__(256) void flagE_k(const int* __restrict__ flagH,
                                               const int* __restrict__ vmask,
                                               const int* __restrict__ xid,
                                               int* __restrict__ flagE) {
  const int i = blockIdx.x * 256 + threadIdx.x;
  if (i >= NHEDGE * ARITY) return;
  const int e = i / ARITY, j = i - e * ARITY;
  if (flagH[e] && vmask[(i64)e * ARITY + j] != 0) flagE[xid[(i64)e * ARITY + j]] = 1;
}
__global__ __launch_bounds__(256) void flagN_k(const int* __restrict__ flagE,
                                               const int* __restrict__ subg,
                                               int* __restrict__ cntC) {
  const int n = blockIdx.x * 256 + threadIdx.x;
  if (n < NNODE) cntC[n] = flagE[subg[n]];
}

__global__ __launch_bounds__(256) void fill_list_k(const int* __restrict__ flag,
                                                   const int* __restrict__ pos,
                                                   const int* __restrict__ part,
                                                   int* __restrict__ list, int n) {
  const int i = blockIdx.x * 256 + threadIdx.x;
  if (i < n && flag[i]) list[pos[i] + part[blockIdx.x]] = i;
}

__global__ __launch_bounds__(256) void cnt_list_k(const int* __restrict__ list,
                                                  const int* __restrict__ tot,
                                                  const int* __restrict__ cs,
                                                  int* __restrict__ cd, int n) {
  const int i = blockIdx.x * 256 + threadIdx.x;
  if (i >= n) return;
  cd[i] = (i < tot[0]) ? cs[list[i]] : 0;
}

__global__ __launch_bounds__(256) void tok_hedge_k(int* __restrict__ ss,
                                                   const int* __restrict__ part,
                                                   const int* __restrict__ tot,
                                                   const int* __restrict__ hedgeL,
                                                   const int* __restrict__ vmask,
                                                   int* __restrict__ tok) {
  const int i = blockIdx.x * 256 + threadIdx.x;
  if (i >= NHEDGE) return;
  int off = ss[i] + part[blockIdx.x];
  ss[i] = off;
  if (i >= tot[0]) return;
  const int e = hedgeL[i];
  tok[off++] = (i << 5);
  for (int j = 0; j < ARITY; j++)
    if (vmask[(i64)e * ARITY + j] != 0) tok[off++] = (i << 5) | (j + 1);
}

__global__ __launch_bounds__(256) void tok_node_k(int* __restrict__ ss,
                                                  const int* __restrict__ part,
                                                  const int* __restrict__ tot,
                                                  const int* __restrict__ nodeL0,
                                                  const int* __restrict__ hmask,
                                                  int* __restrict__ tok) {
  const int i = blockIdx.x * 256 + threadIdx.x;
  if (i >= NNODE) return;
  int off = ss[i] + part[blockIdx.x];
  ss[i] = off;
  if (i >= tot[0]) return;
  const int nd = nodeL0[i];
  for (int j = 0; j < SE; j++)
    if (hmask[(i64)nd * SE + j] != 0) tok[off++] = (i << 5) | j;
}

__global__ __launch_bounds__(64) void seqlim_k(const int* __restrict__ tot, int chunk,
                                               int nch, int* __restrict__ out) {
  const int c = threadIdx.x;
  if (c <= nch) out[c] = min(tot[0], c * chunk);
}

// ================= 128x128 bf16 MFMA GEMM =====================================
template <int K, int MODE>
__global__ __launch_bounds__(256) void gemm_bf16_k(const ushort* __restrict__ A,
                                                   const ushort* __restrict__ W,
                                                   const float* __restrict__ bias,
                                                   ushort* __restrict__ C, int M, int N,
                                                   const int* ssn, int nseq,
                                                   const int* arp) {
  const int tid = threadIdx.x;
  const int wave = tid >> 6, lane = tid & 63;
  const int nwg = gridDim.x * gridDim.y;
  const int wg = xcd_swizzle(blockIdx.y * gridDim.x + blockIdx.x, nwg);
  const int bx = wg % gridDim.x, by = wg / gridDim.x;
  const int m0 = by << 7, n0 = bx << 7;
  if (ssn && m0 >= ssn[nseq] - ssn[0]) return;
  __shared__ ushort As[128 * 64];
  __shared__ ushort Ws[128 * 64];
  const int wr = wave >> 1, wc = wave & 1;

  f32x4 acc[4][4];
#pragma unroll
  for (int m = 0; m < 4; m++)
#pragma unroll
    for (int n = 0; n < 4; n++) acc[m][n] = (f32x4){0.f, 0.f, 0.f, 0.f};

  const int srow = (wave << 5) + (lane >> 3);
  const int kblk_g = (lane & 7) ^ (lane >> 3);
  const i64 arow = arp ? (i64)(arp[m0 + srow] - arp[0]) : (i64)(m0 + srow);
  const ushort* Ag = A + arow * K + (kblk_g << 3);
  const ushort* Wg = W + (i64)(n0 + srow) * K + (kblk_g << 3);
  char* lA = (char*)As + (wave << 12);
  char* lB = (char*)Ws + (wave << 12);

#pragma unroll
  for (int i = 0; i < 4; i++) {
    gload_lds16(Ag + (i64)(i * 8) * K, lA + i * 1024);
    gload_lds16(Wg + (i64)(i * 8) * K, lB + i * 1024);
  }

  for (int k0 = 0; k0 < K; k0 += 64) {
    __syncthreads();
    bf16x8 af[2][4], bf[2][4];
#pragma unroll
    for (int kh = 0; kh < 2; kh++) {
      const int kb = (kh << 2) + (lane >> 4);
#pragma unroll
      for (int m = 0; m < 4; m++) {
        const int row = (wr << 6) + (m << 4) + (lane & 15);
        af[kh][m] = *(const bf16x8*)&As[row * 64 + ((kb ^ (row & 7)) << 3)];
      }
#pragma unroll
      for (int n = 0; n < 4; n++) {
        const int row = (wc << 6) + (n << 4) + (lane & 15);
        bf[kh][n] = *(const bf16x8*)&Ws[row * 64 + ((kb ^ (row & 7)) << 3)];
      }
    }
    __syncthreads();
    if (k0 + 64 < K) {
#pragma unroll
      for (int i = 0; i < 4; i++) {
        gload_lds16(Ag + (k0 + 64) + (i64)(i * 8) * K, lA + i * 1024);
        gload_lds16(Wg + (k0 + 64) + (i64)(i * 8) * K, lB + i * 1024);
      }
    }
#pragma unroll
    for (int kh = 0; kh < 2; kh++)
#pragma unroll
      for (int m = 0; m < 4; m++)
#pragma unroll
        for (int n = 0; n < 4; n++)
          acc[m][n] = __builtin_amdgcn_mfma_f32_16x16x32_bf16(bf[kh][n], af[kh][m], acc[m][n], 0, 0, 0);
  }

#pragma unroll
  for (int m = 0; m < 4; m++) {
    const int row = m0 + (wr << 6) + (m << 4) + (lane & 15);
#pragma unroll
    for (int n = 0; n < 4; n++) {
      const int col = n0 + (wc << 6) + (n << 4) + ((lane >> 4) << 2);
      float v0 = acc[m][n][0], v1 = acc[m][n][1], v2 = acc[m][n][2], v3 = acc[m][n][3];
      if (MODE > 0) {
        const f32x4 bv = *(const f32x4*)&bias[col];
        v0 += bv[0]; v1 += bv[1]; v2 += bv[2]; v3 += bv[3];
      }
      if (MODE == 2) {
        v0 = fmaxf(v0, 0.f); v1 = fmaxf(v1, 0.f);
        v2 = fmaxf(v2, 0.f); v3 = fmaxf(v3, 0.f);
      }
      uint2 o; o.x = pack2(v0, v1); o.y = pack2(v2, v3);
      *(uint2*)&C[(i64)row * N + col] = o;
    }
  }
}

// ============ Fused GEMM + residual + LayerNorm (N = 256, K = 256) =============
template <int K>
__global__ __launch_bounds__(512) void gemm_ln_k(const ushort* __restrict__ A,
                                                 const ushort* __restrict__ W,
                                                 const float* __restrict__ bias,
                                                 const ushort* R, int rstride,
                                                 const float* __restrict__ g,
                                                 const float* __restrict__ b,
                                                 ushort* C, int cstride, int M,
                                                 const int* ssn, int nseq,
                                                 const int* rrp) {
  const int m0 = blockIdx.x << 7;
  if (ssn && m0 >= ssn[nseq] - ssn[0]) return;
  __shared__ ushort As[128 * 64];
  __shared__ ushort Ws[256 * 64];
  __shared__ float partS[128][4];
  __shared__ float partQ[128][4];
  const int tid = threadIdx.x;
  const int wave = tid >> 6, lane = tid & 63;
  const int wr = wave >> 2, wc = wave & 3;

  f32x4 acc[4][4];
#pragma unroll
  for (int m = 0; m < 4; m++)
#pragma unroll
    for (int n = 0; n < 4; n++) acc[m][n] = (f32x4){0.f, 0.f, 0.f, 0.f};

  int rowA[2], kgA[2];
#pragma unroll
  for (int i = 0; i < 2; i++) {
    const int u = wave * 128 + i * 64 + lane;
    rowA[i] = u >> 3; kgA[i] = (u & 7) ^ ((u >> 3) & 7);
  }
  int rowW[4], kgW[4];
#pragma unroll
  for (int i = 0; i < 4; i++) {
    const int u = wave * 256 + i * 64 + lane;
    rowW[i] = u >> 3; kgW[i] = (u & 7) ^ ((u >> 3) & 7);
  }

#pragma unroll
  for (int i = 0; i < 2; i++)
    gload_lds16(A + (i64)(m0 + rowA[i]) * K + (kgA[i] << 3),
                (char*)As + (wave * 128 + i * 64) * 16);
#pragma unroll
  for (int i = 0; i < 4; i++)
    gload_lds16(W + (i64)rowW[i] * K + (kgW[i] << 3),
                (char*)Ws + (wave * 256 + i * 64) * 16);

  for (int k0 = 0; k0 < K; k0 += 64) {
    __syncthreads();
    bf16x8 af[2][4], bf[2][4];
#pragma unroll
    for (int kh = 0; kh < 2; kh++) {
      const int kb = (kh << 2) + (lane >> 4);
#pragma unroll
      for (int m = 0; m < 4; m++) {
        const int row = (wr << 6) + (m << 4) + (lane & 15);
        af[kh][m] = *(const bf16x8*)&As[row * 64 + ((kb ^ (row & 7)) << 3)];
      }
#pragma unroll
      for (int n = 0; n < 4; n++) {
        const int row = (wc << 6) + (n << 4) + (lane & 15);
        bf[kh][n] = *(const bf16x8*)&Ws[row * 64 + ((kb ^ (row & 7)) << 3)];
      }
    }
    __syncthreads();
    if (k0 + 64 < K) {
#pragma unroll
      for (int i = 0; i < 2; i++)
        gload_lds16(A + (i64)(m0 + rowA[i]) * K + (k0 + 64) + (kgA[i] << 3),
                    (char*)As + (wave * 128 + i * 64) * 16);
#pragma unroll
      for (int i = 0; i < 4; i++)
        gload_lds16(W + (i64)rowW[i] * K + (k0 + 64) + (kgW[i] << 3),
                    (char*)Ws + (wave * 256 + i * 64) * 16);
    }
#pragma unroll
    for (int kh = 0; kh < 2; kh++)
#pragma unroll
      for (int m = 0; m < 4; m++)
#pragma unroll
        for (int n = 0; n < 4; n++)
          acc[m][n] = __builtin_amdgcn_mfma_f32_16x16x32_bf16(bf[kh][n], af[kh][m], acc[m][n], 0, 0, 0);
  }

#pragma unroll
  for (int m = 0; m < 4; m++) {
    const int tokl = (wr << 6) + (m << 4) + (lane & 15);
    const int row = m0 + tokl;
    const i64 rr = rrp ? (i64)(rrp[row] - rrp[0]) : (i64)row;
    float s = 0.f, q = 0.f;
#pragma unroll
    for (int n = 0; n < 4; n++) {
      const int col = (wc << 6) + (n << 4) + ((lane >> 4) << 2);
      const f32x4 bv = *(const f32x4*)&bias[col];
      const uint2 ru = *(const uint2*)&R[rr * rstride + col];
      float v0 = acc[m][n][0] + bv[0] + b2f((ushort)(ru.x & 0xffff));
      float v1 = acc[m][n][1] + bv[1] + b2f((ushort)(ru.x >> 16));
      float v2 = acc[m][n][2] + bv[2] + b2f((ushort)(ru.y & 0xffff));
      float v3 = acc[m][n][3] + bv[3] + b2f((ushort)(ru.y >> 16));
      acc[m][n][0] = v0; acc[m][n][1] = v1; acc[m][n][2] = v2; acc[m][n][3] = v3;
      s += v0 + v1 + v2 + v3;
      q += v0 * v0 + v1 * v1 + v2 * v2 + v3 * v3;
    }
    s += __shfl_xor(s, 16, 64); s += __shfl_xor(s, 32, 64);
    q += __shfl_xor(q, 16, 64); q += __shfl_xor(q, 32, 64);
    if (lane < 16) { partS[tokl][wc] = s; partQ[tokl][wc] = q; }
  }
  __syncthreads();
#pragma unroll
  for (int m = 0; m < 4; m++) {
    const int tokl = (wr << 6) + (m << 4) + (lane & 15);
    const i64 row = (i64)(m0 + tokl);
    const f32x4 s4 = *(const f32x4*)&partS[tokl][0];
    const f32x4 q4 = *(const f32x4*)&partQ[tokl][0];
    const float mean = (s4[0] + s4[1] + s4[2] + s4[3]) * (1.f / 256.f);
    const float var = (q4[0] + q4[1] + q4[2] + q4[3]) * (1.f / 256.f) - mean * mean;
    const float rs = rsqrtf(var + 1e-5f);
#pragma unroll
    for (int n = 0; n < 4; n++) {
      const int col = (wc << 6) + (n << 4) + ((lane >> 4) << 2);
      const f32x4 g4 = *(const f32x4*)&g[col];
      const f32x4 b4 = *(const f32x4*)&b[col];
      uint2 o;
      o.x = pack2((acc[m][n][0] - mean) * rs * g4[0] + b4[0],
                  (acc[m][n][1] - mean) * rs * g4[1] + b4[1]);
      o.y = pack2((acc[m][n][2] - mean) * rs * g4[2] + b4[2],
                  (acc[m][n][3] - mean) * rs * g4[3] + b4[3]);
      *(uint2*)&C[row * cstride + col] = o;
    }
  }
}

// ===== Fused FFN: C = LN(R + relu(A@W1^T+b1)@W2^T + b2)*g + bb ================
// 64 tokens/block, 256 thr (4 waves = col-groups of 64). 8 ff-chunks of 128:
// phase A: Yc = relu(A@W1c^T+b1c) -> swizzled bf16 LDS; phase B: acc += Yc@W2c^T.
// K-accumulation order identical to separate FF1/FF2 kernels (bit-exact).
__global__ __launch_bounds__(256) void ff_ln_k(const ushort* __restrict__ A,
                                               const ushort* __restrict__ W1,
                                               const float* __restrict__ b1,
                                               const ushort* __restrict__ W2,
                                               const float* __restrict__ b2,
                                               const ushort* R, int rstride,
                                               const float* __restrict__ g,
                                               const float* __restrict__ bb,
                                               ushort* C, int cstride, int M,
                                               const int* ssn, int nseq) {
  const int m0 = blockIdx.x << 6;
  if (ssn && m0 >= ssn[nseq] - ssn[0]) return;
  __shared__ ushort Ys[64 * 128];      // 16KB persistent Y chunk
  __shared__ ushort Stage[256 * 64];   // 32KB staging (A+W1 | W2)
  __shared__ float partS[64][4];
  __shared__ float partQ[64][4];
  const int tid = threadIdx.x;
  const int wave = tid >> 6, lane = tid & 63;

  f32x4 acc[4][4];
#pragma unroll
  for (int m = 0; m < 4; m++)
#pragma unroll
    for (int n = 0; n < 4; n++) acc[m][n] = (f32x4){0.f, 0.f, 0.f, 0.f};

  for (int fc = 0; fc < 8; fc++) {
    f32x4 accY[4][2];
#pragma unroll
    for (int m = 0; m < 4; m++)
#pragma unroll
      for (int n = 0; n < 2; n++) accY[m][n] = (f32x4){0.f, 0.f, 0.f, 0.f};

    // ---- phase A: Yc[64][128] = A[64][256] @ W1c[128][256]^T ----
    for (int t = 0; t < 4; t++) {
      const int kk = t << 6;
#pragma unroll
      for (int i = 0; i < 2; i++) {  // A tile [64][64]
        const int u = i * 256 + tid;
        const int row = u >> 3, kg = (u & 7) ^ (row & 7);
        gload_lds16(A + (i64)(m0 + row) * 256 + kk + (kg << 3), (char*)Stage + u * 16);
      }
#pragma unroll
      for (int i = 0; i < 4; i++) {  // W1 tile [128][64]
        const int u = i * 256 + tid;
        const int row = u >> 3, kg = (u & 7) ^ (row & 7);
        gload_lds16(W1 + (i64)(fc * 128 + row) * 256 + kk + (kg << 3),
                    (char*)(Stage + 4096) + u * 16);
      }
      __syncthreads();
#pragma unroll
      for (int kh = 0; kh < 2; kh++) {
        const int kb = (kh << 2) + (lane >> 4);
        bf16x8 af[4], bf[2];
#pragma unroll
        for (int m = 0; m < 4; m++) {
          const int row = (m << 4) + (lane & 15);
          af[m] = *(const bf16x8*)&Stage[row * 64 + ((kb ^ (row & 7)) << 3)];
        }
#pragma unroll
        for (int n = 0; n < 2; n++) {
          const int row = (wave << 5) + (n << 4) + (lane & 15);
          bf[n] = *(const bf16x8*)&Stage[4096 + row * 64 + ((kb ^ (row & 7)) << 3)];
        }
#pragma unroll
        for (int m = 0; m < 4; m++)
#pragma unroll
          for (int n = 0; n < 2; n++)
            accY[m][n] = __builtin_amdgcn_mfma_f32_16x16x32_bf16(bf[n], af[m], accY[m][n], 0, 0, 0);
      }
      __syncthreads();
    }
    // ---- write relu(Yc + b1) to swizzled LDS ----
#pragma unroll
    for (int m = 0; m < 4; m++) {
      const int row = (m << 4) + (lane & 15);
#pragma unroll
      for (int n = 0; n < 2; n++) {
        const int colg = (wave << 5) + (n << 4) + ((lane >> 4) << 2);
        const f32x4 bv = *(const f32x4*)&b1[fc * 128 + colg];
        const float v0 = fmaxf(accY[m][n][0] + bv[0], 0.f);
        const float v1 = fmaxf(accY[m][n][1] + bv[1], 0.f);
        const float v2 = fmaxf(accY[m][n][2] + bv[2], 0.f);
        const float v3 = fmaxf(accY[m][n][3] + bv[3], 0.f);
        const int kbY = colg >> 3, off = colg & 7;
        const int swz = (kbY & 8) | ((kbY ^ (row & 7)) & 7);
        uint2 o; o.x = pack2(v0, v1); o.y = pack2(v2, v3);
        *(uint2*)&Ys[row * 128 + swz * 8 + off] = o;
      }
    }
    // ---- phase B: acc += Yc[64][128] @ W2c[256][128]^T (two K=64 steps) ----
#pragma unroll
    for (int ks = 0; ks < 2; ks++) {
#pragma unroll
      for (int i = 0; i < 8; i++) {  // W2 tile [256][64]
        const int u = i * 256 + tid;
        const int row = u >> 3, kg = (u & 7) ^ (row & 7);
        gload_lds16(W2 + (i64)row * 1024 + fc * 128 + (ks << 6) + (kg << 3),
                    (char*)Stage + u * 16);
      }
      __syncthreads();  // Yc writes + W2 stage visible
#pragma unroll
      for (int kh = 0; kh < 2; kh++) {
        const int kb = (kh << 2) + (lane >> 4);
        bf16x8 af[4], bf[4];
#pragma unroll
        for (int m = 0; m < 4; m++) {
          const int row = (m << 4) + (lane & 15);
          const int kbY = (ks << 3) + kb;
          const int swz = (kbY & 8) | ((kbY ^ (row & 7)) & 7);
          af[m] = *(const bf16x8*)&Ys[row * 128 + (swz << 3)];
        }
#pragma unroll
        for (int n = 0; n < 4; n++) {
          const int row = (wave << 6) + (n << 4) + (lane & 15);
          bf[n] = *(const bf16x8*)&Stage[row * 64 + ((kb ^ (row & 7)) << 3)];
        }
#pragma unroll
        for (int m = 0; m < 4; m++)
#pragma unroll
          for (int n = 0; n < 4; n++)
            acc[m][n] = __builtin_amdgcn_mfma_f32_16x16x32_bf16(bf[n], af[m], acc[m][n], 0, 0, 0);
      }
      __syncthreads();
    }
  }

  // ---- epilogue: residual + LN (rows 64, wave = col-group of 64) ----
#pragma unroll
  for (int m = 0; m < 4; m++) {
    const int tokl = (m << 4) + (lane & 15);
    const i64 row = (i64)(m0 + tokl);
    float s = 0.f, q = 0.f;
#pragma unroll
    for (int n = 0; n < 4; n++) {
      const int col = (wave << 6) + (n << 4) + ((lane >> 4) << 2);
      const f32x4 bv = *(const f32x4*)&b2[col];
      const uint2 ru = *(const uint2*)&R[row * rstride + col];
      float v0 = acc[m][n][0] + bv[0] + b2f((ushort)(ru.x & 0xffff));
      float v1 = acc[m][n][1] + bv[1] + b2f((ushort)(ru.x >> 16));
      float v2 = acc[m][n][2] + bv[2] + b2f((ushort)(ru.y & 0xffff));
      float v3 = acc[m][n][3] + bv[3] + b2f((ushort)(ru.y >> 16));
      acc[m][n][0] = v0; acc[m][n][1] = v1; acc[m][n][2] = v2; acc[m][n][3] = v3;
      s += v0 + v1 + v2 + v3;
      q += v0 * v0 + v1 * v1 + v2 * v2 + v3 * v3;
    }
    s += __shfl_xor(s, 16, 64); s += __shfl_xor(s, 32, 64);
    q += __shfl_xor(q, 16, 64); q += __shfl_xor(q, 32, 64);
    if (lane < 16) { partS[tokl][wave] = s; partQ[tokl][wave] = q; }
  }
  __syncthreads();
#pragma unroll
  for (int m = 0; m < 4; m++) {
    const int tokl = (m << 4) + (lane & 15);
    const i64 row = (i64)(m0 + tokl);
    const f32x4 s4 = *(const f32x4*)&partS[tokl][0];
    const f32x4 q4 = *(const f32x4*)&partQ[tokl][0];
    const float mean = (s4[0] + s4[1] + s4[2] + s4[3]) * (1.f / 256.f);
    const float var = (q4[0] + q4[1] + q4[2] + q4[3]) * (1.f / 256.f) - mean * mean;
    const float rs = rsqrtf(var + 1e-5f);
#pragma unroll
    for (int n = 0; n < 4; n++) {
      const int col = (wave << 6) + (n << 4) + ((lane >> 4) << 2);
      const f32x4 g4 = *(const f32x4*)&g[col];
      const f32x4 b4 = *(const f32x4*)&bb[col];
      uint2 o;
      o.x = pack2((acc[m][n][0] - mean) * rs * g4[0] + b4[0],
                  (acc[m][n][1] - mean) * rs * g4[1] + b4[1]);
      o.y = pack2((acc[m][n][2] - mean) * rs * g4[2] + b4[2],
                  (acc[m][n][3] - mean) * rs * g4[3] + b4[3]);
      *(uint2*)&C[row * cstride + col] = o;
    }
  }
}

// ========= Layer-1 attention (compact token rows) =============================
template <int S>
__global__ __launch_bounds__(16 * S) void attn1_k(const ushort* __restrict__ QKV,
                                                  const int* __restrict__ ss,
                                                  ushort* __restrict__ O) {
  __shared__ float KL[4][S][68];
  __shared__ float VL[4][S][68];
  const int tid = threadIdx.x;
  const int s0 = ss[0];
  const int base = ss[blockIdx.x] - s0;
  const int L = ss[blockIdx.x + 1] - ss[blockIdx.x];

  for (int u = tid; u < 128 * L; u += 16 * S) {
    const int d4 = u & 15, h = (u >> 4) & 3, mt = u >> 6;
    const int mat = (mt >= L), t = mat ? mt - L : mt;
    const ushort* gp = QKV + (i64)(base + t) * 768 + 256 + mat * 256 + h * 64 + d4 * 4;
    ushort4 raw = *(const ushort4*)gp;
    float* dst = (mat ? &VL[h][t][0] : &KL[h][t][0]) + d4 * 4;
    dst[0] = b2f(raw.x); dst[1] = b2f(raw.y); dst[2] = b2f(raw.z); dst[3] = b2f(raw.w);
  }
  __syncthreads();

  const int h = tid / (4 * S);
  const int r = tid - h * 4 * S;
  const int q = r >> 2, j = r & 3;
  if (q >= L) return;

  float qv[16];
  {
    const ushort* qp = QKV + (i64)(base + q) * 768 + h * 64 + j * 16;
    cvt8(*(const uint4*)qp, qv);
    cvt8(*(const uint4*)(qp + 8), qv + 8);
  }

  float w[S];
  float mx = -1e30f;
#pragma unroll
  for (int s = 0; s < S; s++) {
    float p = -1e30f;
    if (s < L) {
      const float* kr = &KL[h][s][j * 16];
      p = 0.f;
#pragma unroll
      for (int e = 0; e < 4; e++) {
        const float4 kv = *(const float4*)(kr + e * 4);
        p = fmaf(qv[e * 4 + 0], kv.x, p);
        p = fmaf(qv[e * 4 + 1], kv.y, p);
        p = fmaf(qv[e * 4 + 2], kv.z, p);
        p = fmaf(qv[e * 4 + 3], kv.w, p);
      }
      p += __shfl_xor(p, 1, 64);
      p += __shfl_xor(p, 2, 64);
      p *= 0.125f;
    }
    w[s] = p;
    mx = fmaxf(mx, p);
  }
  float sum = 0.f;
#pragma unroll
  for (int s = 0; s < S; s++) { w[s] = __expf(w[s] - mx); sum += w[s]; }
  const float inv = 1.f / sum;

  float o[16];
#pragma unroll
  for (int e = 0; e < 16; e++) o[e] = 0.f;
#pragma unroll
  for (int s = 0; s < S; s++) {
    if (s < L) {
      const float ws = w[s];
      const float* vr = &VL[h][s][j * 16];
#pragma unroll
      for (int e = 0; e < 4; e++) {
        const float4 vv = *(const float4*)(vr + e * 4);
        o[e * 4 + 0] = fmaf(ws, vv.x, o[e * 4 + 0]);
        o[e * 4 + 1] = fmaf(ws, vv.y, o[e * 4 + 1]);
        o[e * 4 + 2] = fmaf(ws, vv.z, o[e * 4 + 2]);
        o[e * 4 + 3] = fmaf(ws, vv.w, o[e * 4 + 3]);
      }
    }
  }
  uint4 st0, st1;
  st0.x = pack2(o[0] * inv, o[1] * inv);   st0.y = pack2(o[2] * inv, o[3] * inv);
  st0.z = pack2(o[4] * inv, o[5] * inv);   st0.w = pack2(o[6] * inv, o[7] * inv);
  st1.x = pack2(o[8] * inv, o[9] * inv);   st1.y = pack2(o[10] * inv, o[11] * inv);
  st1.z = pack2(o[12] * inv, o[13] * inv); st1.w = pack2(o[14] * inv, o[15] * inv);
  ushort* op = O + (i64)(base + q) * 256 + h * 64 + j * 16;
  *(uint4*)op = st0;
  *(uint4*)(op + 8) = st1;
}

// ========= Layer-1 attention, E2V: QKV gathered from hedge table ==============
template <int S>
__global__ __launch_bounds__(16 * S) void attn1g_k(const ushort* __restrict__ QKVE,
                                                   const int* __restrict__ gid,
                                                   const int* __restrict__ ss,
                                                   ushort* __restrict__ O) {
  __shared__ float KL[4][S][68];
  __shared__ float VL[4][S][68];
  __shared__ int ids[S];
  const int tid = threadIdx.x;
  const int s0 = ss[0];
  const int base = ss[blockIdx.x] - s0;
  const int L = ss[blockIdx.x + 1] - ss[blockIdx.x];

  if (tid < L) ids[tid] = gid[base + tid];
  __syncthreads();

  for (int u = tid; u < 128 * L; u += 16 * S) {
    const int d4 = u & 15, h = (u >> 4) & 3, mt = u >> 6;
    const int mat = (mt >= L), t = mat ? mt - L : mt;
    const ushort* gp = QKVE + (i64)ids[t] * 768 + 256 + mat * 256 + h * 64 + d4 * 4;
    ushort4 raw = *(const ushort4*)gp;
    float* dst = (mat ? &VL[h][t][0] : &KL[h][t][0]) + d4 * 4;
    dst[0] = b2f(raw.x); dst[1] = b2f(raw.y); dst[2] = b2f(raw.z); dst[3] = b2f(raw.w);
  }
  __syncthreads();

  const int h = tid / (4 * S);
  const int r = tid - h * 4 * S;
  const int q = r >> 2, j = r & 3;
  if (q >= L) return;

  float qv[16];
  {
    const ushort* qp = QKVE + (i64)ids[q] * 768 + h * 64 + j * 16;
    cvt8(*(const uint4*)qp, qv);
    cvt8(*(const uint4*)(qp + 8), qv + 8);
  }

  float w[S];
  float mx = -1e30f;
#pragma unroll
  for (int s = 0; s < S; s++) {
    float p = -1e30f;
    if (s < L) {
      const float* kr = &KL[h][s][j * 16];
      p = 0.f;
#pragma unroll
      for (int e = 0; e < 4; e++) {
        const float4 kv = *(const float4*)(kr + e * 4);
        p = fmaf(qv[e * 4 + 0], kv.x, p);
        p = fmaf(qv[e * 4 + 1], kv.y, p);
        p = fmaf(qv[e * 4 + 2], kv.z, p);
        p = fmaf(qv[e * 4 + 3], kv.w, p);
      }
      p += __shfl_xor(p, 1, 64);
      p += __shfl_xor(p, 2, 64);
      p *= 0.125f;
    }
    w[s] = p;
    mx = fmaxf(mx, p);
  }
  float sum = 0.f;
#pragma unroll
  for (int s = 0; s < S; s++) { w[s] = __expf(w[s] - mx); sum += w[s]; }
  const float inv = 1.f / sum;

  float o[16];
#pragma unroll
  for (int e = 0; e < 16; e++) o[e] = 0.f;
#pragma unroll
  for (int s = 0; s < S; s++) {
    if (s < L) {
      const float ws = w[s];
      const float* vr = &VL[h][s][j * 16];
#pragma unroll
      for (int e = 0; e < 4; e++) {
        const float4 vv = *(const float4*)(vr + e * 4);
        o[e * 4 + 0] = fmaf(ws, vv.x, o[e * 4 + 0]);
        o[e * 4 + 1] = fmaf(ws, vv.y, o[e * 4 + 1]);
        o[e * 4 + 2] = fmaf(ws, vv.z, o[e * 4 + 2]);
        o[e * 4 + 3] = fmaf(ws, vv.w, o[e * 4 + 3]);
      }
    }
  }
  uint4 st0, st1;
  st0.x = pack2(o[0] * inv, o[1] * inv);   st0.y = pack2(o[2] * inv, o[3] * inv);
  st0.z = pack2(o[4] * inv, o[5] * inv);   st0.w = pack2(o[6] * inv, o[7] * inv);
  st1.x = pack2(o[8] * inv, o[9] * inv);   st1.y = pack2(o[10] * inv, o[11] * inv);
  st1.z = pack2(o[12] * inv, o[13] * inv); st1.w = pack2(o[14] * inv, o[15] * inv);
  ushort* op = O + (i64)(base + q) * 256 + h * 64 + j * 16;
  *(uint4*)op = st0;
  *(uint4*)(op + 8) = st1;
}

// ===== Layer-2 attention, CLS query ===========================================
template <int S>
__global__ __launch_bounds__(256) void attn_cls_k(const ushort* __restrict__ Qc,
                                                  const ushort* __restrict__ KV,
                                                  const int* __restrict__ ss,
                                                  ushort* __restrict__ Ocls) {
  const int tid = threadIdx.x;
  const int sl = tid >> 4, h = (tid >> 2) & 3, j = tid & 3;
  const int seq = blockIdx.x * 16 + sl;
  const int base = ss[seq] - ss[0];
  const int L = ss[seq + 1] - ss[seq];

  float qv[16];
  {
    const ushort* qp = Qc + (i64)seq * 256 + h * 64 + j * 16;
    cvt8(*(const uint4*)qp, qv);
    cvt8(*(const uint4*)(qp + 8), qv + 8);
  }
  float w[S];
  float mx = -1e30f;
#pragma unroll
  for (int s = 0; s < S; s++) {
    float p = -1e30f;
    if (s < L) {
      float kf[16];
      const ushort* kp = KV + (i64)(base + s) * 512 + h * 64 + j * 16;
      cvt8(*(const uint4*)kp, kf);
      cvt8(*(const uint4*)(kp + 8), kf + 8);
      p = 0.f;
#pragma unroll
      for (int e = 0; e < 16; e++) p = fmaf(qv[e], kf[e], p);
      p += __shfl_xor(p, 1, 64);
      p += __shfl_xor(p, 2, 64);
      p *= 0.125f;
    }
    w[s] = p;
    mx = fmaxf(mx, p);
  }
  float sum = 0.f;
#pragma unroll
  for (int s = 0; s < S; s++) { w[s] = __expf(w[s] - mx); sum += w[s]; }
  const float inv = 1.f / sum;

  float o[16];
#pragma unroll
  for (int e = 0; e < 16; e++) o[e] = 0.f;
#pragma unroll
  for (int s = 0; s < S; s++) {
    if (s < L) {
      float vf[16];
      const ushort* vp = KV + (i64)(base + s) * 512 + 256 + h * 64 + j * 16;
      cvt8(*(const uint4*)vp, vf);
      cvt8(*(const uint4*)(vp + 8), vf + 8);
      const float ws = w[s];
#pragma unroll
      for (int e = 0; e < 16; e++) o[e] = fmaf(ws, vf[e], o[e]);
    }
  }
  uint4 st0, st1;
  st0.x = pack2(o[0] * inv, o[1] * inv);   st0.y = pack2(o[2] * inv, o[3] * inv);
  st0.z = pack2(o[4] * inv, o[5] * inv);   st0.w = pack2(o[6] * inv, o[7] * inv);
  st1.x = pack2(o[8] * inv, o[9] * inv);   st1.y = pack2(o[10] * inv, o[11] * inv);
  st1.z = pack2(o[12] * inv, o[13] * inv); st1.w = pack2(o[14] * inv, o[15] * inv);
  ushort* op = Ocls + (i64)seq * 256 + h * 64 + j * 16;
  *(uint4*)op = st0;
  *(uint4*)(op + 8) = st1;
}

// ================= gathers / scatters / conversion =============================
__global__ __launch_bounds__(256) void f2b_cvt_k(const float* __restrict__ in,
                                                 ushort* __restrict__ out, int n) {
  for (int i = blockIdx.x * 256 + threadIdx.x; i < n; i += gridDim.x * 256)
    out[i] = f2b(in[i]);
}

__global__ __launch_bounds__(256) void gather_v2e_k(const float* __restrict__ unity,
                                                    const float* __restrict__ pos,
                                                    const int* __restrict__ xid,
                                                    const int* __restrict__ xpos,
                                                    const int* __restrict__ tok,
                                                    const int* __restrict__ ss, int nseq,
                                                    ushort* __restrict__ X) {
  const int t = blockIdx.x * 4 + (threadIdx.x >> 6);
  const int lane = threadIdx.x & 63;
  const int s0 = ss[0];
  if (t >= ss[nseq] - s0) return;
  const int code = tok[s0 + t];
  const int e = code >> 5, slot = code & 31;
  float4 v = make_float4(0.f, 0.f, 0.f, 0.f);
  if (slot > 0) {
    const int id = xid[(i64)e * ARITY + (slot - 1)];
    v = *(const float4*)&unity[(i64)id * 256 + lane * 4];
  }
  const int pp = xpos[(i64)e * SV + slot];
  const float4 pv = *(const float4*)&pos[(i64)pp * 256 + lane * 4];
  uint2 o;
  o.x = pack2(v.x + pv.x, v.y + pv.y);
  o.y = pack2(v.z + pv.z, v.w + pv.w);
  *(uint2*)&X[(i64)t * 256 + lane * 4] = o;
}

__global__ __launch_bounds__(256) void gather_v2eh_k(const float* __restrict__ unity,
                                                     const float* __restrict__ pos,
                                                     const int* __restrict__ xid,
                                                     const int* __restrict__ xpos,
                                                     const int* __restrict__ hedgeL,
                                                     const int* __restrict__ tok,
                                                     const int* __restrict__ ss, int nseq,
                                                     ushort* __restrict__ X) {
  const int t = blockIdx.x * 4 + (threadIdx.x >> 6);
  const int lane = threadIdx.x & 63;
  const int s0 = ss[0];
  if (t >= ss[nseq] - s0) return;
  const int code = tok[s0 + t];
  const int e = hedgeL[code >> 5], slot = code & 31;
  float4 v = make_float4(0.f, 0.f, 0.f, 0.f);
  if (slot > 0) {
    const int id = xid[(i64)e * ARITY + (slot - 1)];
    v = *(const float4*)&unity[(i64)id * 256 + lane * 4];
  }
  const int pp = xpos[(i64)e * SV + slot];
  const float4 pv = *(const float4*)&pos[(i64)pp * 256 + lane * 4];
  uint2 o;
  o.x = pack2(v.x + pv.x, v.y + pv.y);
  o.y = pack2(v.z + pv.z, v.w + pv.w);
  *(uint2*)&X[(i64)t * 256 + lane * 4] = o;
}

__global__ __launch_bounds__(256) void gather_e2vc_k(const ushort* __restrict__ ext,
                                                     const int* __restrict__ hid,
                                                     const int* __restrict__ nodeL,
                                                     const int* __restrict__ tok,
                                                     const int* __restrict__ ss, int nseq,
                                                     ushort* __restrict__ X,
                                                     int* __restrict__ gid) {
  const int t = blockIdx.x * 4 + (threadIdx.x >> 6);
  const int lane = threadIdx.x & 63;
  const int s0 = ss[0];
  if (t >= ss[nseq] - s0) return;
  const int code = tok[s0 + t];
  const int id = hid[(i64)nodeL[code >> 5] * SE + (code & 31)];
  if (lane == 0) gid[t] = id;
  *(uint2*)&X[(i64)t * 256 + lane * 4] =
      *(const uint2*)&ext[(i64)id * 256 + lane * 4];
}

__global__ __launch_bounds__(256) void scatter_ext_k(const ushort* __restrict__ Xc,
                                                     const int* __restrict__ hedgeL,
                                                     const int* __restrict__ tot,
                                                     ushort* __restrict__ ext, int base) {
  const int il = blockIdx.x * 4 + (threadIdx.x >> 6);
  const int lane = threadIdx.x & 63;
  const int i = base + il;
  if (i >= tot[0]) return;
  *(uint2*)&ext[(i64)hedgeL[i] * 256 + lane * 4] =
      *(const uint2*)&Xc[(i64)il * 256 + lane * 4];
}

__global__ __launch_bounds__(256) void scatter_nc_k(const ushort* __restrict__ Xc,
                                                    const int* __restrict__ subg,
                                                    const int* __restrict__ nodeL,
                                                    const int* __restrict__ tot,
                                                    float* __restrict__ unity, int base) {
  const int il = blockIdx.x * 4 + (threadIdx.x >> 6);
  const int lane = threadIdx.x & 63;
  const int i = base + il;
  if (tot && i >= tot[0]) return;
  const int dst = subg[nodeL[i]];
  ushort4 v = *(const ushort4*)&Xc[(i64)il * 256 + lane * 4];
  float4 o; o.x = b2f(v.x); o.y = b2f(v.y); o.z = b2f(v.z); o.w = b2f(v.w);
  *(float4*)&unity[(i64)dst * 256 + lane * 4] = o;
}

__global__ __launch_bounds__(256) void ext_init_k(ushort* __restrict__ ext,
                                                  const float* __restrict__ pad,
                                                  const float* __restrict__ cls) {
  const int d = threadIdx.x;
  ext[(i64)NHEDGE * 256 + d] = f2b(pad[d]);
  ext[(i64)(NHEDGE + 1) * 256 + d] = f2b(cls[d]);
  for (int r = NHEDGE + 2; r < EXTROWS; r += 1)
    ext[(i64)r * 256 + d] = 0;
}

__global__ __launch_bounds__(256) void out_cvt_k(const ushort* __restrict__ predHe,
                                                 float* __restrict__ out) {
  const int i = blockIdx.x * 4 + (threadIdx.x >> 6);
  const int lane = threadIdx.x & 63;
  ushort4 v = *(const ushort4*)&predHe[(i64)i * 256 + lane * 4];
  float4 o; o.x = b2f(v.x); o.y = b2f(v.y); o.z = b2f(v.z); o.w = b2f(v.w);
  *(float4*)&out[(i64)i * 256 + lane * 4] = o;
}

// ================= host orchestration ==========================================
extern "C" void kernel_launch(void* const* d_in, const int* in_sizes, int n_in,
                              void* d_out, int out_size, void* d_ws, size_t ws_size,
                              hipStream_t stream) {
  (void)in_sizes; (void)n_in; (void)out_size;
  const float* unity_in = (const float*)d_in[0];
  const float* cls_emb  = (const float*)d_in[1];
  const float* pad_emb  = (const float*)d_in[2];
  const float* pos_tab  = (const float*)d_in[3];
  const float* qkv_w    = (const float*)d_in[4];
  const float* qkv_b    = (const float*)d_in[5];
  const float* out_w    = (const float*)d_in[6];
  const float* out_b    = (const float*)d_in[7];
  const float* ln1_g    = (const float*)d_in[8];
  const float* ln1_b    = (const float*)d_in[9];
  const float* ln2_g    = (const float*)d_in[10];
  const float* ln2_b    = (const float*)d_in[11];
  const float* ff1_w    = (const float*)d_in[12];
  const float* ff1_b    = (const float*)d_in[13];
  const float* ff2_w    = (const float*)d_in[14];
  const float* ff2_b    = (const float*)d_in[15];
  const int* xid   = (const int*)d_in[16];
  const int* vmask = (const int*)d_in[17];
  const int* xpos  = (const int*)d_in[18];
  const int* hid   = (const int*)d_in[19];
  const int* hmask = (const int*)d_in[20];
  const int* subg  = (const int*)d_in[21];
  const int* pred  = (const int*)d_in[22];

  const i64 unity_b = (i64)NTOTAL * 256 * 4;
  const i64 ext_b   = (i64)EXTROWS * 256 * 2;
  const i64 qkvE_b  = (i64)EXTROWS * 768 * 2;
  const int nq = 2 * 768 * 256, no = 2 * 256 * 256,
            n1 = 2 * 1024 * 256, n2 = 2 * 256 * 1024;
  const i64 wts_b = (i64)(nq + no + n1 + n2) * 2;
  const i64 idx_b = 16 * 1024 * 1024;
  const i64 per_elem = (i64)SE * (512 + 2048 + 512 + 4);
  int CHUNK = 8192;
  while (CHUNK > 4096 &&
         unity_b + ext_b + qkvE_b + wts_b + idx_b + (i64)CHUNK * per_elem > (i64)ws_size)
    CHUNK >>= 1;
  const int NCH_H = NHEDGE / CHUNK;
  const int NCH_N = NNODE / CHUNK;

  char* w = (char*)d_ws;
  float*  unity = (float*)w;  w += unity_b;
  ushort* ext   = (ushort*)w; w += ext_b;
  ushort* qkvE  = (ushort*)w; w += qkvE_b;
  ushort* wq    = (ushort*)w; w += (i64)nq * 2;
  ushort* wo    = (ushort*)w; w += (i64)no * 2;
  ushort* w1    = (ushort*)w; w += (i64)n1 * 2;
  ushort* w2    = (ushort*)w; w += (i64)n2 * 2;
  ushort* X     = (ushort*)w; w += (i64)CHUNK * SE * 256 * 2;
  ushort* Y     = (ushort*)w; w += (i64)CHUNK * SE * 1024 * 2;
  ushort* O     = (ushort*)w; w += (i64)CHUNK * SE * 256 * 2;
  int* gid    = (int*)w; w += (i64)CHUNK * SE * 4;
  int* inv    = (int*)w; w += (i64)NTOTAL * 4;
  int* cntE   = (int*)w; w += (i64)NNODE * 4;
  int* cntV   = (int*)w; w += (i64)NHEDGE * 4;
  int* partV  = (int*)w; w += 256 * 4;
  int* partN  = (int*)w; w += 256 * 4;
  int* partA  = (int*)w; w += 256 * 4;
  int* partB  = (int*)w; w += 256 * 4;
  int* ssV    = (int*)w; w += (i64)(NHEDGE + 1) * 4;
  int* ssP    = (int*)w; w += 257 * 4;
  int* ssN    = (int*)w; w += (i64)(NN1 + 1) * 4;
  int* nodeL  = (int*)w; w += (i64)NN1 * 4;
  int* cntN   = (int*)w; w += (i64)NN1 * 4;
  int* tokV   = (int*)w; w += (i64)NHEDGE * SV * 4;
  int* tokP   = (int*)w; w += MPRED * 4;
  int* tokN   = (int*)w; w += (i64)MN1 * 4;
  int* gidN   = (int*)w; w += (i64)MN1 * 4;
  int* flagH  = (int*)w; w += (i64)NHEDGE * 4;
  int* flagE  = (int*)w; w += (i64)NTOTAL * 4;
  int* posH   = (int*)w; w += (i64)(NHEDGE + 1) * 4;
  int* posN   = (int*)w; w += (i64)(NNODE + 1) * 4;
  int* hedgeL = (int*)w; w += (i64)NHEDGE * 4;
  int* nodeL0 = (int*)w; w += (i64)NNODE * 4;
  int* cntB   = (int*)w; w += (i64)NHEDGE * 4;
  int* cntC   = (int*)w; w += (i64)NNODE * 4;
  int* cntD   = (int*)w; w += (i64)NNODE * 4;
  int* ssH    = (int*)w; w += (i64)(NHEDGE + 1) * 4;
  int* ssN0   = (int*)w; w += (i64)(NNODE + 1) * 4;
  int* tokH   = (int*)w; w += (i64)NHEDGE * SV * 4;
  int* tokN0  = (int*)w; w += (i64)NNODE * SE * 4;
  int* ssHseq = (int*)w; w += 16 * 4;
  int* ssNseq = (int*)w; w += 16 * 4;
  ushort* predHe = (ushort*)w; w += (i64)NPRED * 256 * 2;
  ushort* Ocls = O;
  ushort* Qcls = O + (i64)CHUNK * 256;
  ushort* X2   = O + (i64)2 * CHUNK * 256;
  ushort* X3   = O + (i64)3 * CHUNK * 256;

  f2b_cvt_k<<<512, 256, 0, stream>>>(qkv_w, wq, nq);
  f2b_cvt_k<<<512, 256, 0, stream>>>(out_w, wo, no);
  f2b_cvt_k<<<512, 256, 0, stream>>>(ff1_w, w1, n1);
  f2b_cvt_k<<<512, 256, 0, stream>>>(ff2_w, w2, n2);
  hipMemcpyAsync(unity, unity_in, unity_b, hipMemcpyDeviceToDevice, stream);
  ext_init_k<<<1, 256, 0, stream>>>(ext, pad_emb, cls_emb);

  cnt_k<<<NHEDGE / 256, 256, 0, stream>>>(vmask, ARITY, 1, cntV, NHEDGE);
  scan1_k<<<NHEDGE / 256, 256, 0, stream>>>(cntV, ssV, partV, NHEDGE);
  scan2_k<<<1, 256, 0, stream>>>(partV, NHEDGE / 256, ssV, NHEDGE);
  scan3_k<<<NHEDGE / 256, 256, 0, stream>>>(ssV, partV, vmask, ARITY, 1, tokV, NHEDGE);
  cnt_k<<<NNODE / 256, 256, 0, stream>>>(hmask, SE, 0, cntE, NNODE);
  predscan_k<<<1, 256, 0, stream>>>(pred, cntV, vmask, ssP, tokP);
  inv_init_k<<<(NTOTAL + 255) / 256, 256, 0, stream>>>(inv, NTOTAL);
  inv_fill_k<<<NNODE / 256, 256, 0, stream>>>(subg, inv, NNODE);
  prednode_k<<<NN1 / 256, 256, 0, stream>>>(pred, xid, vmask, inv, cntE, nodeL, cntN);
  scan1_k<<<NN1 / 256, 256, 0, stream>>>(cntN, ssN, partN, NN1);
  scan2_k<<<1, 256, 0, stream>>>(partN, NN1 / 256, ssN, NN1);
  scan3n_k<<<NN1 / 256, 256, 0, stream>>>(ssN, partN, hmask, nodeL, tokN);
  zero_k<<<NHEDGE / 256, 256, 0, stream>>>(flagH, NHEDGE);
  zero_k<<<(NTOTAL + 255) / 256, 256, 0, stream>>>(flagE, NTOTAL);
  flagH_k<<<(NN1 * SE + 255) / 256, 256, 0, stream>>>(nodeL, hmask, hid, flagH);
  flagE_k<<<NHEDGE * ARITY / 256, 256, 0, stream>>>(flagH, vmask, xid, flagE);
  flagN_k<<<NNODE / 256, 256, 0, stream>>>(flagE, subg, cntC);
  scan1_k<<<NHEDGE / 256, 256, 0, stream>>>(flagH, posH, partA, NHEDGE);
  scan2_k<<<1, 256, 0, stream>>>(partA, NHEDGE / 256, posH, NHEDGE);
  fill_list_k<<<NHEDGE / 256, 256, 0, stream>>>(flagH, posH, partA, hedgeL, NHEDGE);
  cnt_list_k<<<NHEDGE / 256, 256, 0, stream>>>(hedgeL, posH + NHEDGE, cntV, cntB, NHEDGE);
  scan1_k<<<NHEDGE / 256, 256, 0, stream>>>(cntB, ssH, partA, NHEDGE);
  scan2_k<<<1, 256, 0, stream>>>(partA, NHEDGE / 256, ssH, NHEDGE);
  tok_hedge_k<<<NHEDGE / 256, 256, 0, stream>>>(ssH, partA, posH + NHEDGE, hedgeL, vmask, tokH);
  scan1_k<<<NNODE / 256, 256, 0, stream>>>(cntC, posN, partB, NNODE);
  scan2_k<<<1, 256, 0, stream>>>(partB, NNODE / 256, posN, NNODE);
  fill_list_k<<<NNODE / 256, 256, 0, stream>>>(cntC, posN, partB, nodeL0, NNODE);
  cnt_list_k<<<NNODE / 256, 256, 0, stream>>>(nodeL0, posN + NNODE, cntE, cntD, NNODE);
  scan1_k<<<NNODE / 256, 256, 0, stream>>>(cntD, ssN0, partB, NNODE);
  scan2_k<<<1, 256, 0, stream>>>(partB, NNODE / 256, ssN0, NNODE);
  tok_node_k<<<NNODE / 256, 256, 0, stream>>>(ssN0, partB, posN + NNODE, nodeL0, hmask, tokN0);
  seqlim_k<<<1, 64, 0, stream>>>(posH + NHEDGE, CHUNK, NCH_H, ssHseq);
  seqlim_k<<<1, 64, 0, stream>>>(posN + NNODE, CHUNK, NCH_N, ssNseq);

  const i64 KVo = (i64)768 * 256 + (i64)256 * 256;
  const i64 Qo  = (i64)768 * 256;

  // ================= hop 0: full V2E =================
  for (int c = 0; c < NCH_H; c++) {
    const int e0 = c * CHUNK;
    const int* ssc = ssV + e0;
    const int Mmax = CHUNK * SV;
    gather_v2e_k<<<Mmax / 4, 256, 0, stream>>>(unity, pos_tab, xid, xpos,
                                               tokV, ssc, CHUNK, X);
    gemm_bf16_k<256, 1><<<dim3(6, Mmax / 128), 256, 0, stream>>>(
        X, wq, qkv_b, Y, Mmax, 768, ssc, CHUNK, nullptr);
    attn1_k<SV><<<CHUNK, 16 * SV, 0, stream>>>(Y, ssc, O);
    gemm_ln_k<256><<<Mmax / 128, 512, 0, stream>>>(
        O, wo, out_b, X, 256, ln1_g, ln1_b, X, 256, Mmax, ssc, CHUNK, nullptr);
    ff_ln_k<<<Mmax / 64, 256, 0, stream>>>(
        X, w1, ff1_b, w2, ff2_b, X, 256, ln2_g, ln2_b, X, 256, Mmax, ssc, CHUNK);
    gemm_bf16_k<256, 1><<<dim3(4, Mmax / 128), 256, 0, stream>>>(
        X, wq + KVo, qkv_b + 768 + 256, Y, Mmax, 512, ssc, CHUNK, nullptr);
    gemm_bf16_k<256, 1><<<dim3(2, CHUNK / 128), 256, 0, stream>>>(
        X, wq + Qo, qkv_b + 768, Qcls, CHUNK, 256, nullptr, 0, ssc);
    attn_cls_k<SV><<<CHUNK / 16, 256, 0, stream>>>(Qcls, Y, ssc, Ocls);
    gemm_ln_k<256><<<CHUNK / 128, 512, 0, stream>>>(
        Ocls, wo + (i64)256 * 256, out_b + 256, X, 256,
        ln1_g + 256, ln1_b + 256, X2, 256, CHUNK, nullptr, 0, ssc);
    ff_ln_k<<<CHUNK / 64, 256, 0, stream>>>(
        X2, w1 + (i64)1024 * 256, ff1_b + 1024, w2 + (i64)256 * 1024, ff2_b + 256,
        X2, 256, ln2_g + 256, ln2_b + 256, ext + (i64)e0 * 256, 256, CHUNK,
        nullptr, 0);
  }
  gemm_bf16_k<256, 1><<<dim3(6, EXTROWS / 128), 256, 0, stream>>>(
      ext, wq, qkv_b, qkvE, EXTROWS, 768, nullptr, 0, nullptr);

  // ================= hop 0: E2V restricted to flagged nodes =================
  for (int c = 0; c < NCH_N; c++) {
    const int base = c * CHUNK;
    const int* ssc = ssN0 + base;
    const int* sqc = ssNseq + c;
    const int Mmax = CHUNK * SE;
    gather_e2vc_k<<<Mmax / 4, 256, 0, stream>>>(ext, hid, nodeL0, tokN0, ssc, CHUNK, X, gid);
    attn1g_k<SE><<<CHUNK, 16 * SE, 0, stream>>>(qkvE, gid, ssc, O);
    gemm_ln_k<256><<<Mmax / 128, 512, 0, stream>>>(
        O, wo, out_b, X, 256, ln1_g, ln1_b, X, 256, Mmax, ssc, CHUNK, nullptr);
    ff_ln_k<<<Mmax / 64, 256, 0, stream>>>(
        X, w1, ff1_b, w2, ff2_b, X, 256, ln2_g, ln2_b, X, 256, Mmax, ssc, CHUNK);
    gemm_bf16_k<256, 1><<<dim3(4, Mmax / 128), 256, 0, stream>>>(
        X, wq + KVo, qkv_b + 768 + 256, Y, Mmax, 512, ssc, CHUNK, nullptr);
    gemm_bf16_k<256, 1><<<dim3(2, CHUNK / 128), 256, 0, stream>>>(
        X, wq + Qo, qkv_b + 768, Qcls, CHUNK, 256, sqc, 1, ssc);
    attn_cls_k<SE><<<CHUNK / 16, 256, 0, stream>>>(Qcls, Y, ssc, Ocls);
    gemm_ln_k<256><<<CHUNK / 128, 512, 0, stream>>>(
        Ocls, wo + (i64)256 * 256, out_b + 256, X, 256,
        ln1_g + 256, ln1_b + 256, X2, 256, CHUNK, sqc, 1, ssc);
    ff_ln_k<<<CHUNK / 64, 256, 0, stream>>>(
        X2, w1 + (i64)1024 * 256, ff1_b + 1024, w2 + (i64)256 * 1024, ff2_b + 256,
        X2, 256, ln2_g + 256, ln2_b + 256, X3, 256, CHUNK, sqc, 1);
    scatter_nc_k<<<CHUNK / 4, 256, 0, stream>>>(X3, subg, nodeL0, posN + NNODE,
                                                unity, base);
  }

  // ================= hop 1: V2E restricted to flagged hedges =================
  for (int c = 0; c < NCH_H; c++) {
    const int base = c * CHUNK;
    const int* ssc = ssH + base;
    const int* sqc = ssHseq + c;
    const int Mmax = CHUNK * SV;
    gather_v2eh_k<<<Mmax / 4, 256, 0, stream>>>(unity, pos_tab, xid, xpos,
                                                hedgeL, tokH, ssc, CHUNK, X);
    gemm_bf16_k<256, 1><<<dim3(6, Mmax / 128), 256, 0, stream>>>(
        X, wq, qkv_b, Y, Mmax, 768, ssc, CHUNK, nullptr);
    attn1_k<SV><<<CHUNK, 16 * SV, 0, stream>>>(Y, ssc, O);
    gemm_ln_k<256><<<Mmax / 128, 512, 0, stream>>>(
        O, wo, out_b, X, 256, ln1_g, ln1_b, X, 256, Mmax, ssc, CHUNK, nullptr);
    ff_ln_k<<<Mmax / 64, 256, 0, stream>>>(
        X, w1, ff1_b, w2, ff2_b, X, 256, ln2_g, ln2_b, X, 256, Mmax, ssc, CHUNK);
    gemm_bf16_k<256, 1><<<dim3(4, Mmax / 128), 256, 0, stream>>>(
        X, wq + KVo, qkv_b + 768 + 256, Y, Mmax, 512, ssc, CHUNK, nullptr);
    gemm_bf16_k<256, 1><<<dim3(2, CHUNK / 128), 256, 0, stream>>>(
        X, wq + Qo, qkv_b + 768, Qcls, CHUNK, 256, sqc, 1, ssc);
    attn_cls_k<SV><<<CHUNK / 16, 256, 0, stream>>>(Qcls, Y, ssc, Ocls);
    gemm_ln_k<256><<<CHUNK / 128, 512, 0, stream>>>(
        Ocls, wo + (i64)256 * 256, out_b + 256, X, 256,
        ln1_g + 256, ln1_b + 256, X2, 256, CHUNK, sqc, 1, ssc);
    ff_ln_k<<<CHUNK / 64, 256, 0, stream>>>(
        X2, w1 + (i64)1024 * 256, ff1_b + 1024, w2 + (i64)256 * 1024, ff2_b + 256,
        X2, 256, ln2_g + 256, ln2_b + 256, X3, 256, CHUNK, sqc, 1);
    scatter_ext_k<<<CHUNK / 4, 256, 0, stream>>>(X3, hedgeL, posH + NHEDGE, ext, base);
  }
  gemm_bf16_k<256, 1><<<dim3(6, EXTROWS / 128), 256, 0, stream>>>(
      ext, wq, qkv_b, qkvE, EXTROWS, 768, nullptr, 0, nullptr);

  // ================= hop 1: E2V restricted to pred cone =================
  {
    gather_e2vc_k<<<MN1 / 4, 256, 0, stream>>>(ext, hid, nodeL, tokN, ssN, NN1, X, gidN);
    attn1g_k<SE><<<NN1, 16 * SE, 0, stream>>>(qkvE, gidN, ssN, O);
    gemm_ln_k<256><<<MN1 / 128, 512, 0, stream>>>(
        O, wo, out_b, X, 256, ln1_g, ln1_b, X, 256, MN1, ssN, NN1, nullptr);
    ff_ln_k<<<MN1 / 64, 256, 0, stream>>>(
        X, w1, ff1_b, w2, ff2_b, X, 256, ln2_g, ln2_b, X, 256, MN1, ssN, NN1);
    gemm_bf16_k<256, 1><<<dim3(4, MN1 / 128), 256, 0, stream>>>(
        X, wq + KVo, qkv_b + 768 + 256, Y, MN1, 512, ssN, NN1, nullptr);
    gemm_bf16_k<256, 1><<<dim3(2, NN1 / 128), 256, 0, stream>>>(
        X, wq + Qo, qkv_b + 768, Qcls, NN1, 256, nullptr, 0, ssN);
    attn_cls_k<SE><<<NN1 / 16, 256, 0, stream>>>(Qcls, Y, ssN, Ocls);
    gemm_ln_k<256><<<NN1 / 128, 512, 0, stream>>>(
        Ocls, wo + (i64)256 * 256, out_b + 256, X, 256,
        ln1_g + 256, ln1_b + 256, X2, 256, NN1, nullptr, 0, ssN);
    ff_ln_k<<<NN1 / 64, 256, 0, stream>>>(
        X2, w1 + (i64)1024 * 256, ff1_b + 1024, w2 + (i64)256 * 1024, ff2_b + 256,
        X2, 256, ln2_g + 256, ln2_b + 256, X3, 256, NN1, nullptr, 0);
    scatter_nc_k<<<NN1 / 4, 256, 0, stream>>>(X3, subg, nodeL, nullptr, unity, 0);
  }

  // ================= hop 2: V2E on the 256 predicted hedges =================
  {
    const int* ssc = ssP;
    gather_v2e_k<<<MPRED / 4, 256, 0, stream>>>(unity, pos_tab, xid, xpos,
                                                tokP, ssc, NPRED, X);
    gemm_bf16_k<256, 1><<<dim3(6, MPRED / 128), 256, 0, stream>>>(
        X, wq, qkv_b, Y, MPRED, 768, ssc, NPRED, nullptr);
    attn1_k<SV><<<NPRED, 16 * SV, 0, stream>>>(Y, ssc, O);
    gemm_ln_k<256><<<MPRED / 128, 512, 0, stream>>>(
        O, wo, out_b, X, 256, ln1_g, ln1_b, X, 256, MPRED, ssc, NPRED, nullptr);
    ff_ln_k<<<MPRED / 64, 256, 0, stream>>>(
        X, w1, ff1_b, w2, ff2_b, X, 256, ln2_g, ln2_b, X, 256, MPRED, ssc, NPRED);
    gemm_bf16_k<256, 1><<<dim3(4, MPRED / 128), 256, 0, stream>>>(
        X, wq + KVo, qkv_b + 768 + 256, Y, MPRED, 512, ssc, NPRED, nullptr);
    gemm_bf16_k<256, 1><<<dim3(2, NPRED / 128), 256, 0, stream>>>(
        X, wq + Qo, qkv_b + 768, Qcls, NPRED, 256, nullptr, 0, ssc);
    attn_cls_k<SV><<<NPRED / 16, 256, 0, stream>>>(Qcls, Y, ssc, Ocls);
    gemm_ln_k<256><<<NPRED / 128, 512, 0, stream>>>(
        Ocls, wo + (i64)256 * 256, out_b + 256, X, 256,
        ln1_g + 256, ln1_b + 256, X2, 256, NPRED, nullptr, 0, ssc);
    ff_ln_k<<<NPRED / 64, 256, 0, stream>>>(
        X2, w1 + (i64)1024 * 256, ff1_b + 1024, w2 + (i64)256 * 1024, ff2_b + 256,
        X2, 256, ln2_g + 256, ln2_b + 256, predHe, 256, NPRED, nullptr, 0);
  }
  out_cvt_k<<<NPRED / 4, 256, 0, stream>>>(predHe, (float*)d_out);
}

// Round 16
// 7083.978 us; speedup vs baseline: 3.6854x; 1.0008x over previous
//
#include <hip/hip_runtime.h>
#include <stdint.h>

typedef long long i64;
typedef __attribute__((ext_vector_type(8))) short bf16x8;
typedef __attribute__((ext_vector_type(4))) float f32x4;

#define SV 11
#define SE 17
#define ARITY 10
#define NHEDGE 32768
#define NNODE 65536
#define NTOTAL 100000
#define EXTROWS 32896
#define NPRED 256
#define MPRED 2816
#define NN1 2560
#define MN1 43520

__device__ __forceinline__ float b2f(ushort u) {
  union { uint32_t i; float f; } v; v.i = (uint32_t)u << 16; return v.f;
}
__device__ __forceinline__ ushort f2b(float f) {
  union { float f; uint32_t i; } v; v.f = f;
  uint32_t u = v.i + 0x7fffu + ((v.i >> 16) & 1u);
  return (ushort)(u >> 16);
}
__device__ __forceinline__ uint pack2(float a, float b) {
  return (uint)f2b(a) | ((uint)f2b(b) << 16);
}
__device__ __forceinline__ void cvt8(uint4 v, float* f) {
  f[0] = b2f((ushort)(v.x & 0xffff)); f[1] = b2f((ushort)(v.x >> 16));
  f[2] = b2f((ushort)(v.y & 0xffff)); f[3] = b2f((ushort)(v.y >> 16));
  f[4] = b2f((ushort)(v.z & 0xffff)); f[5] = b2f((ushort)(v.z >> 16));
  f[6] = b2f((ushort)(v.w & 0xffff)); f[7] = b2f((ushort)(v.w >> 16));
}

__device__ __forceinline__ void gload_lds16(const void* g, void* l) {
  __builtin_amdgcn_global_load_lds((const __attribute__((address_space(1))) void*)g,
                                   (__attribute__((address_space(3))) void*)l, 16, 0, 0);
}

__device__ __forceinline__ int xcd_swizzle(int orig, int nwg) {
  const int xcd = orig & 7, rest = orig >> 3;
  const int q = nwg >> 3, r = nwg & 7;
  return (xcd < r ? xcd * (q + 1) : r * (q + 1) + (xcd - r) * q) + rest;
}

// ================= compaction: count / scan / fill =============================
__global__ __launch_bounds__(256) void zero_k(int* __restrict__ p, int n) {
  const int i = blockIdx.x * 256 + threadIdx.x;
  if (i < n) p[i] = 0;
}

__global__ __launch_bounds__(256) void cnt_k(const int* __restrict__ mask, int width,
                                             int extra, int* __restrict__ cnt, int n) {
  const int i = blockIdx.x * 256 + threadIdx.x;
  if (i >= n) return;
  int c = extra;
  for (int j = 0; j < width; j++) c += (mask[(i64)i * width + j] != 0);
  cnt[i] = c;
}

__global__ __launch_bounds__(256) void scan1_k(const int* __restrict__ cnt,
                                               int* __restrict__ ss,
                                               int* __restrict__ part, int n) {
  __shared__ int sm[256];
  const int i = blockIdx.x * 256 + threadIdx.x;
  const int v = (i < n) ? cnt[i] : 0;
  sm[threadIdx.x] = v;
  __syncthreads();
  for (int o = 1; o < 256; o <<= 1) {
    const int t = (threadIdx.x >= o) ? sm[threadIdx.x - o] : 0;
    __syncthreads();
    sm[threadIdx.x] += t;
    __syncthreads();
  }
  if (i < n) ss[i] = sm[threadIdx.x] - v;
  if (threadIdx.x == 255) part[blockIdx.x] = sm[255];
}

__global__ __launch_bounds__(256) void scan2_k(int* __restrict__ part, int nb,
                                               int* __restrict__ ss, int n) {
  __shared__ int sm[256];
  const int v = (threadIdx.x < nb) ? part[threadIdx.x] : 0;
  sm[threadIdx.x] = v;
  __syncthreads();
  for (int o = 1; o < 256; o <<= 1) {
    const int t = (threadIdx.x >= o) ? sm[threadIdx.x - o] : 0;
    __syncthreads();
    sm[threadIdx.x] += t;
    __syncthreads();
  }
  if (threadIdx.x < nb) part[threadIdx.x] = sm[threadIdx.x] - v;
  if (threadIdx.x == 255) ss[n] = sm[255];
}

__global__ __launch_bounds__(256) void scan3_k(int* __restrict__ ss,
                                               const int* __restrict__ part,
                                               const int* __restrict__ mask, int width,
                                               int extra, int* __restrict__ tok, int n) {
  const int i = blockIdx.x * 256 + threadIdx.x;
  if (i >= n) return;
  int off = ss[i] + part[blockIdx.x];
  ss[i] = off;
  if (extra) {
    tok[off++] = (i << 5);
    for (int j = 0; j < width; j++)
      if (mask[(i64)i * width + j] != 0) tok[off++] = (i << 5) | (j + 1);
  } else {
    for (int j = 0; j < width; j++)
      if (mask[(i64)i * width + j] != 0) tok[off++] = (i << 5) | j;
  }
}

__global__ __launch_bounds__(256) void predscan_k(const int* __restrict__ pred,
                                                  const int* __restrict__ cntV,
                                                  const int* __restrict__ vmask,
                                                  int* __restrict__ ssP,
                                                  int* __restrict__ tokP) {
  __shared__ int sm[256];
  const int tid = threadIdx.x;
  const int e = pred[tid];
  const int v = cntV[e];
  sm[tid] = v;
  __syncthreads();
  for (int o = 1; o < 256; o <<= 1) {
    const int t = (tid >= o) ? sm[tid - o] : 0;
    __syncthreads();
    sm[tid] += t;
    __syncthreads();
  }
  int off = sm[tid] - v;
  ssP[tid] = off;
  if (tid == 255) ssP[256] = sm[255];
  tokP[off++] = (e << 5);
  for (int j = 0; j < ARITY; j++)
    if (vmask[(i64)e * ARITY + j] != 0) tokP[off++] = (e << 5) | (j + 1);
}

// ===== dependency-cone flags ==================================================
__global__ __launch_bounds__(256) void inv_init_k(int* __restrict__ inv, int n) {
  const int i = blockIdx.x * 256 + threadIdx.x;
  if (i < n) inv[i] = -1;
}
__global__ __launch_bounds__(256) void inv_fill_k(const int* __restrict__ subg,
                                                  int* __restrict__ inv, int n) {
  const int i = blockIdx.x * 256 + threadIdx.x;
  if (i < n) inv[subg[i]] = i;
}
__global__ __launch_bounds__(256) void prednode_k(const int* __restrict__ pred,
                                                  const int* __restrict__ xid,
                                                  const int* __restrict__ vmask,
                                                  const int* __restrict__ inv,
                                                  const int* __restrict__ cntE,
                                                  int* __restrict__ nodeL,
                                                  int* __restrict__ cntN) {
  const int i = blockIdx.x * 256 + threadIdx.x;
  if (i >= NN1) return;
  const int e = pred[i / ARITY], j = i - (i / ARITY) * ARITY;
  int nd = 0;
  if (vmask[(i64)e * ARITY + j] != 0) {
    const int v = inv[xid[(i64)e * ARITY + j]];
    if (v >= 0) nd = v;
  }
  nodeL[i] = nd;
  cntN[i] = cntE[nd];
}
__global__ __launch_bounds__(256) void scan3n_k(int* __restrict__ ss,
                                                const int* __restrict__ part,
                                                const int* __restrict__ hmask,
                                                const int* __restrict__ nodeL,
                                                int* __restrict__ tok) {
  const int i = blockIdx.x * 256 + threadIdx.x;
  if (i >= NN1) return;
  int off = ss[i] + part[blockIdx.x];
  ss[i] = off;
  const int nd = nodeL[i];
  for (int j = 0; j < SE; j++)
    if (hmask[(i64)nd * SE + j] != 0) tok[off++] = (i << 5) | j;
}

__global__ __launch_bounds__(256) void flagH_k(const int* __restrict__ nodeL,
                                               const int* __restrict__ hmask,
                                               const int* __restrict__ hid,
                                               int* __restrict__ flagH) {
  const int i = blockIdx.x * 256 + threadIdx.x;
  if (i >= NN1 * SE) return;
  const int s = i / SE, j = i - s * SE;
  const int nd = nodeL[s];
  if (hmask[(i64)nd * SE + j] != 0) {
    const int h = hid[(i64)nd * SE + j];
    if (h < NHEDGE) flagH[h] = 1;
  }
}
__global__ __launch_bounds__(256) void flagE_k(const int* __restrict__ flagH,
                                               const int* __restrict__ vmask,
                                               const int* __restrict__ xid,
                                               int* __restrict__ flagE) {
  const int i = blockIdx.x * 256 + threadIdx.x;
  if (i >= NHEDGE * ARITY) return;
  const int e = i / ARITY, j = i - e * ARITY;
  if (flagH[e] && vmask[(i64)e * ARITY + j] != 0) flagE[xid[(i64)e * ARITY + j]] = 1;
}
__global__ __launch_bounds__(256) void flagN_k(const int* __restrict__ flagE,
                                               const int* __restrict__ subg,
                                               int* __restrict__ cntC) {
  const int n = blockIdx.x * 256 + threadIdx.x;
  if (n < NNODE) cntC[n] = flagE[subg[n]];
}

__global__ __launch_bounds__(256) void fill_list_k(const int* __restrict__ flag,
                                                   const int* __restrict__ pos,
                                                   const int* __restrict__ part,
                                                   int* __restrict__ list, int n) {
  const int i = blockIdx.x * 256 + threadIdx.x;
  if (i < n && flag[i]) list[pos[i] + part[blockIdx.x]] = i;
}

__global__ __launch_bounds__(256) void cnt_list_k(const int* __restrict__ list,
                                                  const int* __restrict__ tot,
                                                  const int* __restrict__ cs,
                                                  int* __restrict__ cd, int n) {
  const int i = blockIdx.x * 256 + threadIdx.x;
  if (i >= n) return;
  cd[i] = (i < tot[0]) ? cs[list[i]] : 0;
}

__global__ __launch_bounds__(256) void tok_hedge_k(int* __restrict__ ss,
                                                   const int* __restrict__ part,
                                                   const int* __restrict__ tot,
                                                   const int* __restrict__ hedgeL,
                                                   const int* __restrict__ vmask,
                                                   int* __restrict__ tok) {
  const int i = blockIdx.x * 256 + threadIdx.x;
  if (i >= NHEDGE) return;
  int off = ss[i] + part[blockIdx.x];
  ss[i] = off;
  if (i >= tot[0]) return;
  const int e = hedgeL[i];
  tok[off++] = (i << 5);
  for (int j = 0; j < ARITY; j++)
    if (vmask[(i64)e * ARITY + j] != 0) tok[off++] = (i << 5) | (j + 1);
}

__global__ __launch_bounds__(256) void tok_node_k(int* __restrict__ ss,
                                                  const int* __restrict__ part,
                                                  const int* __restrict__ tot,
                                                  const int* __restrict__ nodeL0,
                                                  const int* __restrict__ hmask,
                                                  int* __restrict__ tok) {
  const int i = blockIdx.x * 256 + threadIdx.x;
  if (i >= NNODE) return;
  int off = ss[i] + part[blockIdx.x];
  ss[i] = off;
  if (i >= tot[0]) return;
  const int nd = nodeL0[i];
  for (int j = 0; j < SE; j++)
    if (hmask[(i64)nd * SE + j] != 0) tok[off++] = (i << 5) | j;
}

__global__ __launch_bounds__(64) void seqlim_k(const int* __restrict__ tot, int chunk,
                                               int nch, int* __restrict__ out) {
  const int c = threadIdx.x;
  if (c <= nch) out[c] = min(tot[0], c * chunk);
}

// ================= 128x128 bf16 MFMA GEMM =====================================
template <int K, int MODE>
__global__ __launch_bounds__(256) void gemm_bf16_k(const ushort* __restrict__ A,
                                                   const ushort* __restrict__ W,
                                                   const float* __restrict__ bias,
                                                   ushort* __restrict__ C, int M, int N,
                                                   const int* ssn, int nseq,
                                                   const int* arp) {
  const int tid = threadIdx.x;
  const int wave = tid >> 6, lane = tid & 63;
  const int nwg = gridDim.x * gridDim.y;
  const int wg = xcd_swizzle(blockIdx.y * gridDim.x + blockIdx.x, nwg);
  const int bx = wg % gridDim.x, by = wg / gridDim.x;
  const int m0 = by << 7, n0 = bx << 7;
  if (ssn && m0 >= ssn[nseq] - ssn[0]) return;
  __shared__ ushort As[128 * 64];
  __shared__ ushort Ws[128 * 64];
  const int wr = wave >> 1, wc = wave & 1;

  f32x4 acc[4][4];
#pragma unroll
  for (int m = 0; m < 4; m++)
#pragma unroll
    for (int n = 0; n < 4; n++) acc[m][n] = (f32x4){0.f, 0.f, 0.f, 0.f};

  const int srow = (wave << 5) + (lane >> 3);
  const int kblk_g = (lane & 7) ^ (lane >> 3);
  const i64 arow = arp ? (i64)(arp[m0 + srow] - arp[0]) : (i64)(m0 + srow);
  const ushort* Ag = A + arow * K + (kblk_g << 3);
  const ushort* Wg = W + (i64)(n0 + srow) * K + (kblk_g << 3);
  char* lA = (char*)As + (wave << 12);
  char* lB = (char*)Ws + (wave << 12);

#pragma unroll
  for (int i = 0; i < 4; i++) {
    gload_lds16(Ag + (i64)(i * 8) * K, lA + i * 1024);
    gload_lds16(Wg + (i64)(i * 8) * K, lB + i * 1024);
  }

  for (int k0 = 0; k0 < K; k0 += 64) {
    __syncthreads();
    bf16x8 af[2][4], bf[2][4];
#pragma unroll
    for (int kh = 0; kh < 2; kh++) {
      const int kb = (kh << 2) + (lane >> 4);
#pragma unroll
      for (int m = 0; m < 4; m++) {
        const int row = (wr << 6) + (m << 4) + (lane & 15);
        af[kh][m] = *(const bf16x8*)&As[row * 64 + ((kb ^ (row & 7)) << 3)];
      }
#pragma unroll
      for (int n = 0; n < 4; n++) {
        const int row = (wc << 6) + (n << 4) + (lane & 15);
        bf[kh][n] = *(const bf16x8*)&Ws[row * 64 + ((kb ^ (row & 7)) << 3)];
      }
    }
    __syncthreads();
    if (k0 + 64 < K) {
#pragma unroll
      for (int i = 0; i < 4; i++) {
        gload_lds16(Ag + (k0 + 64) + (i64)(i * 8) * K, lA + i * 1024);
        gload_lds16(Wg + (k0 + 64) + (i64)(i * 8) * K, lB + i * 1024);
      }
    }
#pragma unroll
    for (int kh = 0; kh < 2; kh++)
#pragma unroll
      for (int m = 0; m < 4; m++)
#pragma unroll
        for (int n = 0; n < 4; n++)
          acc[m][n] = __builtin_amdgcn_mfma_f32_16x16x32_bf16(bf[kh][n], af[kh][m], acc[m][n], 0, 0, 0);
  }

#pragma unroll
  for (int m = 0; m < 4; m++) {
    const int row = m0 + (wr << 6) + (m << 4) + (lane & 15);
#pragma unroll
    for (int n = 0; n < 4; n++) {
      const int col = n0 + (wc << 6) + (n << 4) + ((lane >> 4) << 2);
      float v0 = acc[m][n][0], v1 = acc[m][n][1], v2 = acc[m][n][2], v3 = acc[m][n][3];
      if (MODE > 0) {
        const f32x4 bv = *(const f32x4*)&bias[col];
        v0 += bv[0]; v1 += bv[1]; v2 += bv[2]; v3 += bv[3];
      }
      if (MODE == 2) {
        v0 = fmaxf(v0, 0.f); v1 = fmaxf(v1, 0.f);
        v2 = fmaxf(v2, 0.f); v3 = fmaxf(v3, 0.f);
      }
      uint2 o; o.x = pack2(v0, v1); o.y = pack2(v2, v3);
      *(uint2*)&C[(i64)row * N + col] = o;
    }
  }
}

// ============ Fused GEMM + residual + LayerNorm (N = 256, K = 256) =============
template <int K>
__global__ __launch_bounds__(512) void gemm_ln_k(const ushort* __restrict__ A,
                                                 const ushort* __restrict__ W,
                                                 const float* __restrict__ bias,
                                                 const ushort* R, int rstride,
                                                 const float* __restrict__ g,
                                                 const float* __restrict__ b,
                                                 ushort* C, int cstride, int M,
                                                 const int* ssn, int nseq,
                                                 const int* rrp) {
  const int m0 = blockIdx.x << 7;
  if (ssn && m0 >= ssn[nseq] - ssn[0]) return;
  __shared__ ushort As[128 * 64];
  __shared__ ushort Ws[256 * 64];
  __shared__ float partS[128][4];
  __shared__ float partQ[128][4];
  const int tid = threadIdx.x;
  const int wave = tid >> 6, lane = tid & 63;
  const int wr = wave >> 2, wc = wave & 3;

  f32x4 acc[4][4];
#pragma unroll
  for (int m = 0; m < 4; m++)
#pragma unroll
    for (int n = 0; n < 4; n++) acc[m][n] = (f32x4){0.f, 0.f, 0.f, 0.f};

  int rowA[2], kgA[2];
#pragma unroll
  for (int i = 0; i < 2; i++) {
    const int u = wave * 128 + i * 64 + lane;
    rowA[i] = u >> 3; kgA[i] = (u & 7) ^ ((u >> 3) & 7);
  }
  int rowW[4], kgW[4];
#pragma unroll
  for (int i = 0; i < 4; i++) {
    const int u = wave * 256 + i * 64 + lane;
    rowW[i] = u >> 3; kgW[i] = (u & 7) ^ ((u >> 3) & 7);
  }

#pragma unroll
  for (int i = 0; i < 2; i++)
    gload_lds16(A + (i64)(m0 + rowA[i]) * K + (kgA[i] << 3),
                (char*)As + (wave * 128 + i * 64) * 16);
#pragma unroll
  for (int i = 0; i < 4; i++)
    gload_lds16(W + (i64)rowW[i] * K + (kgW[i] << 3),
                (char*)Ws + (wave * 256 + i * 64) * 16);

  for (int k0 = 0; k0 < K; k0 += 64) {
    __syncthreads();
    bf16x8 af[2][4], bf[2][4];
#pragma unroll
    for (int kh = 0; kh < 2; kh++) {
      const int kb = (kh << 2) + (lane >> 4);
#pragma unroll
      for (int m = 0; m < 4; m++) {
        const int row = (wr << 6) + (m << 4) + (lane & 15);
        af[kh][m] = *(const bf16x8*)&As[row * 64 + ((kb ^ (row & 7)) << 3)];
      }
#pragma unroll
      for (int n = 0; n < 4; n++) {
        const int row = (wc << 6) + (n << 4) + (lane & 15);
        bf[kh][n] = *(const bf16x8*)&Ws[row * 64 + ((kb ^ (row & 7)) << 3)];
      }
    }
    __syncthreads();
    if (k0 + 64 < K) {
#pragma unroll
      for (int i = 0; i < 2; i++)
        gload_lds16(A + (i64)(m0 + rowA[i]) * K + (k0 + 64) + (kgA[i] << 3),
                    (char*)As + (wave * 128 + i * 64) * 16);
#pragma unroll
      for (int i = 0; i < 4; i++)
        gload_lds16(W + (i64)rowW[i] * K + (k0 + 64) + (kgW[i] << 3),
                    (char*)Ws + (wave * 256 + i * 64) * 16);
    }
#pragma unroll
    for (int kh = 0; kh < 2; kh++)
#pragma unroll
      for (int m = 0; m < 4; m++)
#pragma unroll
        for (int n = 0; n < 4; n++)
          acc[m][n] = __builtin_amdgcn_mfma_f32_16x16x32_bf16(bf[kh][n], af[kh][m], acc[m][n], 0, 0, 0);
  }

#pragma unroll
  for (int m = 0; m < 4; m++) {
    const int tokl = (wr << 6) + (m << 4) + (lane & 15);
    const int row = m0 + tokl;
    const i64 rr = rrp ? (i64)(rrp[row] - rrp[0]) : (i64)row;
    float s = 0.f, q = 0.f;
#pragma unroll
    for (int n = 0; n < 4; n++) {
      const int col = (wc << 6) + (n << 4) + ((lane >> 4) << 2);
      const f32x4 bv = *(const f32x4*)&bias[col];
      const uint2 ru = *(const uint2*)&R[rr * rstride + col];
      float v0 = acc[m][n][0] + bv[0] + b2f((ushort)(ru.x & 0xffff));
      float v1 = acc[m][n][1] + bv[1] + b2f((ushort)(ru.x >> 16));
      float v2 = acc[m][n][2] + bv[2] + b2f((ushort)(ru.y & 0xffff));
      float v3 = acc[m][n][3] + bv[3] + b2f((ushort)(ru.y >> 16));
      acc[m][n][0] = v0; acc[m][n][1] = v1; acc[m][n][2] = v2; acc[m][n][3] = v3;
      s += v0 + v1 + v2 + v3;
      q += v0 * v0 + v1 * v1 + v2 * v2 + v3 * v3;
    }
    s += __shfl_xor(s, 16, 64); s += __shfl_xor(s, 32, 64);
    q += __shfl_xor(q, 16, 64); q += __shfl_xor(q, 32, 64);
    if (lane < 16) { partS[tokl][wc] = s; partQ[tokl][wc] = q; }
  }
  __syncthreads();
#pragma unroll
  for (int m = 0; m < 4; m++) {
    const int tokl = (wr << 6) + (m << 4) + (lane & 15);
    const i64 row = (i64)(m0 + tokl);
    const f32x4 s4 = *(const f32x4*)&partS[tokl][0];
    const f32x4 q4 = *(const f32x4*)&partQ[tokl][0];
    const float mean = (s4[0] + s4[1] + s4[2] + s4[3]) * (1.f / 256.f);
    const float var = (q4[0] + q4[1] + q4[2] + q4[3]) * (1.f / 256.f) - mean * mean;
    const float rs = rsqrtf(var + 1e-5f);
#pragma unroll
    for (int n = 0; n < 4; n++) {
      const int col = (wc << 6) + (n << 4) + ((lane >> 4) << 2);
      const f32x4 g4 = *(const f32x4*)&g[col];
      const f32x4 b4 = *(const f32x4*)&b[col];
      uint2 o;
      o.x = pack2((acc[m][n][0] - mean) * rs * g4[0] + b4[0],
                  (acc[m][n][1] - mean) * rs * g4[1] + b4[1]);
      o.y = pack2((acc[m][n][2] - mean) * rs * g4[2] + b4[2],
                  (acc[m][n][3] - mean) * rs * g4[3] + b4[3]);
      *(uint2*)&C[row * cstride + col] = o;
    }
  }
}

// ===== Fused FFN: C = LN(R + relu(A@W1^T+b1)@W2^T + b2)*g + bb ================
__global__ __launch_bounds__(256) void ff_ln_k(const ushort* __restrict__ A,
                                               const ushort* __restrict__ W1,
                                               const float* __restrict__ b1,
                                               const ushort* __restrict__ W2,
                                               const float* __restrict__ b2,
                                               const ushort* R, int rstride,
                                               const float* __restrict__ g,
                                               const float* __restrict__ bb,
                                               ushort* C, int cstride, int M,
                                               const int* ssn, int nseq) {
  const int m0 = blockIdx.x << 6;
  if (ssn && m0 >= ssn[nseq] - ssn[0]) return;
  __shared__ ushort Ys[64 * 128];
  __shared__ ushort Stage[256 * 64];
  __shared__ float partS[64][4];
  __shared__ float partQ[64][4];
  const int tid = threadIdx.x;
  const int wave = tid >> 6, lane = tid & 63;

  f32x4 acc[4][4];
#pragma unroll
  for (int m = 0; m < 4; m++)
#pragma unroll
    for (int n = 0; n < 4; n++) acc[m][n] = (f32x4){0.f, 0.f, 0.f, 0.f};

  for (int fc = 0; fc < 8; fc++) {
    f32x4 accY[4][2];
#pragma unroll
    for (int m = 0; m < 4; m++)
#pragma unroll
      for (int n = 0; n < 2; n++) accY[m][n] = (f32x4){0.f, 0.f, 0.f, 0.f};

    for (int t = 0; t < 4; t++) {
      const int kk = t << 6;
#pragma unroll
      for (int i = 0; i < 2; i++) {
        const int u = i * 256 + tid;
        const int row = u >> 3, kg = (u & 7) ^ (row & 7);
        gload_lds16(A + (i64)(m0 + row) * 256 + kk + (kg << 3), (char*)Stage + u * 16);
      }
#pragma unroll
      for (int i = 0; i < 4; i++) {
        const int u = i * 256 + tid;
        const int row = u >> 3, kg = (u & 7) ^ (row & 7);
        gload_lds16(W1 + (i64)(fc * 128 + row) * 256 + kk + (kg << 3),
                    (char*)(Stage + 4096) + u * 16);
      }
      __syncthreads();
#pragma unroll
      for (int kh = 0; kh < 2; kh++) {
        const int kb = (kh << 2) + (lane >> 4);
        bf16x8 af[4], bf[2];
#pragma unroll
        for (int m = 0; m < 4; m++) {
          const int row = (m << 4) + (lane & 15);
          af[m] = *(const bf16x8*)&Stage[row * 64 + ((kb ^ (row & 7)) << 3)];
        }
#pragma unroll
        for (int n = 0; n < 2; n++) {
          const int row = (wave << 5) + (n << 4) + (lane & 15);
          bf[n] = *(const bf16x8*)&Stage[4096 + row * 64 + ((kb ^ (row & 7)) << 3)];
        }
#pragma unroll
        for (int m = 0; m < 4; m++)
#pragma unroll
          for (int n = 0; n < 2; n++)
            accY[m][n] = __builtin_amdgcn_mfma_f32_16x16x32_bf16(bf[n], af[m], accY[m][n], 0, 0, 0);
      }
      __syncthreads();
    }
#pragma unroll
    for (int m = 0; m < 4; m++) {
      const int row = (m << 4) + (lane & 15);
#pragma unroll
      for (int n = 0; n < 2; n++) {
        const int colg = (wave << 5) + (n << 4) + ((lane >> 4) << 2);
        const f32x4 bv = *(const f32x4*)&b1[fc * 128 + colg];
        const float v0 = fmaxf(accY[m][n][0] + bv[0], 0.f);
        const float v1 = fmaxf(accY[m][n][1] + bv[1], 0.f);
        const float v2 = fmaxf(accY[m][n][2] + bv[2], 0.f);
        const float v3 = fmaxf(accY[m][n][3] + bv[3], 0.f);
        const int kbY = colg >> 3, off = colg & 7;
        const int swz = (kbY & 8) | ((kbY ^ (row & 7)) & 7);
        uint2 o; o.x = pack2(v0, v1); o.y = pack2(v2, v3);
        *(uint2*)&Ys[row * 128 + swz * 8 + off] = o;
      }
    }
#pragma unroll
    for (int ks = 0; ks < 2; ks++) {
#pragma unroll
      for (int i = 0; i < 8; i++) {
        const int u = i * 256 + tid;
        const int row = u >> 3, kg = (u & 7) ^ (row & 7);
        gload_lds16(W2 + (i64)row * 1024 + fc * 128 + (ks << 6) + (kg << 3),
                    (char*)Stage + u * 16);
      }
      __syncthreads();
#pragma unroll
      for (int kh = 0; kh < 2; kh++) {
        const int kb = (kh << 2) + (lane >> 4);
        bf16x8 af[4], bf[4];
#pragma unroll
        for (int m = 0; m < 4; m++) {
          const int row = (m << 4) + (lane & 15);
          const int kbY = (ks << 3) + kb;
          const int swz = (kbY & 8) | ((kbY ^ (row & 7)) & 7);
          af[m] = *(const bf16x8*)&Ys[row * 128 + (swz << 3)];
        }
#pragma unroll
        for (int n = 0; n < 4; n++) {
          const int row = (wave << 6) + (n << 4) + (lane & 15);
          bf[n] = *(const bf16x8*)&Stage[row * 64 + ((kb ^ (row & 7)) << 3)];
        }
#pragma unroll
        for (int m = 0; m < 4; m++)
#pragma unroll
          for (int n = 0; n < 4; n++)
            acc[m][n] = __builtin_amdgcn_mfma_f32_16x16x32_bf16(bf[n], af[m], acc[m][n], 0, 0, 0);
      }
      __syncthreads();
    }
  }

#pragma unroll
  for (int m = 0; m < 4; m++) {
    const int tokl = (m << 4) + (lane & 15);
    const i64 row = (i64)(m0 + tokl);
    float s = 0.f, q = 0.f;
#pragma unroll
    for (int n = 0; n < 4; n++) {
      const int col = (wave << 6) + (n << 4) + ((lane >> 4) << 2);
      const f32x4 bv = *(const f32x4*)&b2[col];
      const uint2 ru = *(const uint2*)&R[row * rstride + col];
      float v0 = acc[m][n][0] + bv[0] + b2f((ushort)(ru.x & 0xffff));
      float v1 = acc[m][n][1] + bv[1] + b2f((ushort)(ru.x >> 16));
      float v2 = acc[m][n][2] + bv[2] + b2f((ushort)(ru.y & 0xffff));
      float v3 = acc[m][n][3] + bv[3] + b2f((ushort)(ru.y >> 16));
      acc[m][n][0] = v0; acc[m][n][1] = v1; acc[m][n][2] = v2; acc[m][n][3] = v3;
      s += v0 + v1 + v2 + v3;
      q += v0 * v0 + v1 * v1 + v2 * v2 + v3 * v3;
    }
    s += __shfl_xor(s, 16, 64); s += __shfl_xor(s, 32, 64);
    q += __shfl_xor(q, 16, 64); q += __shfl_xor(q, 32, 64);
    if (lane < 16) { partS[tokl][wave] = s; partQ[tokl][wave] = q; }
  }
  __syncthreads();
#pragma unroll
  for (int m = 0; m < 4; m++) {
    const int tokl = (m << 4) + (lane & 15);
    const i64 row = (i64)(m0 + tokl);
    const f32x4 s4 = *(const f32x4*)&partS[tokl][0];
    const f32x4 q4 = *(const f32x4*)&partQ[tokl][0];
    const float mean = (s4[0] + s4[1] + s4[2] + s4[3]) * (1.f / 256.f);
    const float var = (q4[0] + q4[1] + q4[2] + q4[3]) * (1.f / 256.f) - mean * mean;
    const float rs = rsqrtf(var + 1e-5f);
#pragma unroll
    for (int n = 0; n < 4; n++) {
      const int col = (wave << 6) + (n << 4) + ((lane >> 4) << 2);
      const f32x4 g4 = *(const f32x4*)&g[col];
      const f32x4 b4 = *(const f32x4*)&bb[col];
      uint2 o;
      o.x = pack2((acc[m][n][0] - mean) * rs * g4[0] + b4[0],
                  (acc[m][n][1] - mean) * rs * g4[1] + b4[1]);
      o.y = pack2((acc[m][n][2] - mean) * rs * g4[2] + b4[2],
                  (acc[m][n][3] - mean) * rs * g4[3] + b4[3]);
      *(uint2*)&C[row * cstride + col] = o;
    }
  }
}

// ========= Layer-1 attention (compact token rows) =============================
template <int S>
__global__ __launch_bounds__(16 * S) void attn1_k(const ushort* __restrict__ QKV,
                                                  const int* __restrict__ ss,
                                                  ushort* __restrict__ O) {
  __shared__ float KL[4][S][68];
  __shared__ float VL[4][S][68];
  const int tid = threadIdx.x;
  const int s0 = ss[0];
  const int base = ss[blockIdx.x] - s0;
  const int L = ss[blockIdx.x + 1] - ss[blockIdx.x];

  for (int u = tid; u < 128 * L; u += 16 * S) {
    const int d4 = u & 15, h = (u >> 4) & 3, mt = u >> 6;
    const int mat = (mt >= L), t = mat ? mt - L : mt;
    const ushort* gp = QKV + (i64)(base + t) * 768 + 256 + mat * 256 + h * 64 + d4 * 4;
    ushort4 raw = *(const ushort4*)gp;
    float* dst = (mat ? &VL[h][t][0] : &KL[h][t][0]) + d4 * 4;
    dst[0] = b2f(raw.x); dst[1] = b2f(raw.y); dst[2] = b2f(raw.z); dst[3] = b2f(raw.w);
  }
  __syncthreads();

  const int h = tid / (4 * S);
  const int r = tid - h * 4 * S;
  const int q = r >> 2, j = r & 3;
  if (q >= L) return;

  float qv[16];
  {
    const ushort* qp = QKV + (i64)(base + q) * 768 + h * 64 + j * 16;
    cvt8(*(const uint4*)qp, qv);
    cvt8(*(const uint4*)(qp + 8), qv + 8);
  }

  float w[S];
  float mx = -1e30f;
#pragma unroll
  for (int s = 0; s < S; s++) {
    float p = -1e30f;
    if (s < L) {
      const float* kr = &KL[h][s][j * 16];
      p = 0.f;
#pragma unroll
      for (int e = 0; e < 4; e++) {
        const float4 kv = *(const float4*)(kr + e * 4);
        p = fmaf(qv[e * 4 + 0], kv.x, p);
        p = fmaf(qv[e * 4 + 1], kv.y, p);
        p = fmaf(qv[e * 4 + 2], kv.z, p);
        p = fmaf(qv[e * 4 + 3], kv.w, p);
      }
      p += __shfl_xor(p, 1, 64);
      p += __shfl_xor(p, 2, 64);
      p *= 0.125f;
    }
    w[s] = p;
    mx = fmaxf(mx, p);
  }
  float sum = 0.f;
#pragma unroll
  for (int s = 0; s < S; s++) { w[s] = __expf(w[s] - mx); sum += w[s]; }
  const float inv = 1.f / sum;

  float o[16];
#pragma unroll
  for (int e = 0; e < 16; e++) o[e] = 0.f;
#pragma unroll
  for (int s = 0; s < S; s++) {
    if (s < L) {
      const float ws = w[s];
      const float* vr = &VL[h][s][j * 16];
#pragma unroll
      for (int e = 0; e < 4; e++) {
        const float4 vv = *(const float4*)(vr + e * 4);
        o[e * 4 + 0] = fmaf(ws, vv.x, o[e * 4 + 0]);
        o[e * 4 + 1] = fmaf(ws, vv.y, o[e * 4 + 1]);
        o[e * 4 + 2] = fmaf(ws, vv.z, o[e * 4 + 2]);
        o[e * 4 + 3] = fmaf(ws, vv.w, o[e * 4 + 3]);
      }
    }
  }
  uint4 st0, st1;
  st0.x = pack2(o[0] * inv, o[1] * inv);   st0.y = pack2(o[2] * inv, o[3] * inv);
  st0.z = pack2(o[4] * inv, o[5] * inv);   st0.w = pack2(o[6] * inv, o[7] * inv);
  st1.x = pack2(o[8] * inv, o[9] * inv);   st1.y = pack2(o[10] * inv, o[11] * inv);
  st1.z = pack2(o[12] * inv, o[13] * inv); st1.w = pack2(o[14] * inv, o[15] * inv);
  ushort* op = O + (i64)(base + q) * 256 + h * 64 + j * 16;
  *(uint4*)op = st0;
  *(uint4*)(op + 8) = st1;
}

// ========= Layer-1 attention, E2V: QKV gathered from hedge table ==============
template <int S>
__global__ __launch_bounds__(16 * S) void attn1g_k(const ushort* __restrict__ QKVE,
                                                   const int* __restrict__ gid,
                                                   const int* __restrict__ ss,
                                                   ushort* __restrict__ O) {
  __shared__ float KL[4][S][68];
  __shared__ float VL[4][S][68];
  __shared__ int ids[S];
  const int tid = threadIdx.x;
  const int s0 = ss[0];
  const int base = ss[blockIdx.x] - s0;
  const int L = ss[blockIdx.x + 1] - ss[blockIdx.x];

  if (tid < L) ids[tid] = gid[base + tid];
  __syncthreads();

  for (int u = tid; u < 128 * L; u += 16 * S) {
    const int d4 = u & 15, h = (u >> 4) & 3, mt = u >> 6;
    const int mat = (mt >= L), t = mat ? mt - L : mt;
    const ushort* gp = QKVE + (i64)ids[t] * 768 + 256 + mat * 256 + h * 64 + d4 * 4;
    ushort4 raw = *(const ushort4*)gp;
    float* dst = (mat ? &VL[h][t][0] : &KL[h][t][0]) + d4 * 4;
    dst[0] = b2f(raw.x); dst[1] = b2f(raw.y); dst[2] = b2f(raw.z); dst[3] = b2f(raw.w);
  }
  __syncthreads();

  const int h = tid / (4 * S);
  const int r = tid - h * 4 * S;
  const int q = r >> 2, j = r & 3;
  if (q >= L) return;

  float qv[16];
  {
    const ushort* qp = QKVE + (i64)ids[q] * 768 + h * 64 + j * 16;
    cvt8(*(const uint4*)qp, qv);
    cvt8(*(const uint4*)(qp + 8), qv + 8);
  }

  float w[S];
  float mx = -1e30f;
#pragma unroll
  for (int s = 0; s < S; s++) {
    float p = -1e30f;
    if (s < L) {
      const float* kr = &KL[h][s][j * 16];
      p = 0.f;
#pragma unroll
      for (int e = 0; e < 4; e++) {
        const float4 kv = *(const float4*)(kr + e * 4);
        p = fmaf(qv[e * 4 + 0], kv.x, p);
        p = fmaf(qv[e * 4 + 1], kv.y, p);
        p = fmaf(qv[e * 4 + 2], kv.z, p);
        p = fmaf(qv[e * 4 + 3], kv.w, p);
      }
      p += __shfl_xor(p, 1, 64);
      p += __shfl_xor(p, 2, 64);
      p *= 0.125f;
    }
    w[s] = p;
    mx = fmaxf(mx, p);
  }
  float sum = 0.f;
#pragma unroll
  for (int s = 0; s < S; s++) { w[s] = __expf(w[s] - mx); sum += w[s]; }
  const float inv = 1.f / sum;

  float o[16];
#pragma unroll
  for (int e = 0; e < 16; e++) o[e] = 0.f;
#pragma unroll
  for (int s = 0; s < S; s++) {
    if (s < L) {
      const float ws = w[s];
      const float* vr = &VL[h][s][j * 16];
#pragma unroll
      for (int e = 0; e < 4; e++) {
        const float4 vv = *(const float4*)(vr + e * 4);
        o[e * 4 + 0] = fmaf(ws, vv.x, o[e * 4 + 0]);
        o[e * 4 + 1] = fmaf(ws, vv.y, o[e * 4 + 1]);
        o[e * 4 + 2] = fmaf(ws, vv.z, o[e * 4 + 2]);
        o[e * 4 + 3] = fmaf(ws, vv.w, o[e * 4 + 3]);
      }
    }
  }
  uint4 st0, st1;
  st0.x = pack2(o[0] * inv, o[1] * inv);   st0.y = pack2(o[2] * inv, o[3] * inv);
  st0.z = pack2(o[4] * inv, o[5] * inv);   st0.w = pack2(o[6] * inv, o[7] * inv);
  st1.x = pack2(o[8] * inv, o[9] * inv);   st1.y = pack2(o[10] * inv, o[11] * inv);
  st1.z = pack2(o[12] * inv, o[13] * inv); st1.w = pack2(o[14] * inv, o[15] * inv);
  ushort* op = O + (i64)(base + q) * 256 + h * 64 + j * 16;
  *(uint4*)op = st0;
  *(uint4*)(op + 8) = st1;
}

// ===== Layer-2 attention, CLS query ===========================================
template <int S>
__global__ __launch_bounds__(256) void attn_cls_k(const ushort* __restrict__ Qc,
                                                  const ushort* __restrict__ KV,
                                                  const int* __restrict__ ss,
                                                  ushort* __restrict__ Ocls) {
  const int tid = threadIdx.x;
  const int sl = tid >> 4, h = (tid >> 2) & 3, j = tid & 3;
  const int seq = blockIdx.x * 16 + sl;
  const int base = ss[seq] - ss[0];
  const int L = ss[seq + 1] - ss[seq];

  float qv[16];
  {
    const ushort* qp = Qc + (i64)seq * 256 + h * 64 + j * 16;
    cvt8(*(const uint4*)qp, qv);
    cvt8(*(const uint4*)(qp + 8), qv + 8);
  }
  float w[S];
  float mx = -1e30f;
#pragma unroll
  for (int s = 0; s < S; s++) {
    float p = -1e30f;
    if (s < L) {
      float kf[16];
      const ushort* kp = KV + (i64)(base + s) * 512 + h * 64 + j * 16;
      cvt8(*(const uint4*)kp, kf);
      cvt8(*(const uint4*)(kp + 8), kf + 8);
      p = 0.f;
#pragma unroll
      for (int e = 0; e < 16; e++) p = fmaf(qv[e], kf[e], p);
      p += __shfl_xor(p, 1, 64);
      p += __shfl_xor(p, 2, 64);
      p *= 0.125f;
    }
    w[s] = p;
    mx = fmaxf(mx, p);
  }
  float sum = 0.f;
#pragma unroll
  for (int s = 0; s < S; s++) { w[s] = __expf(w[s] - mx); sum += w[s]; }
  const float inv = 1.f / sum;

  float o[16];
#pragma unroll
  for (int e = 0; e < 16; e++) o[e] = 0.f;
#pragma unroll
  for (int s = 0; s < S; s++) {
    if (s < L) {
      float vf[16];
      const ushort* vp = KV + (i64)(base + s) * 512 + 256 + h * 64 + j * 16;
      cvt8(*(const uint4*)vp, vf);
      cvt8(*(const uint4*)(vp + 8), vf + 8);
      const float ws = w[s];
#pragma unroll
      for (int e = 0; e < 16; e++) o[e] = fmaf(ws, vf[e], o[e]);
    }
  }
  uint4 st0, st1;
  st0.x = pack2(o[0] * inv, o[1] * inv);   st0.y = pack2(o[2] * inv, o[3] * inv);
  st0.z = pack2(o[4] * inv, o[5] * inv);   st0.w = pack2(o[6] * inv, o[7] * inv);
  st1.x = pack2(o[8] * inv, o[9] * inv);   st1.y = pack2(o[10] * inv, o[11] * inv);
  st1.z = pack2(o[12] * inv, o[13] * inv); st1.w = pack2(o[14] * inv, o[15] * inv);
  ushort* op = Ocls + (i64)seq * 256 + h * 64 + j * 16;
  *(uint4*)op = st0;
  *(uint4*)(op + 8) = st1;
}

// ================= gathers / scatters / conversion =============================
__global__ __launch_bounds__(256) void f2b_cvt_k(const float* __restrict__ in,
                                                 ushort* __restrict__ out, int n) {
  for (int i = blockIdx.x * 256 + threadIdx.x; i < n; i += gridDim.x * 256)
    out[i] = f2b(in[i]);
}

__global__ __launch_bounds__(256) void gather_v2e_k(const float* __restrict__ unity,
                                                    const float* __restrict__ pos,
                                                    const int* __restrict__ xid,
                                                    const int* __restrict__ xpos,
                                                    const int* __restrict__ tok,
                                                    const int* __restrict__ ss, int nseq,
                                                    ushort* __restrict__ X) {
  const int t = blockIdx.x * 4 + (threadIdx.x >> 6);
  const int lane = threadIdx.x & 63;
  const int s0 = ss[0];
  if (t >= ss[nseq] - s0) return;
  const int code = tok[s0 + t];
  const int e = code >> 5, slot = code & 31;
  float4 v = make_float4(0.f, 0.f, 0.f, 0.f);
  if (slot > 0) {
    const int id = xid[(i64)e * ARITY + (slot - 1)];
    v = *(const float4*)&unity[(i64)id * 256 + lane * 4];
  }
  const int pp = xpos[(i64)e * SV + slot];
  const float4 pv = *(const float4*)&pos[(i64)pp * 256 + lane * 4];
  uint2 o;
  o.x = pack2(v.x + pv.x, v.y + pv.y);
  o.y = pack2(v.z + pv.z, v.w + pv.w);
  *(uint2*)&X[(i64)t * 256 + lane * 4] = o;
}

__global__ __launch_bounds__(256) void gather_v2eh_k(const float* __restrict__ unity,
                                                     const float* __restrict__ pos,
                                                     const int* __restrict__ xid,
                                                     const int* __restrict__ xpos,
                                                     const int* __restrict__ hedgeL,
                                                     const int* __restrict__ tok,
                                                     const int* __restrict__ ss, int nseq,
                                                     ushort* __restrict__ X) {
  const int t = blockIdx.x * 4 + (threadIdx.x >> 6);
  const int lane = threadIdx.x & 63;
  const int s0 = ss[0];
  if (t >= ss[nseq] - s0) return;
  const int code = tok[s0 + t];
  const int e = hedgeL[code >> 5], slot = code & 31;
  float4 v = make_float4(0.f, 0.f, 0.f, 0.f);
  if (slot > 0) {
    const int id = xid[(i64)e * ARITY + (slot - 1)];
    v = *(const float4*)&unity[(i64)id * 256 + lane * 4];
  }
  const int pp = xpos[(i64)e * SV + slot];
  const float4 pv = *(const float4*)&pos[(i64)pp * 256 + lane * 4];
  uint2 o;
  o.x = pack2(v.x + pv.x, v.y + pv.y);
  o.y = pack2(v.z + pv.z, v.w + pv.w);
  *(uint2*)&X[(i64)t * 256 + lane * 4] = o;
}

__global__ __launch_bounds__(256) void gather_e2vc_k(const ushort* __restrict__ ext,
                                                     const int* __restrict__ hid,
                                                     const int* __restrict__ nodeL,
                                                     const int* __restrict__ tok,
                                                     const int* __restrict__ ss, int nseq,
                                                     ushort* __restrict__ X,
                                                     int* __restrict__ gid) {
  const int t = blockIdx.x * 4 + (threadIdx.x >> 6);
  const int lane = threadIdx.x & 63;
  const int s0 = ss[0];
  if (t >= ss[nseq] - s0) return;
  const int code = tok[s0 + t];
  const int id = hid[(i64)nodeL[code >> 5] * SE + (code & 31)];
  if (lane == 0) gid[t] = id;
  *(uint2*)&X[(i64)t * 256 + lane * 4] =
      *(const uint2*)&ext[(i64)id * 256 + lane * 4];
}

__global__ __launch_bounds__(256) void scatter_ext_k(const ushort* __restrict__ Xc,
                                                     const int* __restrict__ hedgeL,
                                                     const int* __restrict__ tot,
                                                     ushort* __restrict__ ext, int base) {
  const int il = blockIdx.x * 4 + (threadIdx.x >> 6);
  const int lane = threadIdx.x & 63;
  const int i = base + il;
  if (i >= tot[0]) return;
  *(uint2*)&ext[(i64)hedgeL[i] * 256 + lane * 4] =
      *(const uint2*)&Xc[(i64)il * 256 + lane * 4];
}

__global__ __launch_bounds__(256) void scatter_nc_k(const ushort* __restrict__ Xc,
                                                    const int* __restrict__ subg,
                                                    const int* __restrict__ nodeL,
                                                    const int* __restrict__ tot,
                                                    float* __restrict__ unity, int base) {
  const int il = blockIdx.x * 4 + (threadIdx.x >> 6);
  const int lane = threadIdx.x & 63;
  const int i = base + il;
  if (tot && i >= tot[0]) return;
  const int dst = subg[nodeL[i]];
  ushort4 v = *(const ushort4*)&Xc[(i64)il * 256 + lane * 4];
  float4 o; o.x = b2f(v.x); o.y = b2f(v.y); o.z = b2f(v.z); o.w = b2f(v.w);
  *(float4*)&unity[(i64)dst * 256 + lane * 4] = o;
}

__global__ __launch_bounds__(256) void ext_init_k(ushort* __restrict__ ext,
                                                  const float* __restrict__ pad,
                                                  const float* __restrict__ cls) {
  const int d = threadIdx.x;
  ext[(i64)NHEDGE * 256 + d] = f2b(pad[d]);
  ext[(i64)(NHEDGE + 1) * 256 + d] = f2b(cls[d]);
  for (int r = NHEDGE + 2; r < EXTROWS; r += 1)
    ext[(i64)r * 256 + d] = 0;
}

__global__ __launch_bounds__(256) void out_cvt_k(const ushort* __restrict__ predHe,
                                                 float* __restrict__ out) {
  const int i = blockIdx.x * 4 + (threadIdx.x >> 6);
  const int lane = threadIdx.x & 63;
  ushort4 v = *(const ushort4*)&predHe[(i64)i * 256 + lane * 4];
  float4 o; o.x = b2f(v.x); o.y = b2f(v.y); o.z = b2f(v.z); o.w = b2f(v.w);
  *(float4*)&out[(i64)i * 256 + lane * 4] = o;
}

// ================= host orchestration ==========================================
extern "C" void kernel_launch(void* const* d_in, const int* in_sizes, int n_in,
                              void* d_out, int out_size, void* d_ws, size_t ws_size,
                              hipStream_t stream) {
  (void)in_sizes; (void)n_in; (void)out_size;
  const float* unity_in = (const float*)d_in[0];
  const float* cls_emb  = (const float*)d_in[1];
  const float* pad_emb  = (const float*)d_in[2];
  const float* pos_tab  = (const float*)d_in[3];
  const float* qkv_w    = (const float*)d_in[4];
  const float* qkv_b    = (const float*)d_in[5];
  const float* out_w    = (const float*)d_in[6];
  const float* out_b    = (const float*)d_in[7];
  const float* ln1_g    = (const float*)d_in[8];
  const float* ln1_b    = (const float*)d_in[9];
  const float* ln2_g    = (const float*)d_in[10];
  const float* ln2_b    = (const float*)d_in[11];
  const float* ff1_w    = (const float*)d_in[12];
  const float* ff1_b    = (const float*)d_in[13];
  const float* ff2_w    = (const float*)d_in[14];
  const float* ff2_b    = (const float*)d_in[15];
  const int* xid   = (const int*)d_in[16];
  const int* vmask = (const int*)d_in[17];
  const int* xpos  = (const int*)d_in[18];
  const int* hid   = (const int*)d_in[19];
  const int* hmask = (const int*)d_in[20];
  const int* subg  = (const int*)d_in[21];
  const int* pred  = (const int*)d_in[22];

  const i64 unity_b = (i64)NTOTAL * 256 * 4;
  const i64 ext_b   = (i64)EXTROWS * 256 * 2;
  const i64 qkvE_b  = (i64)EXTROWS * 768 * 2;
  const int nq = 2 * 768 * 256, no = 2 * 256 * 256,
            n1 = 2 * 1024 * 256, n2 = 2 * 256 * 1024;
  const i64 wts_b = (i64)(nq + no + n1 + n2) * 2;
  const i64 idx_b = 16 * 1024 * 1024;
  const i64 per_elem = (i64)SE * (512 + 2048 + 512 + 4);
  int CHUNK = 8192;
  while (CHUNK > 4096 &&
         unity_b + ext_b + qkvE_b + wts_b + idx_b + (i64)CHUNK * per_elem > (i64)ws_size)
    CHUNK >>= 1;
  const int NCH_H = NHEDGE / CHUNK;
  const int NCH_N = NNODE / CHUNK;

  char* w = (char*)d_ws;
  float*  unity = (float*)w;  w += unity_b;
  ushort* ext   = (ushort*)w; w += ext_b;
  ushort* qkvE  = (ushort*)w; w += qkvE_b;
  ushort* wq    = (ushort*)w; w += (i64)nq * 2;
  ushort* wo    = (ushort*)w; w += (i64)no * 2;
  ushort* w1    = (ushort*)w; w += (i64)n1 * 2;
  ushort* w2    = (ushort*)w; w += (i64)n2 * 2;
  ushort* X     = (ushort*)w; w += (i64)CHUNK * SE * 256 * 2;
  ushort* Y     = (ushort*)w; w += (i64)CHUNK * SE * 1024 * 2;
  ushort* O     = (ushort*)w; w += (i64)CHUNK * SE * 256 * 2;
  int* gid    = (int*)w; w += (i64)CHUNK * SE * 4;
  int* inv    = (int*)w; w += (i64)NTOTAL * 4;
  int* cntE   = (int*)w; w += (i64)NNODE * 4;
  int* cntV   = (int*)w; w += (i64)NHEDGE * 4;
  int* partV  = (int*)w; w += 256 * 4;
  int* partN  = (int*)w; w += 256 * 4;
  int* partA  = (int*)w; w += 256 * 4;
  int* partB  = (int*)w; w += 256 * 4;
  int* ssV    = (int*)w; w += (i64)(NHEDGE + 1) * 4;
  int* ssP    = (int*)w; w += 257 * 4;
  int* ssN    = (int*)w; w += (i64)(NN1 + 1) * 4;
  int* nodeL  = (int*)w; w += (i64)NN1 * 4;
  int* cntN   = (int*)w; w += (i64)NN1 * 4;
  int* tokV   = (int*)w; w += (i64)NHEDGE * SV * 4;
  int* tokP   = (int*)w; w += MPRED * 4;
  int* tokN   = (int*)w; w += (i64)MN1 * 4;
  int* gidN   = (int*)w; w += (i64)MN1 * 4;
  int* flagH  = (int*)w; w += (i64)NHEDGE * 4;
  int* flagE  = (int*)w; w += (i64)NTOTAL * 4;
  int* posH   = (int*)w; w += (i64)(NHEDGE + 1) * 4;
  int* posN   = (int*)w; w += (i64)(NNODE + 1) * 4;
  int* hedgeL = (int*)w; w += (i64)NHEDGE * 4;
  int* nodeL0 = (int*)w; w += (i64)NNODE * 4;
  int* cntB   = (int*)w; w += (i64)NHEDGE * 4;
  int* cntC   = (int*)w; w += (i64)NNODE * 4;
  int* cntD   = (int*)w; w += (i64)NNODE * 4;
  int* ssH    = (int*)w; w += (i64)(NHEDGE + 1) * 4;
  int* ssN0   = (int*)w; w += (i64)(NNODE + 1) * 4;
  int* tokH   = (int*)w; w += (i64)NHEDGE * SV * 4;
  int* tokN0  = (int*)w; w += (i64)NNODE * SE * 4;
  int* ssHseq = (int*)w; w += 16 * 4;
  int* ssNseq = (int*)w; w += 16 * 4;
  ushort* predHe = (ushort*)w; w += (i64)NPRED * 256 * 2;
  ushort* Ocls = O;
  ushort* Qcls = O + (i64)CHUNK * 256;
  ushort* X2   = O + (i64)2 * CHUNK * 256;
  ushort* X3   = O + (i64)3 * CHUNK * 256;

  f2b_cvt_k<<<512, 256, 0, stream>>>(qkv_w, wq, nq);
  f2b_cvt_k<<<512, 256, 0, stream>>>(out_w, wo, no);
  f2b_cvt_k<<<512, 256, 0, stream>>>(ff1_w, w1, n1);
  f2b_cvt_k<<<512, 256, 0, stream>>>(ff2_w, w2, n2);
  hipMemcpyAsync(unity, unity_in, unity_b, hipMemcpyDeviceToDevice, stream);
  ext_init_k<<<1, 256, 0, stream>>>(ext, pad_emb, cls_emb);

  cnt_k<<<NHEDGE / 256, 256, 0, stream>>>(vmask, ARITY, 1, cntV, NHEDGE);
  scan1_k<<<NHEDGE / 256, 256, 0, stream>>>(cntV, ssV, partV, NHEDGE);
  scan2_k<<<1, 256, 0, stream>>>(partV, NHEDGE / 256, ssV, NHEDGE);
  scan3_k<<<NHEDGE / 256, 256, 0, stream>>>(ssV, partV, vmask, ARITY, 1, tokV, NHEDGE);
  cnt_k<<<NNODE / 256, 256, 0, stream>>>(hmask, SE, 0, cntE, NNODE);
  predscan_k<<<1, 256, 0, stream>>>(pred, cntV, vmask, ssP, tokP);
  inv_init_k<<<(NTOTAL + 255) / 256, 256, 0, stream>>>(inv, NTOTAL);
  inv_fill_k<<<NNODE / 256, 256, 0, stream>>>(subg, inv, NNODE);
  prednode_k<<<NN1 / 256, 256, 0, stream>>>(pred, xid, vmask, inv, cntE, nodeL, cntN);
  scan1_k<<<NN1 / 256, 256, 0, stream>>>(cntN, ssN, partN, NN1);
  scan2_k<<<1, 256, 0, stream>>>(partN, NN1 / 256, ssN, NN1);
  scan3n_k<<<NN1 / 256, 256, 0, stream>>>(ssN, partN, hmask, nodeL, tokN);
  zero_k<<<NHEDGE / 256, 256, 0, stream>>>(flagH, NHEDGE);
  zero_k<<<(NTOTAL + 255) / 256, 256, 0, stream>>>(flagE, NTOTAL);
  flagH_k<<<(NN1 * SE + 255) / 256, 256, 0, stream>>>(nodeL, hmask, hid, flagH);
  flagE_k<<<NHEDGE * ARITY / 256, 256, 0, stream>>>(flagH, vmask, xid, flagE);
  flagN_k<<<NNODE / 256, 256, 0, stream>>>(flagE, subg, cntC);
  scan1_k<<<NHEDGE / 256, 256, 0, stream>>>(flagH, posH, partA, NHEDGE);
  scan2_k<<<1, 256, 0, stream>>>(partA, NHEDGE / 256, posH, NHEDGE);
  fill_list_k<<<NHEDGE / 256, 256, 0, stream>>>(flagH, posH, partA, hedgeL, NHEDGE);
  cnt_list_k<<<NHEDGE / 256, 256, 0, stream>>>(hedgeL, posH + NHEDGE, cntV, cntB, NHEDGE);
  scan1_k<<<NHEDGE / 256, 256, 0, stream>>>(cntB, ssH, partA, NHEDGE);
  scan2_k<<<1, 256, 0, stream>>>(partA, NHEDGE / 256, ssH, NHEDGE);
  tok_hedge_k<<<NHEDGE / 256, 256, 0, stream>>>(ssH, partA, posH + NHEDGE, hedgeL, vmask, tokH);
  scan1_k<<<NNODE / 256, 256, 0, stream>>>(cntC, posN, partB, NNODE);
  scan2_k<<<1, 256, 0, stream>>>(partB, NNODE / 256, posN, NNODE);
  fill_list_k<<<NNODE / 256, 256, 0, stream>>>(cntC, posN, partB, nodeL0, NNODE);
  cnt_list_k<<<NNODE / 256, 256, 0, stream>>>(nodeL0, posN + NNODE, cntE, cntD, NNODE);
  scan1_k<<<NNODE / 256, 256, 0, stream>>>(cntD, ssN0, partB, NNODE);
  scan2_k<<<1, 256, 0, stream>>>(partB, NNODE / 256, ssN0, NNODE);
  tok_node_k<<<NNODE / 256, 256, 0, stream>>>(ssN0, partB, posN + NNODE, nodeL0, hmask, tokN0);
  seqlim_k<<<1, 64, 0, stream>>>(posH + NHEDGE, CHUNK, NCH_H, ssHseq);
  seqlim_k<<<1, 64, 0, stream>>>(posN + NNODE, CHUNK, NCH_N, ssNseq);

  const i64 KVo = (i64)768 * 256 + (i64)256 * 256;
  const i64 Qo  = (i64)768 * 256;

  // ================= hop 0: full V2E =================
  for (int c = 0; c < NCH_H; c++) {
    const int e0 = c * CHUNK;
    const int* ssc = ssV + e0;
    const int Mmax = CHUNK * SV;
    gather_v2e_k<<<Mmax / 4, 256, 0, stream>>>(unity, pos_tab, xid, xpos,
                                               tokV, ssc, CHUNK, X);
    gemm_bf16_k<256, 1><<<dim3(6, Mmax / 128), 256, 0, stream>>>(
        X, wq, qkv_b, Y, Mmax, 768, ssc, CHUNK, nullptr);
    attn1_k<SV><<<CHUNK, 16 * SV, 0, stream>>>(Y, ssc, O);
    gemm_ln_k<256><<<Mmax / 128, 512, 0, stream>>>(
        O, wo, out_b, X, 256, ln1_g, ln1_b, X, 256, Mmax, ssc, CHUNK, nullptr);
    ff_ln_k<<<Mmax / 64, 256, 0, stream>>>(
        X, w1, ff1_b, w2, ff2_b, X, 256, ln2_g, ln2_b, X, 256, Mmax, ssc, CHUNK);
    gemm_bf16_k<256, 1><<<dim3(4, Mmax / 128), 256, 0, stream>>>(
        X, wq + KVo, qkv_b + 768 + 256, Y, Mmax, 512, ssc, CHUNK, nullptr);
    gemm_bf16_k<256, 1><<<dim3(2, CHUNK / 128), 256, 0, stream>>>(
        X, wq + Qo, qkv_b + 768, Qcls, CHUNK, 256, nullptr, 0, ssc);
    attn_cls_k<SV><<<CHUNK / 16, 256, 0, stream>>>(Qcls, Y, ssc, Ocls);
    gemm_ln_k<256><<<CHUNK / 128, 512, 0, stream>>>(
        Ocls, wo + (i64)256 * 256, out_b + 256, X, 256,
        ln1_g + 256, ln1_b + 256, X2, 256, CHUNK, nullptr, 0, ssc);
    ff_ln_k<<<CHUNK / 64, 256, 0, stream>>>(
        X2, w1 + (i64)1024 * 256, ff1_b + 1024, w2 + (i64)256 * 1024, ff2_b + 256,
        X2, 256, ln2_g + 256, ln2_b + 256, ext + (i64)e0 * 256, 256, CHUNK,
        nullptr, 0);
  }
  gemm_bf16_k<256, 1><<<dim3(6, EXTROWS / 128), 256, 0, stream>>>(
      ext, wq, qkv_b, qkvE, EXTROWS, 768, nullptr, 0, nullptr);

  // ================= hop 0: E2V restricted to flagged nodes =================
  for (int c = 0; c < NCH_N; c++) {
    const int base = c * CHUNK;
    const int* ssc = ssN0 + base;
    const int* sqc = ssNseq + c;
    const int Mmax = CHUNK * SE;
    gather_e2vc_k<<<Mmax / 4, 256, 0, stream>>>(ext, hid, nodeL0, tokN0, ssc, CHUNK, X, gid);
    attn1g_k<SE><<<CHUNK, 16 * SE, 0, stream>>>(qkvE, gid, ssc, O);
    gemm_ln_k<256><<<Mmax / 128, 512, 0, stream>>>(
        O, wo, out_b, X, 256, ln1_g, ln1_b, X, 256, Mmax, ssc, CHUNK, nullptr);
    ff_ln_k<<<Mmax / 64, 256, 0, stream>>>(
        X, w1, ff1_b, w2, ff2_b, X, 256, ln2_g, ln2_b, X, 256, Mmax, ssc, CHUNK);
    gemm_bf16_k<256, 1><<<dim3(4, Mmax / 128), 256, 0, stream>>>(
        X, wq + KVo, qkv_b + 768 + 256, Y, Mmax, 512, ssc, CHUNK, nullptr);
    gemm_bf16_k<256, 1><<<dim3(2, CHUNK / 128), 256, 0, stream>>>(
        X, wq + Qo, qkv_b + 768, Qcls, CHUNK, 256, sqc, 1, ssc);
    attn_cls_k<SE><<<CHUNK / 16, 256, 0, stream>>>(Qcls, Y, ssc, Ocls);
    gemm_ln_k<256><<<CHUNK / 128, 512, 0, stream>>>(
        Ocls, wo + (i64)256 * 256, out_b + 256, X, 256,
        ln1_g + 256, ln1_b + 256, X2, 256, CHUNK, sqc, 1, ssc);
    ff_ln_k<<<CHUNK / 64, 256, 0, stream>>>(
        X2, w1 + (i64)1024 * 256, ff1_b + 1024, w2 + (i64)256 * 1024, ff2_b + 256,
        X2, 256, ln2_g + 256, ln2_b + 256, X3, 256, CHUNK, sqc, 1);
    scatter_nc_k<<<CHUNK / 4, 256, 0, stream>>>(X3, subg, nodeL0, posN + NNODE,
                                                unity, base);
  }

  // ================= hop 1: V2E restricted to flagged hedges =================
  for (int c = 0; c < NCH_H; c++) {
    const int base = c * CHUNK;
    const int* ssc = ssH + base;
    const int* sqc = ssHseq + c;
    const int Mmax = CHUNK * SV;
    gather_v2eh_k<<<Mmax / 4, 256, 0, stream>>>(unity, pos_tab, xid, xpos,
                                                hedgeL, tokH, ssc, CHUNK, X);
    gemm_bf16_k<256, 1><<<dim3(6, Mmax / 128), 256, 0, stream>>>(
        X, wq, qkv_b, Y, Mmax, 768, ssc, CHUNK, nullptr);
    attn1_k<SV><<<CHUNK, 16 * SV, 0, stream>>>(Y, ssc, O);
    gemm_ln_k<256><<<Mmax / 128, 512, 0, stream>>>(
        O, wo, out_b, X, 256, ln1_g, ln1_b, X, 256, Mmax, ssc, CHUNK, nullptr);
    ff_ln_k<<<Mmax / 64, 256, 0, stream>>>(
        X, w1, ff1_b, w2, ff2_b, X, 256, ln2_g, ln2_b, X, 256, Mmax, ssc, CHUNK);
    gemm_bf16_k<256, 1><<<dim3(4, Mmax / 128), 256, 0, stream>>>(
        X, wq + KVo, qkv_b + 768 + 256, Y, Mmax, 512, ssc, CHUNK, nullptr);
    gemm_bf16_k<256, 1><<<dim3(2, CHUNK / 128), 256, 0, stream>>>(
        X, wq + Qo, qkv_b + 768, Qcls, CHUNK, 256, sqc, 1, ssc);
    attn_cls_k<SV><<<CHUNK / 16, 256, 0, stream>>>(Qcls, Y, ssc, Ocls);
    gemm_ln_k<256><<<CHUNK / 128, 512, 0, stream>>>(
        Ocls, wo + (i64)256 * 256, out_b + 256, X, 256,
        ln1_g + 256, ln1_b + 256, X2, 256, CHUNK, sqc, 1, ssc);
    ff_ln_k<<<CHUNK / 64, 256, 0, stream>>>(
        X2, w1 + (i64)1024 * 256, ff1_b + 1024, w2 + (i64)256 * 1024, ff2_b + 256,
        X2, 256, ln2_g + 256, ln2_b + 256, X3, 256, CHUNK, sqc, 1);
    scatter_ext_k<<<CHUNK / 4, 256, 0, stream>>>(X3, hedgeL, posH + NHEDGE, ext, base);
  }
  gemm_bf16_k<256, 1><<<dim3(6, EXTROWS / 128), 256, 0, stream>>>(
      ext, wq, qkv_b, qkvE, EXTROWS, 768, nullptr, 0, nullptr);

  // ================= hop 1: E2V restricted to pred cone =================
  {
    gather_e2vc_k<<<MN1 / 4, 256, 0, stream>>>(ext, hid, nodeL, tokN, ssN, NN1, X, gidN);
    attn1g_k<SE><<<NN1, 16 * SE, 0, stream>>>(qkvE, gidN, ssN, O);
    gemm_ln_k<256><<<MN1 / 128, 512, 0, stream>>>(
        O, wo, out_b, X, 256, ln1_g, ln1_b, X, 256, MN1, ssN, NN1, nullptr);
    ff_ln_k<<<MN1 / 64, 256, 0, stream>>>(
        X, w1, ff1_b, w2, ff2_b, X, 256, ln2_g, ln2_b, X, 256, MN1, ssN, NN1);
    gemm_bf16_k<256, 1><<<dim3(4, MN1 / 128), 256, 0, stream>>>(
        X, wq + KVo, qkv_b + 768 + 256, Y, MN1, 512, ssN, NN1, nullptr);
    gemm_bf16_k<256, 1><<<dim3(2, NN1 / 128), 256, 0, stream>>>(
        X, wq + Qo, qkv_b + 768, Qcls, NN1, 256, nullptr, 0, ssN);
    attn_cls_k<SE><<<NN1 / 16, 256, 0, stream>>>(Qcls, Y, ssN, Ocls);
    gemm_ln_k<256><<<NN1 / 128, 512, 0, stream>>>(
        Ocls, wo + (i64)256 * 256, out_b + 256, X, 256,
        ln1_g + 256, ln1_b + 256, X2, 256, NN1, nullptr, 0, ssN);
    ff_ln_k<<<NN1 / 64, 256, 0, stream>>>(
        X2, w1 + (i64)1024 * 256, ff1_b + 1024, w2 + (i64)256 * 1024, ff2_b + 256,
        X2, 256, ln2_g + 256, ln2_b + 256, X3, 256, NN1, nullptr, 0);
    scatter_nc_k<<<NN1 / 4, 256, 0, stream>>>(X3, subg, nodeL, nullptr, unity, 0);
  }

  // ================= hop 2: V2E on the 256 predicted hedges =================
  {
    const int* ssc = ssP;
    gather_v2e_k<<<MPRED / 4, 256, 0, stream>>>(unity, pos_tab, xid, xpos,
                                                tokP, ssc, NPRED, X);
    gemm_bf16_k<256, 1><<<dim3(6, MPRED / 128), 256, 0, stream>>>(
        X, wq, qkv_b, Y, MPRED, 768, ssc, NPRED, nullptr);
    attn1_k<SV><<<NPRED, 16 * SV, 0, stream>>>(Y, ssc, O);
    gemm_ln_k<256><<<MPRED / 128, 512, 0, stream>>>(
        O, wo, out_b, X, 256, ln1_g, ln1_b, X, 256, MPRED, ssc, NPRED, nullptr);
    ff_ln_k<<<MPRED / 64, 256, 0, stream>>>(
        X, w1, ff1_b, w2, ff2_b, X, 256, ln2_g, ln2_b, X, 256, MPRED, ssc, NPRED);
    gemm_bf16_k<256, 1><<<dim3(4, MPRED / 128), 256, 0, stream>>>(
        X, wq + KVo, qkv_b + 768 + 256, Y, MPRED, 512, ssc, NPRED, nullptr);
    gemm_bf16_k<256, 1><<<dim3(2, NPRED / 128), 256, 0, stream>>>(
        X, wq + Qo, qkv_b + 768, Qcls, NPRED, 256, nullptr, 0, ssc);
    attn_cls_k<SV><<<NPRED / 16, 256, 0, stream>>>(Qcls, Y, ssc, Ocls);
    gemm_ln_k<256><<<NPRED / 128, 512, 0, stream>>>(
        Ocls, wo + (i64)256 * 256, out_b + 256, X, 256,
        ln1_g + 256, ln1_b + 256, X2, 256, NPRED, nullptr, 0, ssc);
    ff_ln_k<<<NPRED / 64, 256, 0, stream>>>(
        X2, w1 + (i64)1024 * 256, ff1_b + 1024, w2 + (i64)256 * 1024, ff2_b + 256,
        X2, 256, ln2_g + 256, ln2_b + 256, predHe, 256, NPRED, nullptr, 0);
  }
  out_cvt_k<<<NPRED / 4, 256, 0, stream>>>(predHe, (float*)d_out);
}